// Round 2
// baseline (2410.489 us; speedup 1.0000x reference)
//
#include <hip/hip_runtime.h>
#include <stdint.h>
#include <math.h>

typedef __attribute__((ext_vector_type(4))) float f4;
typedef __attribute__((ext_vector_type(8))) __bf16 bf8;
typedef __attribute__((ext_vector_type(8))) short s8;

#define DI __device__ __forceinline__

DI short f2bf(float f){
  union { float f; uint32_t u; } v; v.f = f;
  uint32_t r = v.u + 0x7fffu + ((v.u >> 16) & 1u);
  return (short)(r >> 16);
}
DI float bf2f(short s){
  union { uint32_t u; float f; } v; v.u = ((uint32_t)(uint16_t)s) << 16;
  return v.f;
}
DI float gelu_f(float u){
  return 0.5f*u*(1.f + tanhf(0.7978845608028654f*(u + 0.044715f*u*u*u)));
}
DI void gload16(const void* g, void* l){
  __builtin_amdgcn_global_load_lds((const __attribute__((address_space(1))) unsigned*)g,
                                   (__attribute__((address_space(3))) unsigned*)l, 16, 0, 0);
}

// ---------------- transpose + f32->bf16 convert: in [K][N] f32 -> out [N][K] bf16
// launch grid = (N/32, K/32, z)
__global__ __launch_bounds__(256)
void k_transpose(const float* __restrict__ in, short* __restrict__ out, int K, int N, size_t stride)
{
  __shared__ float t[32][33];
  in  += (size_t)blockIdx.z * stride;
  out += (size_t)blockIdx.z * stride;
  int n0 = blockIdx.x*32, k0 = blockIdx.y*32;
  int tx = threadIdx.x, ty = threadIdx.y;
  #pragma unroll
  for (int i=0;i<32;i+=8) t[ty+i][tx] = in[(size_t)(k0+ty+i)*N + n0+tx];
  __syncthreads();
  #pragma unroll
  for (int i=0;i<32;i+=8) out[(size_t)(n0+ty+i)*K + k0+tx] = f2bf(t[tx][ty+i]);
}

// ---------------- sinusoidal positional table pe[1024][512] f32
__global__ void k_pe(float* __restrict__ pe)
{
  int p = blockIdx.x;
  for (int d = threadIdx.x; d < 512; d += 256){
    int j = (d < 256) ? d : d - 256;
    float div = expf((float)(2*j) * (-9.210340371976184f/512.f));
    float a = (float)p * div;
    pe[(size_t)p*512 + d] = (d < 256) ? sinf(a) : cosf(a);
  }
}

// ---------------- patch gather: img NHWC f32 -> patches[16384][768] bf16
__global__ __launch_bounds__(256)
void k_gather(const float* __restrict__ img1, const float* __restrict__ img2, short* __restrict__ patches)
{
  int row = blockIdx.x;              // (img*8 + b)*1024 + p
  int img = row >> 13;
  int b   = (row >> 10) & 7;
  int p   = row & 1023;
  int ph = p >> 5, pw = p & 31;
  const float* src = (img ? img2 : img1) + (size_t)b*512*512*3;
  short* dst = patches + (size_t)row*768;
  for (int k = threadIdx.x; k < 768; k += 256){
    int i = k / 48; int rem = k - i*48; int j = rem / 3; int c = rem - j*3;
    int yy = ph*16 + i, xx = pw*16 + j;
    dst[k] = f2bf(src[((size_t)yy*512 + xx)*3 + c]);
  }
}

// ---------------- zero pad token rows of x, set cls rows
__global__ void k_zeropad(float* __restrict__ x)
{
  int idx = blockIdx.x; int ib = idx / 31; int t = 1025 + (idx - ib*31);
  x[((size_t)ib*1056 + t)*512 + threadIdx.x] = 0.f;
}
__global__ void k_cls(const float* __restrict__ ct, const float* __restrict__ cp, float* __restrict__ x)
{
  int ib = blockIdx.x; int e = threadIdx.x;
  x[(size_t)ib*1056*512 + e] = ct[e] + cp[e];
}

// ---------------- layernorm rows of x (fp32) -> y (bf16). 4 rows/block, 1 wave per row.
__global__ __launch_bounds__(256)
void k_layernorm(const float* __restrict__ x, short* __restrict__ y,
                 const float* __restrict__ g, const float* __restrict__ b)
{
  int row = blockIdx.x*4 + (threadIdx.x>>6);
  int l = threadIdx.x & 63;
  const float* xr = x + (size_t)row*512 + l*8;
  f4 v0 = *(const f4*)xr;
  f4 v1 = *(const f4*)(xr+4);
  float s = v0[0]+v0[1]+v0[2]+v0[3]+v1[0]+v1[1]+v1[2]+v1[3];
  float q = v0[0]*v0[0]+v0[1]*v0[1]+v0[2]*v0[2]+v0[3]*v0[3]
          + v1[0]*v1[0]+v1[1]*v1[1]+v1[2]*v1[2]+v1[3]*v1[3];
  #pragma unroll
  for (int m=1;m<64;m<<=1){ s += __shfl_xor(s,m); q += __shfl_xor(q,m); }
  float mu = s * 0.001953125f;
  float var = q * 0.001953125f - mu*mu;
  float rstd = rsqrtf(var + 1e-6f);
  const float* gp = g + l*8;
  const float* bp = b + l*8;
  s8 ov;
  #pragma unroll
  for (int j=0;j<8;j++){
    float xv = (j<4) ? v0[j] : v1[j-4];
    ov[j] = f2bf(gp[j]*(xv-mu)*rstd + bp[j]);
  }
  *(s8*)(y + (size_t)row*512 + l*8) = ov;
}

// ---------------- straight f32 -> bf16 cast (8 elems/thread)
__global__ void k_cast_bf16(const float* __restrict__ in, short* __restrict__ out)
{
  size_t i = (size_t)blockIdx.x*256 + threadIdx.x;
  const float* p = in + i*8;
  s8 ov;
  #pragma unroll
  for (int j=0;j<8;j++) ov[j] = f2bf(p[j]);
  *(s8*)(out + i*8) = ov;
}

// ---------------- bf16 MFMA GEMM, 128x128 tile, BK=32, A[M][K], Bt[N][K]
// EPI: 0=bf16 out, 1=bf16 out + vT scatter (QKV), 2=f32 residual add (+bias), 3=bias+gelu->bf16, 4=embed(+pe)->x
struct EpiArgs { short* outb; float* outf; const float* bias; const float* pe; short* vT; };

template<int EPI>
__global__ __launch_bounds__(256)
void k_gemm(const short* __restrict__ A, const short* __restrict__ Bt,
            int M, int N, int K, EpiArgs ea)
{
  __shared__ short Al[128*32];
  __shared__ short Bl[128*32];
  const int tid = threadIdx.x;
  const int l = tid & 63;
  const int w = tid >> 6;
  const int wr = (w >> 1) * 64, wc = (w & 1) * 64;
  const int lr = l & 15, lg = l >> 4;
  const int brow = blockIdx.y * 128, bcol = blockIdx.x * 128;
  const short* Ab = A  + (size_t)brow * K;
  const short* Bb = Bt + (size_t)bcol * K;
  f4 acc[4][4];
  #pragma unroll
  for (int m=0;m<4;m++)
    #pragma unroll
    for (int n=0;n<4;n++){ acc[m][n][0]=0.f; acc[m][n][1]=0.f; acc[m][n][2]=0.f; acc[m][n][3]=0.f; }

  const int c0 = tid, c1 = tid + 256;
  const int r0 = c0>>2, cc0 = (c0&3)*8;
  const int r1 = c1>>2, cc1 = (c1&3)*8;
  for (int kt = 0; kt < K; kt += 32){
    gload16(Ab + (size_t)r0*K + kt + cc0, &Al[c0*8]);
    gload16(Ab + (size_t)r1*K + kt + cc1, &Al[c1*8]);
    gload16(Bb + (size_t)r0*K + kt + cc0, &Bl[c0*8]);
    gload16(Bb + (size_t)r1*K + kt + cc1, &Bl[c1*8]);
    __syncthreads();
    bf8 af[4], bfr[4];
    #pragma unroll
    for (int m=0;m<4;m++) af[m]  = *(const bf8*)&Al[(wr + m*16 + lr)*32 + lg*8];
    #pragma unroll
    for (int n=0;n<4;n++) bfr[n] = *(const bf8*)&Bl[(wc + n*16 + lr)*32 + lg*8];
    #pragma unroll
    for (int m=0;m<4;m++)
      #pragma unroll
      for (int n=0;n<4;n++)
        acc[m][n] = __builtin_amdgcn_mfma_f32_16x16x32_bf16(af[m], bfr[n], acc[m][n], 0, 0, 0);
    __syncthreads();
  }
  #pragma unroll
  for (int m=0;m<4;m++){
    #pragma unroll
    for (int n=0;n<4;n++){
      #pragma unroll
      for (int r=0;r<4;r++){
        int row = brow + wr + m*16 + lg*4 + r;
        int col = bcol + wc + n*16 + lr;
        float v = acc[m][n][r];
        if (EPI == 0){
          ea.outb[(size_t)row*N + col] = f2bf(v);
        } else if (EPI == 1){
          ea.outb[(size_t)row*N + col] = f2bf(v);
          if (col >= 1024){
            int ib = row / 1056, t = row - ib*1056;
            ea.vT[((size_t)ib*512 + (col - 1024))*1056 + t] = f2bf(v);
          }
        } else if (EPI == 2){
          float bv = ea.bias ? ea.bias[col] : 0.f;
          ea.outf[(size_t)row*N + col] += v + bv;
        } else if (EPI == 3){
          ea.outb[(size_t)row*N + col] = f2bf(gelu_f(v + ea.bias[col]));
        } else if (EPI == 4){
          int ib = row >> 10, p = row & 1023;
          ea.outf[((size_t)(ib*1056 + 1 + p))*512 + col] = v + ea.pe[(size_t)p*512 + col];
        }
      }
    }
  }
}

// ---------------- fused self-attention: 1 wave per (unit, 32-row q tile)
// qkv [16896][1536] bf16 (q|k|v), vT [16][512][1056] bf16, out attn [16896][512] bf16
__global__ __launch_bounds__(64)
void k_attn(const short* __restrict__ qkv, const short* __restrict__ vT, short* __restrict__ aout)
{
  int qt = blockIdx.x;
  int u  = blockIdx.y;
  int ib = u >> 3, h = u & 7;
  int l = threadIdx.x, lr = l & 15, lg = l >> 4;
  const size_t rb = (size_t)ib * 1056;
  int t0 = qt * 32;
  bf8 qf[2][2];
  #pragma unroll
  for (int m=0;m<2;m++)
    #pragma unroll
    for (int ks=0;ks<2;ks++)
      qf[m][ks] = *(const bf8*)&qkv[(rb + t0 + m*16 + lr)*1536 + h*64 + ks*32 + lg*8];
  f4 o[2][4];
  float mrun[2][4], lrun[2][4];
  #pragma unroll
  for (int m=0;m<2;m++){
    #pragma unroll
    for (int n=0;n<4;n++){ o[m][n][0]=0.f; o[m][n][1]=0.f; o[m][n][2]=0.f; o[m][n][3]=0.f; }
    #pragma unroll
    for (int r=0;r<4;r++){ mrun[m][r] = -1e30f; lrun[m][r] = 0.f; }
  }
  __shared__ short Pl[32*32];
  for (int jt=0; jt<33; jt++){
    int j0 = jt*32;
    f4 s[2][2];
    #pragma unroll
    for (int m=0;m<2;m++)
      #pragma unroll
      for (int n=0;n<2;n++){ s[m][n][0]=0.f; s[m][n][1]=0.f; s[m][n][2]=0.f; s[m][n][3]=0.f; }
    #pragma unroll
    for (int n=0;n<2;n++)
      #pragma unroll
      for (int ks=0;ks<2;ks++){
        bf8 kf = *(const bf8*)&qkv[(rb + j0 + n*16 + lr)*1536 + 512 + h*64 + ks*32 + lg*8];
        #pragma unroll
        for (int m=0;m<2;m++)
          s[m][n] = __builtin_amdgcn_mfma_f32_16x16x32_bf16(qf[m][ks], kf, s[m][n], 0, 0, 0);
      }
    bool msk0 = (j0 + lr) > 1024;
    bool msk1 = (j0 + 16 + lr) > 1024;
    __syncthreads();   // previous PV reads of Pl done before overwrite
    #pragma unroll
    for (int m=0;m<2;m++){
      #pragma unroll
      for (int r=0;r<4;r++){
        float v0 = msk0 ? -1e30f : s[m][0][r]*0.125f;
        float v1 = msk1 ? -1e30f : s[m][1][r]*0.125f;
        float mx = fmaxf(v0, v1);
        #pragma unroll
        for (int mm=1; mm<16; mm<<=1) mx = fmaxf(mx, __shfl_xor(mx, mm, 16));
        float mn = fmaxf(mrun[m][r], mx);
        float scl = __expf(mrun[m][r] - mn);
        float p0 = __expf(v0 - mn), p1 = __expf(v1 - mn);
        float rs = p0 + p1;
        #pragma unroll
        for (int mm=1; mm<16; mm<<=1) rs += __shfl_xor(rs, mm, 16);
        mrun[m][r] = mn;
        lrun[m][r] = lrun[m][r]*scl + rs;
        int prow = m*16 + lg*4 + r;
        Pl[prow*32 + lr]      = f2bf(p0);
        Pl[prow*32 + 16 + lr] = f2bf(p1);
        #pragma unroll
        for (int n=0;n<4;n++) o[m][n][r] *= scl;
      }
    }
    __syncthreads();
    #pragma unroll
    for (int m=0;m<2;m++){
      bf8 pa = *(const bf8*)&Pl[(m*16 + lr)*32 + lg*8];
      #pragma unroll
      for (int n=0;n<4;n++){
        bf8 vb = *(const bf8*)&vT[((size_t)ib*512 + h*64 + n*16 + lr)*1056 + j0 + lg*8];
        o[m][n] = __builtin_amdgcn_mfma_f32_16x16x32_bf16(pa, vb, o[m][n], 0, 0, 0);
      }
    }
  }
  #pragma unroll
  for (int m=0;m<2;m++)
    #pragma unroll
    for (int n=0;n<4;n++)
      #pragma unroll
      for (int r=0;r<4;r++){
        int t = t0 + m*16 + lg*4 + r;
        int col = h*64 + n*16 + lr;
        aout[(rb + t)*512 + col] = f2bf(o[m][n][r] / lrun[m][r]);
      }
}

// ---------------- cross-attention path (tiny, fp32)
__global__ __launch_bounds__(256)
void k_cross_q(const float* __restrict__ x, const float* __restrict__ Wq, float* __restrict__ qc)
{
  __shared__ float xs[512];
  int ib = blockIdx.x;
  const float* xr = x + (size_t)ib*1056*512;
  for (int e=threadIdx.x;e<512;e+=256) xs[e] = xr[e];
  __syncthreads();
  for (int n=threadIdx.x;n<512;n+=256){
    float acc = 0.f;
    for (int k=0;k<512;k++) acc += xs[k]*Wq[(size_t)k*512 + n];
    qc[(size_t)ib*512 + n] = acc;
  }
}

__global__ __launch_bounds__(64)
void k_cross_attn(const float* __restrict__ qc, const short* __restrict__ kv, float* __restrict__ oc)
{
  int u = blockIdx.x; int ib = u >> 3, h = u & 7;
  int img = ib >> 3, b = ib & 7;
  int sib = (1 - img)*8 + b;
  int l = threadIdx.x;
  __shared__ float qs[64];
  __shared__ float pl[1024];
  qs[l] = qc[(size_t)ib*512 + h*64 + l];
  __syncthreads();
  float lmax = -1e30f;
  for (int jj=0; jj<16; jj++){
    int j = jj*64 + l;
    const short* kr = kv + ((size_t)(sib*1056 + 1 + j))*1024 + h*64;
    float acc = 0.f;
    for (int d=0; d<64; d++) acc += qs[d]*bf2f(kr[d]);
    acc *= 0.125f;
    pl[j] = acc;
    lmax = fmaxf(lmax, acc);
  }
  #pragma unroll
  for (int m=1;m<64;m<<=1) lmax = fmaxf(lmax, __shfl_xor(lmax, m));
  __syncthreads();
  float lsum = 0.f;
  for (int jj=0; jj<16; jj++){
    int j = jj*64 + l;
    float p = __expf(pl[j] - lmax);
    pl[j] = p; lsum += p;
  }
  #pragma unroll
  for (int m=1;m<64;m<<=1) lsum += __shfl_xor(lsum, m);
  __syncthreads();
  float acc = 0.f;
  for (int j=0;j<1024;j++)
    acc += pl[j] * bf2f(kv[((size_t)(sib*1056 + 1 + j))*1024 + 512 + h*64 + l]);
  oc[(size_t)ib*512 + h*64 + l] = acc / lsum;
}

__global__ __launch_bounds__(256)
void k_cross_out(const float* __restrict__ x, const float* __restrict__ oc,
                 const float* __restrict__ Wo, float* __restrict__ cn)
{
  __shared__ float os[512];
  int ib = blockIdx.x;
  for (int e=threadIdx.x;e<512;e+=256) os[e] = oc[(size_t)ib*512+e];
  __syncthreads();
  for (int n=threadIdx.x;n<512;n+=256){
    float acc = 0.f;
    for (int k=0;k<512;k++) acc += os[k]*Wo[(size_t)k*512+n];
    cn[(size_t)ib*512+n] = x[(size_t)ib*1056*512 + n] + acc;
  }
}

__global__ __launch_bounds__(256)
void k_final(const float* __restrict__ cn, const float* __restrict__ nfg, const float* __restrict__ nfb,
             const float* __restrict__ Wdec, const float* __restrict__ bdec, float* __restrict__ out)
{
  int b = blockIdx.x;
  __shared__ float a[512];
  __shared__ float an[512];
  __shared__ float red[8];
  int tid = threadIdx.x;
  float s = 0.f, q = 0.f;
  for (int e=tid;e<512;e+=256){
    float av = 0.5f*(cn[(size_t)b*512 + e] + cn[(size_t)(8+b)*512 + e]);
    a[e] = av; s += av; q += av*av;
  }
  #pragma unroll
  for (int m=1;m<64;m<<=1){ s += __shfl_xor(s,m); q += __shfl_xor(q,m); }
  int w = tid>>6;
  if ((tid&63)==0){ red[w] = s; red[4+w] = q; }
  __syncthreads();
  s = red[0]+red[1]+red[2]+red[3];
  q = red[4]+red[5]+red[6]+red[7];
  float mu = s*0.001953125f;
  float var = q*0.001953125f - mu*mu;
  float rstd = rsqrtf(var + 1e-6f);
  for (int e=tid;e<512;e+=256) an[e] = nfg[e]*(a[e]-mu)*rstd + nfb[e];
  __syncthreads();
  for (int n=tid;n<1024;n+=256){
    float acc = bdec[n];
    for (int e=0;e<512;e++) acc += an[e]*Wdec[(size_t)e*1024 + n];
    out[(size_t)b*1024 + n] = acc;
  }
}

// =======================================================================
extern "C" void kernel_launch(void* const* d_in, const int* in_sizes, int n_in,
                              void* d_out, int out_size, void* d_ws, size_t ws_size,
                              hipStream_t stream)
{
  (void)in_sizes; (void)n_in;
  const float* img1 = (const float*)d_in[0];
  const float* img2 = (const float*)d_in[1];
  const float* patchW = (const float*)d_in[2];
  const float* cls_t = (const float*)d_in[3];
  const float* cls_p = (const float*)d_in[4];
  const float* ln1g = (const float*)d_in[5];
  const float* ln1b = (const float*)d_in[6];
  const float* Wqkv = (const float*)d_in[7];
  const float* Wo   = (const float*)d_in[8];
  const float* ln2g = (const float*)d_in[9];
  const float* ln2b = (const float*)d_in[10];
  const float* W1   = (const float*)d_in[11];
  const float* b1   = (const float*)d_in[12];
  const float* W2   = (const float*)d_in[13];
  const float* b2   = (const float*)d_in[14];
  const float* Wqc  = (const float*)d_in[15];
  const float* Wkvc = (const float*)d_in[16];
  const float* Woc  = (const float*)d_in[17];
  const float* nfg  = (const float*)d_in[18];
  const float* nfb  = (const float*)d_in[19];
  const float* Wdec = (const float*)d_in[20];
  const float* bdec = (const float*)d_in[21];
  float* out = (float*)d_out;

  // ---- compact aliased workspace layout (bytes) ----
  // [0, 34.6M)   x    f32 [16896][512]
  // [A, +17.3M)  y    bf16 [16896][512]        (also reused as attn output)
  // [B, +69.2M)  pool: {patches[16384][768]bf16 ; pe[1024][512]f32}  OR
  //                    {qkv[16896][1536]bf16 ; vT[16][512][1056]bf16} OR
  //                    {mh[16896][2048]bf16}  OR  {kv_cross[16896][1024]bf16}
  // [C, +27.0M)  wts  bf16 (transposed weights)
  // [D, ...)     qc/oc/cn f32 (16x512 each)
  const size_t offA = 34603008, offB = 51904512, offC = 121110528, offD = 148111360;
  const size_t NEEDED = 148209664;
  if (ws_size < NEEDED){
    // diagnostic fallback: report ws too small as a clean absmax failure, not a fault
    hipMemsetAsync(d_out, 0, (size_t)out_size*sizeof(float), stream);
    return;
  }
  char* ws = (char*)d_ws;
  float* x    = (float*)ws;
  short* y    = (short*)(ws + offA);
  short* attn = y;
  short* qkv  = (short*)(ws + offB);
  short* vT   = (short*)(ws + offB + 51904512);
  short* mh   = (short*)(ws + offB);
  short* patches = (short*)(ws + offB);
  float* pe   = (float*)(ws + offB + 25165824);
  short* kvc  = (short*)(ws + offB);
  short* wts  = (short*)(ws + offC);
  float* qc   = (float*)(ws + offD);
  float* oc   = (float*)(ws + offD + 32768);
  float* cn   = (float*)(ws + offD + 65536);

  short* patchWt = wts;              // [512][768]
  short* WqkvT = wts + 393216;       // 4 x [1536][512]
  short* WoT   = wts + 3538944;      // 4 x [512][512]
  short* W1T   = wts + 4587520;      // 4 x [2048][512]
  short* W2T   = wts + 8781824;      // 4 x [512][2048]
  short* WkvT  = wts + 12976128;     // [1024][512]

  dim3 tb(32,8,1);
  k_transpose<<<dim3(16,24,1), tb, 0, stream>>>(patchW, patchWt, 768, 512, (size_t)768*512);
  k_transpose<<<dim3(48,16,4), tb, 0, stream>>>(Wqkv, WqkvT, 512, 1536, (size_t)512*1536);
  k_transpose<<<dim3(16,16,4), tb, 0, stream>>>(Wo,   WoT,   512, 512,  (size_t)512*512);
  k_transpose<<<dim3(64,16,4), tb, 0, stream>>>(W1,   W1T,   512, 2048, (size_t)512*2048);
  k_transpose<<<dim3(16,64,4), tb, 0, stream>>>(W2,   W2T,   2048, 512, (size_t)2048*512);
  k_transpose<<<dim3(32,16,1), tb, 0, stream>>>(Wkvc, WkvT,  512, 1024, (size_t)512*1024);  // FIXED grid

  k_pe<<<1024, 256, 0, stream>>>(pe);
  k_gather<<<16384, 256, 0, stream>>>(img1, img2, patches);
  k_zeropad<<<496, 512, 0, stream>>>(x);
  k_cls<<<16, 512, 0, stream>>>(cls_t, cls_p, x);

  EpiArgs ea;
  // patch embedding: x[:,1:1025,:] = patches @ patchW + pe
  ea = EpiArgs{nullptr, x, nullptr, pe, nullptr};
  k_gemm<4><<<dim3(4, 128), 256, 0, stream>>>(patches, patchWt, 16384, 512, 768, ea);

  for (int i=0;i<4;i++){
    k_layernorm<<<4224, 256, 0, stream>>>(x, y, ln1g + i*512, ln1b + i*512);
    ea = EpiArgs{qkv, nullptr, nullptr, nullptr, vT};
    k_gemm<1><<<dim3(12, 132), 256, 0, stream>>>(y, WqkvT + (size_t)i*1536*512, 16896, 1536, 512, ea);
    k_attn<<<dim3(33, 128), 64, 0, stream>>>(qkv, vT, attn);
    ea = EpiArgs{nullptr, x, nullptr, nullptr, nullptr};
    k_gemm<2><<<dim3(4, 132), 256, 0, stream>>>(attn, WoT + (size_t)i*512*512, 16896, 512, 512, ea);
    k_layernorm<<<4224, 256, 0, stream>>>(x, y, ln2g + i*512, ln2b + i*512);
    ea = EpiArgs{mh, nullptr, b1 + i*2048, nullptr, nullptr};
    k_gemm<3><<<dim3(16, 132), 256, 0, stream>>>(y, W1T + (size_t)i*2048*512, 16896, 2048, 512, ea);
    ea = EpiArgs{nullptr, x, b2 + i*512, nullptr, nullptr};
    k_gemm<2><<<dim3(4, 132), 256, 0, stream>>>(mh, W2T + (size_t)i*512*2048, 16896, 512, 2048, ea);
  }

  // cross attention between cls tokens and the other image's tokens
  k_cast_bf16<<<4224, 256, 0, stream>>>(x, y);
  ea = EpiArgs{kvc, nullptr, nullptr, nullptr, nullptr};
  k_gemm<0><<<dim3(8, 132), 256, 0, stream>>>(y, WkvT, 16896, 1024, 512, ea);
  k_cross_q<<<16, 256, 0, stream>>>(x, Wqc, qc);
  k_cross_attn<<<128, 64, 0, stream>>>(qc, kvc, oc);
  k_cross_out<<<16, 256, 0, stream>>>(x, oc, Woc, cn);
  k_final<<<8, 256, 0, stream>>>(cn, nfg, nfb, Wdec, bdec, out);
}

// Round 3
// 2035.019 us; speedup vs baseline: 1.1845x; 1.1845x over previous
//
#include <hip/hip_runtime.h>
#include <stdint.h>
#include <math.h>

typedef __attribute__((ext_vector_type(4))) float f4;
typedef __attribute__((ext_vector_type(8))) __bf16 bf8;
typedef __attribute__((ext_vector_type(8))) short s8;

#define DI __device__ __forceinline__

DI short f2bf(float f){
  union { float f; uint32_t u; } v; v.f = f;
  uint32_t r = v.u + 0x7fffu + ((v.u >> 16) & 1u);
  return (short)(r >> 16);
}
DI float bf2f(short s){
  union { uint32_t u; float f; } v; v.u = ((uint32_t)(uint16_t)s) << 16;
  return v.f;
}
DI uint32_t pk2(float a, float b){
  return (uint32_t)(uint16_t)f2bf(a) | ((uint32_t)(uint16_t)f2bf(b) << 16);
}
DI float gelu_f(float u){
  return 0.5f*u*(1.f + tanhf(0.7978845608028654f*(u + 0.044715f*u*u*u)));
}
DI void gload16(const void* g, void* l){
  __builtin_amdgcn_global_load_lds((const __attribute__((address_space(1))) unsigned*)g,
                                   (__attribute__((address_space(3))) unsigned*)l, 16, 0, 0);
}

// ---------------- transpose + f32->bf16 convert: in [K][N] f32 -> out [N][K] bf16
// launch grid = (N/32, K/32, z)
__global__ __launch_bounds__(256)
void k_transpose(const float* __restrict__ in, short* __restrict__ out, int K, int N, size_t stride)
{
  __shared__ float t[32][33];
  in  += (size_t)blockIdx.z * stride;
  out += (size_t)blockIdx.z * stride;
  int n0 = blockIdx.x*32, k0 = blockIdx.y*32;
  int tx = threadIdx.x, ty = threadIdx.y;
  #pragma unroll
  for (int i=0;i<32;i+=8) t[ty+i][tx] = in[(size_t)(k0+ty+i)*N + n0+tx];
  __syncthreads();
  #pragma unroll
  for (int i=0;i<32;i+=8) out[(size_t)(n0+ty+i)*K + k0+tx] = f2bf(t[tx][ty+i]);
}

// ---------------- sinusoidal positional table pe[1024][512] f32
__global__ void k_pe(float* __restrict__ pe)
{
  int p = blockIdx.x;
  for (int d = threadIdx.x; d < 512; d += 256){
    int j = (d < 256) ? d : d - 256;
    float div = expf((float)(2*j) * (-9.210340371976184f/512.f));
    float a = (float)p * div;
    pe[(size_t)p*512 + d] = (d < 256) ? sinf(a) : cosf(a);
  }
}

// ---------------- patch gather: img NHWC f32 -> patches[16384][768] bf16
__global__ __launch_bounds__(256)
void k_gather(const float* __restrict__ img1, const float* __restrict__ img2, short* __restrict__ patches)
{
  int row = blockIdx.x;              // (img*8 + b)*1024 + p
  int img = row >> 13;
  int b   = (row >> 10) & 7;
  int p   = row & 1023;
  int ph = p >> 5, pw = p & 31;
  const float* src = (img ? img2 : img1) + (size_t)b*512*512*3;
  short* dst = patches + (size_t)row*768;
  for (int k = threadIdx.x; k < 768; k += 256){
    int i = k / 48; int rem = k - i*48; int j = rem / 3; int c = rem - j*3;
    int yy = ph*16 + i, xx = pw*16 + j;
    dst[k] = f2bf(src[((size_t)yy*512 + xx)*3 + c]);
  }
}

// ---------------- zero pad token rows of x, set cls rows
__global__ void k_zeropad(float* __restrict__ x)
{
  int idx = blockIdx.x; int ib = idx / 31; int t = 1025 + (idx - ib*31);
  x[((size_t)ib*1056 + t)*512 + threadIdx.x] = 0.f;
}
__global__ void k_cls(const float* __restrict__ ct, const float* __restrict__ cp, float* __restrict__ x)
{
  int ib = blockIdx.x; int e = threadIdx.x;
  x[(size_t)ib*1056*512 + e] = ct[e] + cp[e];
}

// ---------------- layernorm rows of x (fp32) -> y (bf16). 4 rows/block, 1 wave per row.
__global__ __launch_bounds__(256)
void k_layernorm(const float* __restrict__ x, short* __restrict__ y,
                 const float* __restrict__ g, const float* __restrict__ b)
{
  int row = blockIdx.x*4 + (threadIdx.x>>6);
  int l = threadIdx.x & 63;
  const float* xr = x + (size_t)row*512 + l*8;
  f4 v0 = *(const f4*)xr;
  f4 v1 = *(const f4*)(xr+4);
  float s = v0[0]+v0[1]+v0[2]+v0[3]+v1[0]+v1[1]+v1[2]+v1[3];
  float q = v0[0]*v0[0]+v0[1]*v0[1]+v0[2]*v0[2]+v0[3]*v0[3]
          + v1[0]*v1[0]+v1[1]*v1[1]+v1[2]*v1[2]+v1[3]*v1[3];
  #pragma unroll
  for (int m=1;m<64;m<<=1){ s += __shfl_xor(s,m); q += __shfl_xor(q,m); }
  float mu = s * 0.001953125f;
  float var = q * 0.001953125f - mu*mu;
  float rstd = rsqrtf(var + 1e-6f);
  const float* gp = g + l*8;
  const float* bp = b + l*8;
  s8 ov;
  #pragma unroll
  for (int j=0;j<8;j++){
    float xv = (j<4) ? v0[j] : v1[j-4];
    ov[j] = f2bf(gp[j]*(xv-mu)*rstd + bp[j]);
  }
  *(s8*)(y + (size_t)row*512 + l*8) = ov;
}

// ---------------- straight f32 -> bf16 cast (8 elems/thread)
__global__ void k_cast_bf16(const float* __restrict__ in, short* __restrict__ out)
{
  size_t i = (size_t)blockIdx.x*256 + threadIdx.x;
  const float* p = in + i*8;
  s8 ov;
  #pragma unroll
  for (int j=0;j<8;j++) ov[j] = f2bf(p[j]);
  *(s8*)(out + i*8) = ov;
}

// ---------------- bf16 MFMA GEMM, 128x128 tile, BK=32, A[M][K], Bt[N][K]
// EPI: 0=bf16 out, 1=bf16 out + vT scatter (QKV), 2=f32 residual add (+bias), 3=bias+gelu->bf16, 4=embed(+pe)->x
struct EpiArgs { short* outb; float* outf; const float* bias; const float* pe; short* vT; };

template<int EPI>
__global__ __launch_bounds__(256)
void k_gemm(const short* __restrict__ A, const short* __restrict__ Bt,
            int M, int N, int K, EpiArgs ea)
{
  __shared__ short Al[128*32];
  __shared__ short Bl[128*32];
  const int tid = threadIdx.x;
  const int l = tid & 63;
  const int w = tid >> 6;
  const int wr = (w >> 1) * 64, wc = (w & 1) * 64;
  const int lr = l & 15, lg = l >> 4;
  const int brow = blockIdx.y * 128, bcol = blockIdx.x * 128;
  const short* Ab = A  + (size_t)brow * K;
  const short* Bb = Bt + (size_t)bcol * K;
  f4 acc[4][4];
  #pragma unroll
  for (int m=0;m<4;m++)
    #pragma unroll
    for (int n=0;n<4;n++){ acc[m][n][0]=0.f; acc[m][n][1]=0.f; acc[m][n][2]=0.f; acc[m][n][3]=0.f; }

  const int c0 = tid, c1 = tid + 256;
  const int r0 = c0>>2, cc0 = (c0&3)*8;
  const int r1 = c1>>2, cc1 = (c1&3)*8;
  for (int kt = 0; kt < K; kt += 32){
    gload16(Ab + (size_t)r0*K + kt + cc0, &Al[c0*8]);
    gload16(Ab + (size_t)r1*K + kt + cc1, &Al[c1*8]);
    gload16(Bb + (size_t)r0*K + kt + cc0, &Bl[c0*8]);
    gload16(Bb + (size_t)r1*K + kt + cc1, &Bl[c1*8]);
    __syncthreads();
    bf8 af[4], bfr[4];
    #pragma unroll
    for (int m=0;m<4;m++) af[m]  = *(const bf8*)&Al[(wr + m*16 + lr)*32 + lg*8];
    #pragma unroll
    for (int n=0;n<4;n++) bfr[n] = *(const bf8*)&Bl[(wc + n*16 + lr)*32 + lg*8];
    #pragma unroll
    for (int m=0;m<4;m++)
      #pragma unroll
      for (int n=0;n<4;n++)
        acc[m][n] = __builtin_amdgcn_mfma_f32_16x16x32_bf16(af[m], bfr[n], acc[m][n], 0, 0, 0);
    __syncthreads();
  }
  #pragma unroll
  for (int m=0;m<4;m++){
    #pragma unroll
    for (int n=0;n<4;n++){
      #pragma unroll
      for (int r=0;r<4;r++){
        int row = brow + wr + m*16 + lg*4 + r;
        int col = bcol + wc + n*16 + lr;
        float v = acc[m][n][r];
        if (EPI == 0){
          ea.outb[(size_t)row*N + col] = f2bf(v);
        } else if (EPI == 1){
          ea.outb[(size_t)row*N + col] = f2bf(v);
          if (col >= 1024){
            int ib = row / 1056, t = row - ib*1056;
            ea.vT[((size_t)ib*512 + (col - 1024))*1056 + t] = f2bf(v);
          }
        } else if (EPI == 2){
          float bv = ea.bias ? ea.bias[col] : 0.f;
          ea.outf[(size_t)row*N + col] += v + bv;
        } else if (EPI == 3){
          ea.outb[(size_t)row*N + col] = f2bf(gelu_f(v + ea.bias[col]));
        } else if (EPI == 4){
          int ib = row >> 10, p = row & 1023;
          ea.outf[((size_t)(ib*1056 + 1 + p))*512 + col] = v + ea.pe[(size_t)p*512 + col];
        }
      }
    }
  }
}

// ---------------- fused self-attention v2: swapped QK^T, in-register softmax.
// 4 independent waves per block, 1 wave = one 32-row q-tile. No barriers.
// qkv [16896][1536] bf16 (q|k|v), vT [16][512][1056] bf16, out attn [16896][512] bf16
__global__ __launch_bounds__(256)
void k_attn(const short* __restrict__ qkv, const short* __restrict__ vT, short* __restrict__ aout)
{
  // per-wave double-buffered P (32 rows x 40-short stride) and scale buffers
  __shared__ short Pl[4][2][32*40];
  __shared__ float Sc[4][2][32];

  const int w  = threadIdx.x >> 6;
  const int qt = blockIdx.x * 4 + w;
  if (qt > 32) return;                 // no barriers in kernel -> safe early exit
  const int u  = blockIdx.y;
  const int ib = u >> 3, h = u & 7;
  const int l = threadIdx.x & 63, lr = l & 15, lg = l >> 4;
  const size_t rb = (size_t)ib * 1056;
  const int t0 = qt * 32;

  // Q fragments: qf[nq][ks] = Q[t0+nq*16+lr][ks*32+lg*8 ..]
  bf8 qf[2][2];
  #pragma unroll
  for (int nq=0;nq<2;nq++)
    #pragma unroll
    for (int ks=0;ks<2;ks++)
      qf[nq][ks] = *(const bf8*)&qkv[(rb + t0 + nq*16 + lr)*1536 + h*64 + ks*32 + lg*8];

  f4 o[2][4];
  float mrun[2], lrun[2];
  #pragma unroll
  for (int mq=0;mq<2;mq++)
    #pragma unroll
    for (int nd=0;nd<4;nd++){ o[mq][nd][0]=0.f; o[mq][nd][1]=0.f; o[mq][nd][2]=0.f; o[mq][nd][3]=0.f; }
  mrun[0]=mrun[1]=-1e30f; lrun[0]=lrun[1]=0.f;

  for (int jt=0; jt<33; jt++){
    const int j0 = jt*32;
    const int pb = jt & 1;
    // K fragments (A operand): kf[mk][ks] = K[j0+mk*16+lr][ks*32+lg*8..]
    bf8 kf[2][2];
    #pragma unroll
    for (int mk=0;mk<2;mk++)
      #pragma unroll
      for (int ks=0;ks<2;ks++)
        kf[mk][ks] = *(const bf8*)&qkv[(rb + j0 + mk*16 + lr)*1536 + 512 + h*64 + ks*32 + lg*8];
    // V fragments (B operand), hoisted: vb[nd] = V^T[h*64+nd*16+lr][j0+lg*8..]
    bf8 vb[4];
    #pragma unroll
    for (int nd=0;nd<4;nd++)
      vb[nd] = *(const bf8*)&vT[((size_t)ib*512 + h*64 + nd*16 + lr)*1056 + j0 + lg*8];

    // S^T = K * Q^T : row = k-token (mk), col = q-token (nq). Lane: q = nq*16+lr fixed,
    // k = j0 + mk*16 + lg*4 + r.
    f4 st[2][2];
    #pragma unroll
    for (int mk=0;mk<2;mk++)
      #pragma unroll
      for (int nq=0;nq<2;nq++){ st[mk][nq][0]=0.f; st[mk][nq][1]=0.f; st[mk][nq][2]=0.f; st[mk][nq][3]=0.f; }
    #pragma unroll
    for (int ks=0;ks<2;ks++)
      #pragma unroll
      for (int mk=0;mk<2;mk++)
        #pragma unroll
        for (int nq=0;nq<2;nq++)
          st[mk][nq] = __builtin_amdgcn_mfma_f32_16x16x32_bf16(kf[mk][ks], qf[nq][ks], st[mk][nq], 0, 0, 0);

    // in-register online softmax per q-row (q = nq*16+lr)
    #pragma unroll
    for (int nq=0;nq<2;nq++){
      float p8[8];
      float mx = -1e30f;
      #pragma unroll
      for (int mk=0;mk<2;mk++)
        #pragma unroll
        for (int r=0;r<4;r++){
          int kk = j0 + mk*16 + lg*4 + r;
          float v = (kk > 1024) ? -1e30f : st[mk][nq][r]*0.125f;
          p8[mk*4+r] = v;
          mx = fmaxf(mx, v);
        }
      mx = fmaxf(mx, __shfl_xor(mx, 16));
      mx = fmaxf(mx, __shfl_xor(mx, 32));
      float mn = fmaxf(mrun[nq], mx);
      float sc = __expf(mrun[nq] - mn);
      mrun[nq] = mn;
      float rs = 0.f;
      #pragma unroll
      for (int i=0;i<8;i++){ p8[i] = __expf(p8[i] - mn); rs += p8[i]; }
      rs += __shfl_xor(rs, 16);
      rs += __shfl_xor(rs, 32);
      lrun[nq] = lrun[nq]*sc + rs;
      Sc[w][pb][nq*16 + lr] = sc;
      uint32_t* prow = (uint32_t*)&Pl[w][pb][(nq*16 + lr)*40];
      #pragma unroll
      for (int mk=0;mk<2;mk++){
        prow[mk*8 + lg*2]     = pk2(p8[mk*4+0], p8[mk*4+1]);
        prow[mk*8 + lg*2 + 1] = pk2(p8[mk*4+2], p8[mk*4+3]);
      }
    }

    asm volatile("s_waitcnt lgkmcnt(0)" ::: "memory");
    __builtin_amdgcn_sched_barrier(0);

    // read back rescale (per o-row q = mq*16+lg*4+r) and P as A-fragments
    f4 scv[2]; bf8 pa[2];
    #pragma unroll
    for (int mq=0;mq<2;mq++){
      scv[mq] = *(const f4*)&Sc[w][pb][mq*16 + lg*4];
      pa[mq]  = *(const bf8*)&Pl[w][pb][(mq*16 + lr)*40 + lg*8];
    }
    #pragma unroll
    for (int mq=0;mq<2;mq++)
      #pragma unroll
      for (int nd=0;nd<4;nd++){
        #pragma unroll
        for (int r=0;r<4;r++) o[mq][nd][r] *= scv[mq][r];
      }
    #pragma unroll
    for (int mq=0;mq<2;mq++)
      #pragma unroll
      for (int nd=0;nd<4;nd++)
        o[mq][nd] = __builtin_amdgcn_mfma_f32_16x16x32_bf16(pa[mq], vb[nd], o[mq][nd], 0, 0, 0);
  }

  // final 1/l normalization: route lrun (per q=nq*16+lr) to o-rows (q=mq*16+lg*4+r)
  #pragma unroll
  for (int nq=0;nq<2;nq++) Sc[w][1][nq*16 + lr] = lrun[nq];
  asm volatile("s_waitcnt lgkmcnt(0)" ::: "memory");
  __builtin_amdgcn_sched_barrier(0);
  f4 lsv[2];
  #pragma unroll
  for (int mq=0;mq<2;mq++) lsv[mq] = *(const f4*)&Sc[w][1][mq*16 + lg*4];
  #pragma unroll
  for (int mq=0;mq<2;mq++)
    #pragma unroll
    for (int nd=0;nd<4;nd++)
      #pragma unroll
      for (int r=0;r<4;r++){
        int t = t0 + mq*16 + lg*4 + r;
        int col = h*64 + nd*16 + lr;
        aout[(rb + t)*512 + col] = f2bf(o[mq][nd][r] / lsv[mq][r]);
      }
}

// ---------------- cross-attention path (tiny, fp32)
__global__ __launch_bounds__(256)
void k_cross_q(const float* __restrict__ x, const float* __restrict__ Wq, float* __restrict__ qc)
{
  __shared__ float xs[512];
  int ib = blockIdx.x;
  const float* xr = x + (size_t)ib*1056*512;
  for (int e=threadIdx.x;e<512;e+=256) xs[e] = xr[e];
  __syncthreads();
  for (int n=threadIdx.x;n<512;n+=256){
    float acc = 0.f;
    for (int k=0;k<512;k++) acc += xs[k]*Wq[(size_t)k*512 + n];
    qc[(size_t)ib*512 + n] = acc;
  }
}

__global__ __launch_bounds__(64)
void k_cross_attn(const float* __restrict__ qc, const short* __restrict__ kv, float* __restrict__ oc)
{
  int u = blockIdx.x; int ib = u >> 3, h = u & 7;
  int img = ib >> 3, b = ib & 7;
  int sib = (1 - img)*8 + b;
  int l = threadIdx.x;
  __shared__ float qs[64];
  __shared__ float pl[1024];
  qs[l] = qc[(size_t)ib*512 + h*64 + l];
  __syncthreads();
  float lmax = -1e30f;
  for (int jj=0; jj<16; jj++){
    int j = jj*64 + l;
    const short* kr = kv + ((size_t)(sib*1056 + 1 + j))*1024 + h*64;
    float acc = 0.f;
    for (int d=0; d<64; d++) acc += qs[d]*bf2f(kr[d]);
    acc *= 0.125f;
    pl[j] = acc;
    lmax = fmaxf(lmax, acc);
  }
  #pragma unroll
  for (int m=1;m<64;m<<=1) lmax = fmaxf(lmax, __shfl_xor(lmax, m));
  __syncthreads();
  float lsum = 0.f;
  for (int jj=0; jj<16; jj++){
    int j = jj*64 + l;
    float p = __expf(pl[j] - lmax);
    pl[j] = p; lsum += p;
  }
  #pragma unroll
  for (int m=1;m<64;m<<=1) lsum += __shfl_xor(lsum, m);
  __syncthreads();
  float acc = 0.f;
  for (int j=0;j<1024;j++)
    acc += pl[j] * bf2f(kv[((size_t)(sib*1056 + 1 + j))*1024 + 512 + h*64 + l]);
  oc[(size_t)ib*512 + h*64 + l] = acc / lsum;
}

__global__ __launch_bounds__(256)
void k_cross_out(const float* __restrict__ x, const float* __restrict__ oc,
                 const float* __restrict__ Wo, float* __restrict__ cn)
{
  __shared__ float os[512];
  int ib = blockIdx.x;
  for (int e=threadIdx.x;e<512;e+=256) os[e] = oc[(size_t)ib*512+e];
  __syncthreads();
  for (int n=threadIdx.x;n<512;n+=256){
    float acc = 0.f;
    for (int k=0;k<512;k++) acc += os[k]*Wo[(size_t)k*512+n];
    cn[(size_t)ib*512+n] = x[(size_t)ib*1056*512 + n] + acc;
  }
}

__global__ __launch_bounds__(256)
void k_final(const float* __restrict__ cn, const float* __restrict__ nfg, const float* __restrict__ nfb,
             const float* __restrict__ Wdec, const float* __restrict__ bdec, float* __restrict__ out)
{
  int b = blockIdx.x;
  __shared__ float a[512];
  __shared__ float an[512];
  __shared__ float red[8];
  int tid = threadIdx.x;
  float s = 0.f, q = 0.f;
  for (int e=tid;e<512;e+=256){
    float av = 0.5f*(cn[(size_t)b*512 + e] + cn[(size_t)(8+b)*512 + e]);
    a[e] = av; s += av; q += av*av;
  }
  #pragma unroll
  for (int m=1;m<64;m<<=1){ s += __shfl_xor(s,m); q += __shfl_xor(q,m); }
  int w = tid>>6;
  if ((tid&63)==0){ red[w] = s; red[4+w] = q; }
  __syncthreads();
  s = red[0]+red[1]+red[2]+red[3];
  q = red[4]+red[5]+red[6]+red[7];
  float mu = s*0.001953125f;
  float var = q*0.001953125f - mu*mu;
  float rstd = rsqrtf(var + 1e-6f);
  for (int e=tid;e<512;e+=256) an[e] = nfg[e]*(a[e]-mu)*rstd + nfb[e];
  __syncthreads();
  for (int n=tid;n<1024;n+=256){
    float acc = bdec[n];
    for (int e=0;e<512;e++) acc += an[e]*Wdec[(size_t)e*1024 + n];
    out[(size_t)b*1024 + n] = acc;
  }
}

// =======================================================================
extern "C" void kernel_launch(void* const* d_in, const int* in_sizes, int n_in,
                              void* d_out, int out_size, void* d_ws, size_t ws_size,
                              hipStream_t stream)
{
  (void)in_sizes; (void)n_in;
  const float* img1 = (const float*)d_in[0];
  const float* img2 = (const float*)d_in[1];
  const float* patchW = (const float*)d_in[2];
  const float* cls_t = (const float*)d_in[3];
  const float* cls_p = (const float*)d_in[4];
  const float* ln1g = (const float*)d_in[5];
  const float* ln1b = (const float*)d_in[6];
  const float* Wqkv = (const float*)d_in[7];
  const float* Wo   = (const float*)d_in[8];
  const float* ln2g = (const float*)d_in[9];
  const float* ln2b = (const float*)d_in[10];
  const float* W1   = (const float*)d_in[11];
  const float* b1   = (const float*)d_in[12];
  const float* W2   = (const float*)d_in[13];
  const float* b2   = (const float*)d_in[14];
  const float* Wqc  = (const float*)d_in[15];
  const float* Wkvc = (const float*)d_in[16];
  const float* Woc  = (const float*)d_in[17];
  const float* nfg  = (const float*)d_in[18];
  const float* nfb  = (const float*)d_in[19];
  const float* Wdec = (const float*)d_in[20];
  const float* bdec = (const float*)d_in[21];
  float* out = (float*)d_out;

  // ---- compact aliased workspace layout (bytes) ----
  const size_t offA = 34603008, offB = 51904512, offC = 121110528, offD = 148111360;
  const size_t NEEDED = 148209664;
  if (ws_size < NEEDED){
    hipMemsetAsync(d_out, 0, (size_t)out_size*sizeof(float), stream);
    return;
  }
  char* ws = (char*)d_ws;
  float* x    = (float*)ws;
  short* y    = (short*)(ws + offA);
  short* attn = y;
  short* qkv  = (short*)(ws + offB);
  short* vT   = (short*)(ws + offB + 51904512);
  short* mh   = (short*)(ws + offB);
  short* patches = (short*)(ws + offB);
  float* pe   = (float*)(ws + offB + 25165824);
  short* kvc  = (short*)(ws + offB);
  short* wts  = (short*)(ws + offC);
  float* qc   = (float*)(ws + offD);
  float* oc   = (float*)(ws + offD + 32768);
  float* cn   = (float*)(ws + offD + 65536);

  short* patchWt = wts;              // [512][768]
  short* WqkvT = wts + 393216;       // 4 x [1536][512]
  short* WoT   = wts + 3538944;      // 4 x [512][512]
  short* W1T   = wts + 4587520;      // 4 x [2048][512]
  short* W2T   = wts + 8781824;      // 4 x [512][2048]
  short* WkvT  = wts + 12976128;     // [1024][512]

  dim3 tb(32,8,1);
  k_transpose<<<dim3(16,24,1), tb, 0, stream>>>(patchW, patchWt, 768, 512, (size_t)768*512);
  k_transpose<<<dim3(48,16,4), tb, 0, stream>>>(Wqkv, WqkvT, 512, 1536, (size_t)512*1536);
  k_transpose<<<dim3(16,16,4), tb, 0, stream>>>(Wo,   WoT,   512, 512,  (size_t)512*512);
  k_transpose<<<dim3(64,16,4), tb, 0, stream>>>(W1,   W1T,   512, 2048, (size_t)512*2048);
  k_transpose<<<dim3(16,64,4), tb, 0, stream>>>(W2,   W2T,   2048, 512, (size_t)2048*512);
  k_transpose<<<dim3(32,16,1), tb, 0, stream>>>(Wkvc, WkvT,  512, 1024, (size_t)512*1024);

  k_pe<<<1024, 256, 0, stream>>>(pe);
  k_gather<<<16384, 256, 0, stream>>>(img1, img2, patches);
  k_zeropad<<<496, 512, 0, stream>>>(x);
  k_cls<<<16, 512, 0, stream>>>(cls_t, cls_p, x);

  EpiArgs ea;
  // patch embedding: x[:,1:1025,:] = patches @ patchW + pe
  ea = EpiArgs{nullptr, x, nullptr, pe, nullptr};
  k_gemm<4><<<dim3(4, 128), 256, 0, stream>>>(patches, patchWt, 16384, 512, 768, ea);

  for (int i=0;i<4;i++){
    k_layernorm<<<4224, 256, 0, stream>>>(x, y, ln1g + i*512, ln1b + i*512);
    ea = EpiArgs{qkv, nullptr, nullptr, nullptr, vT};
    k_gemm<1><<<dim3(12, 132), 256, 0, stream>>>(y, WqkvT + (size_t)i*1536*512, 16896, 1536, 512, ea);
    k_attn<<<dim3(9, 128), 256, 0, stream>>>(qkv, vT, attn);
    ea = EpiArgs{nullptr, x, nullptr, nullptr, nullptr};
    k_gemm<2><<<dim3(4, 132), 256, 0, stream>>>(attn, WoT + (size_t)i*512*512, 16896, 512, 512, ea);
    k_layernorm<<<4224, 256, 0, stream>>>(x, y, ln2g + i*512, ln2b + i*512);
    ea = EpiArgs{mh, nullptr, b1 + i*2048, nullptr, nullptr};
    k_gemm<3><<<dim3(16, 132), 256, 0, stream>>>(y, W1T + (size_t)i*2048*512, 16896, 2048, 512, ea);
    ea = EpiArgs{nullptr, x, b2 + i*512, nullptr, nullptr};
    k_gemm<2><<<dim3(4, 132), 256, 0, stream>>>(mh, W2T + (size_t)i*512*2048, 16896, 512, 2048, ea);
  }

  // cross attention between cls tokens and the other image's tokens
  k_cast_bf16<<<4224, 256, 0, stream>>>(x, y);
  ea = EpiArgs{kvc, nullptr, nullptr, nullptr, nullptr};
  k_gemm<0><<<dim3(8, 132), 256, 0, stream>>>(y, WkvT, 16896, 1024, 512, ea);
  k_cross_q<<<16, 256, 0, stream>>>(x, Wqc, qc);
  k_cross_attn<<<128, 64, 0, stream>>>(qc, kvc, oc);
  k_cross_out<<<16, 256, 0, stream>>>(x, oc, Woc, cn);
  k_final<<<8, 256, 0, stream>>>(cn, nfg, nfb, Wdec, bdec, out);
}

// Round 4
// 1751.263 us; speedup vs baseline: 1.3764x; 1.1620x over previous
//
#include <hip/hip_runtime.h>
#include <stdint.h>
#include <math.h>

typedef __attribute__((ext_vector_type(4))) float f4;
typedef __attribute__((ext_vector_type(8))) __bf16 bf8;
typedef __attribute__((ext_vector_type(8))) short s8;
typedef __attribute__((ext_vector_type(4))) uint32_t u32x4;

#define DI __device__ __forceinline__

DI short f2bf(float f){
  union { float f; uint32_t u; } v; v.f = f;
  uint32_t r = v.u + 0x7fffu + ((v.u >> 16) & 1u);
  return (short)(r >> 16);
}
DI float bf2f(short s){
  union { uint32_t u; float f; } v; v.u = ((uint32_t)(uint16_t)s) << 16;
  return v.f;
}
// packed f32x2 -> bf16x2 (RNE), lo = first arg
DI uint32_t cvtpk(float lo, float hi){
  uint32_t r;
  asm("v_cvt_pk_bf16_f32 %0, %1, %2" : "=v"(r) : "v"(lo), "v"(hi));
  return r;
}
// gelu-tanh == u * sigmoid(2c(u + 0.044715 u^3)), c = 0.7978845608
DI float gelu_f(float u){
  float z = 1.5957691216057308f * u * fmaf(0.044715f, u*u, 1.f);
  return u * __builtin_amdgcn_rcpf(1.f + __expf(-z));
}
DI void gload16(const void* g, void* l){
  __builtin_amdgcn_global_load_lds((const __attribute__((address_space(1))) unsigned*)g,
                                   (__attribute__((address_space(3))) unsigned*)l, 16, 0, 0);
}

// ---------------- transpose + f32->bf16 convert: in [K][N] f32 -> out [N][K] bf16
// launch grid = (N/32, K/32, z)
__global__ __launch_bounds__(256)
void k_transpose(const float* __restrict__ in, short* __restrict__ out, int K, int N, size_t stride)
{
  __shared__ float t[32][33];
  in  += (size_t)blockIdx.z * stride;
  out += (size_t)blockIdx.z * stride;
  int n0 = blockIdx.x*32, k0 = blockIdx.y*32;
  int tx = threadIdx.x, ty = threadIdx.y;
  #pragma unroll
  for (int i=0;i<32;i+=8) t[ty+i][tx] = in[(size_t)(k0+ty+i)*N + n0+tx];
  __syncthreads();
  #pragma unroll
  for (int i=0;i<32;i+=8) out[(size_t)(n0+ty+i)*K + k0+tx] = f2bf(t[tx][ty+i]);
}

// ---------------- sinusoidal positional table pe[1024][512] f32
__global__ void k_pe(float* __restrict__ pe)
{
  int p = blockIdx.x;
  for (int d = threadIdx.x; d < 512; d += 256){
    int j = (d < 256) ? d : d - 256;
    float div = expf((float)(2*j) * (-9.210340371976184f/512.f));
    float a = (float)p * div;
    pe[(size_t)p*512 + d] = (d < 256) ? sinf(a) : cosf(a);
  }
}

// ---------------- patch gather: img NHWC f32 -> patches[16384][768] bf16
__global__ __launch_bounds__(256)
void k_gather(const float* __restrict__ img1, const float* __restrict__ img2, short* __restrict__ patches)
{
  int row = blockIdx.x;              // (img*8 + b)*1024 + p
  int img = row >> 13;
  int b   = (row >> 10) & 7;
  int p   = row & 1023;
  int ph = p >> 5, pw = p & 31;
  const float* src = (img ? img2 : img1) + (size_t)b*512*512*3;
  short* dst = patches + (size_t)row*768;
  for (int k = threadIdx.x; k < 768; k += 256){
    int i = k / 48; int rem = k - i*48; int j = rem / 3; int c = rem - j*3;
    int yy = ph*16 + i, xx = pw*16 + j;
    dst[k] = f2bf(src[((size_t)yy*512 + xx)*3 + c]);
  }
}

// ---------------- zero pad token rows of x, set cls rows
__global__ void k_zeropad(float* __restrict__ x)
{
  int idx = blockIdx.x; int ib = idx / 31; int t = 1025 + (idx - ib*31);
  x[((size_t)ib*1056 + t)*512 + threadIdx.x] = 0.f;
}
__global__ void k_cls(const float* __restrict__ ct, const float* __restrict__ cp, float* __restrict__ x)
{
  int ib = blockIdx.x; int e = threadIdx.x;
  x[(size_t)ib*1056*512 + e] = ct[e] + cp[e];
}

// ---------------- layernorm rows of x (fp32) -> y (bf16). 4 rows/block, 1 wave per row.
__global__ __launch_bounds__(256)
void k_layernorm(const float* __restrict__ x, short* __restrict__ y,
                 const float* __restrict__ g, const float* __restrict__ b)
{
  int row = blockIdx.x*4 + (threadIdx.x>>6);
  int l = threadIdx.x & 63;
  const float* xr = x + (size_t)row*512 + l*8;
  f4 v0 = *(const f4*)xr;
  f4 v1 = *(const f4*)(xr+4);
  float s = v0[0]+v0[1]+v0[2]+v0[3]+v1[0]+v1[1]+v1[2]+v1[3];
  float q = v0[0]*v0[0]+v0[1]*v0[1]+v0[2]*v0[2]+v0[3]*v0[3]
          + v1[0]*v1[0]+v1[1]*v1[1]+v1[2]*v1[2]+v1[3]*v1[3];
  #pragma unroll
  for (int m=1;m<64;m<<=1){ s += __shfl_xor(s,m); q += __shfl_xor(q,m); }
  float mu = s * 0.001953125f;
  float var = q * 0.001953125f - mu*mu;
  float rstd = rsqrtf(var + 1e-6f);
  const float* gp = g + l*8;
  const float* bp = b + l*8;
  float ov[8];
  #pragma unroll
  for (int j=0;j<8;j++){
    float xv = (j<4) ? v0[j] : v1[j-4];
    ov[j] = gp[j]*(xv-mu)*rstd + bp[j];
  }
  u32x4 pk;
  #pragma unroll
  for (int j=0;j<4;j++) pk[j] = cvtpk(ov[2*j], ov[2*j+1]);
  *(u32x4*)(y + (size_t)row*512 + l*8) = pk;
}

// ---------------- straight f32 -> bf16 cast (8 elems/thread)
__global__ void k_cast_bf16(const float* __restrict__ in, short* __restrict__ out)
{
  size_t i = (size_t)blockIdx.x*256 + threadIdx.x;
  const float* p = in + i*8;
  u32x4 pk;
  #pragma unroll
  for (int j=0;j<4;j++) pk[j] = cvtpk(p[2*j], p[2*j+1]);
  *(u32x4*)(out + i*8) = pk;
}

// ---------------- bf16 MFMA GEMM, 128x128 tile, BK=64, A[M][K], Bt[N][K]
// LDS XOR-swizzled (both sides: pre-swizzled global src + swizzled ds_read).
// EPI: 0=bf16 out, 1=bf16 out + q-prescale + vT scatter (QKV), 2=f32 residual add (+bias),
//      3=bias+gelu->bf16, 4=embed(+pe)->x
struct EpiArgs { short* outb; float* outf; const float* bias; const float* pe; short* vT; };

template<int EPI>
__global__ __launch_bounds__(256)
void k_gemm(const short* __restrict__ A, const short* __restrict__ Bt,
            int M, int N, int K, EpiArgs ea)
{
  __shared__ short Al[128*64];
  __shared__ short Bl[128*64];
  const int tid = threadIdx.x;
  const int l = tid & 63;
  const int w = tid >> 6;
  const int wr = (w >> 1) * 64, wc = (w & 1) * 64;
  const int lr = l & 15, lg = l >> 4;
  const int brow = blockIdx.y * 128, bcol = blockIdx.x * 128;
  const short* Ab = A  + (size_t)brow * K;
  const short* Bb = Bt + (size_t)bcol * K;
  f4 acc[4][4];
  #pragma unroll
  for (int m=0;m<4;m++)
    #pragma unroll
    for (int n=0;n<4;n++){ acc[m][n][0]=0.f; acc[m][n][1]=0.f; acc[m][n][2]=0.f; acc[m][n][3]=0.f; }

  // read-side swizzled col-slot per thread (involution: slot ^ (row&7))
  const int rsw = lr & 7;
  for (int kt = 0; kt < K; kt += 64){
    #pragma unroll
    for (int i=0;i<4;i++){
      int s   = i*256 + tid;
      int row = s >> 3;
      int gs  = (s & 7) ^ (row & 7);
      gload16(Ab + (size_t)row*K + kt + gs*8, &Al[s*8]);
      gload16(Bb + (size_t)row*K + kt + gs*8, &Bl[s*8]);
    }
    __syncthreads();
    #pragma unroll
    for (int ko=0;ko<2;ko++){
      bf8 af[4], bfr[4];
      const int ps = ((ko*4 + lg) ^ rsw) * 8;
      #pragma unroll
      for (int m=0;m<4;m++) af[m]  = *(const bf8*)&Al[(wr + m*16 + lr)*64 + ps];
      #pragma unroll
      for (int n=0;n<4;n++) bfr[n] = *(const bf8*)&Bl[(wc + n*16 + lr)*64 + ps];
      #pragma unroll
      for (int m=0;m<4;m++)
        #pragma unroll
        for (int n=0;n<4;n++)
          acc[m][n] = __builtin_amdgcn_mfma_f32_16x16x32_bf16(af[m], bfr[n], acc[m][n], 0, 0, 0);
    }
    __syncthreads();
  }

  #pragma unroll
  for (int m=0;m<4;m++){
    #pragma unroll
    for (int n=0;n<4;n++){
      const int row0 = brow + wr + m*16 + lg*4;
      const int col  = bcol + wc + n*16 + lr;
      float v0 = acc[m][n][0], v1 = acc[m][n][1], v2 = acc[m][n][2], v3 = acc[m][n][3];
      if (EPI == 0 || EPI == 1){
        if (EPI == 1 && col < 512){ v0*=0.125f; v1*=0.125f; v2*=0.125f; v3*=0.125f; }
        uint32_t u01 = cvtpk(v0, v1), u23 = cvtpk(v2, v3);
        short s0 = (short)u01, s1 = (short)(u01>>16), s2 = (short)u23, s3 = (short)(u23>>16);
        ea.outb[(size_t)(row0+0)*N + col] = s0;
        ea.outb[(size_t)(row0+1)*N + col] = s1;
        ea.outb[(size_t)(row0+2)*N + col] = s2;
        ea.outb[(size_t)(row0+3)*N + col] = s3;
        if (EPI == 1 && col >= 1024){
          int ib = row0 / 1056, t = row0 - ib*1056;
          short* vtb = ea.vT + ((size_t)ib*512 + (col - 1024))*1056;
          vtb[t] = s0; vtb[t+1] = s1; vtb[t+2] = s2; vtb[t+3] = s3;
        }
      } else if (EPI == 2){
        float bv = ea.bias ? ea.bias[col] : 0.f;
        ea.outf[(size_t)(row0+0)*N + col] += v0 + bv;
        ea.outf[(size_t)(row0+1)*N + col] += v1 + bv;
        ea.outf[(size_t)(row0+2)*N + col] += v2 + bv;
        ea.outf[(size_t)(row0+3)*N + col] += v3 + bv;
      } else if (EPI == 3){
        float bv = ea.bias[col];
        float g0 = gelu_f(v0+bv), g1 = gelu_f(v1+bv), g2 = gelu_f(v2+bv), g3 = gelu_f(v3+bv);
        uint32_t u01 = cvtpk(g0, g1), u23 = cvtpk(g2, g3);
        ea.outb[(size_t)(row0+0)*N + col] = (short)u01;
        ea.outb[(size_t)(row0+1)*N + col] = (short)(u01>>16);
        ea.outb[(size_t)(row0+2)*N + col] = (short)u23;
        ea.outb[(size_t)(row0+3)*N + col] = (short)(u23>>16);
      } else if (EPI == 4){
        #pragma unroll
        for (int r=0;r<4;r++){
          int row = row0 + r;
          int ib = row >> 10, p = row & 1023;
          float v = (r==0)?v0:(r==1)?v1:(r==2)?v2:v3;
          ea.outf[((size_t)(ib*1056 + 1 + p))*512 + col] = v + ea.pe[(size_t)p*512 + col];
        }
      }
    }
  }
}

// ---------------- fused self-attention v3: swapped QK^T, in-register softmax,
// Q pre-scaled by 1/8 in QKV epilogue, defer-max rescale skip, mask only last tile.
// 4 independent waves per block, 1 wave = one 32-row q-tile. No barriers.
__global__ __launch_bounds__(256)
void k_attn(const short* __restrict__ qkv, const short* __restrict__ vT, short* __restrict__ aout)
{
  __shared__ short Pl[4][2][32*40];
  __shared__ float Sc[4][2][32];

  const int w  = threadIdx.x >> 6;
  const int qt = blockIdx.x * 4 + w;
  if (qt > 32) return;                 // no barriers in kernel -> safe early exit
  const int u  = blockIdx.y;
  const int ib = u >> 3, h = u & 7;
  const int l = threadIdx.x & 63, lr = l & 15, lg = l >> 4;
  const size_t rb = (size_t)ib * 1056;
  const int t0 = qt * 32;

  bf8 qf[2][2];
  #pragma unroll
  for (int nq=0;nq<2;nq++)
    #pragma unroll
    for (int ks=0;ks<2;ks++)
      qf[nq][ks] = *(const bf8*)&qkv[(rb + t0 + nq*16 + lr)*1536 + h*64 + ks*32 + lg*8];

  f4 o[2][4];
  float mrun[2], lrun[2];
  #pragma unroll
  for (int mq=0;mq<2;mq++)
    #pragma unroll
    for (int nd=0;nd<4;nd++){ o[mq][nd][0]=0.f; o[mq][nd][1]=0.f; o[mq][nd][2]=0.f; o[mq][nd][3]=0.f; }
  mrun[0]=mrun[1]=-1e30f; lrun[0]=lrun[1]=0.f;

  auto tile = [&](int jt, bool MASK){
    const int j0 = jt*32;
    const int pb = jt & 1;
    bf8 kf[2][2];
    #pragma unroll
    for (int mk=0;mk<2;mk++)
      #pragma unroll
      for (int ks=0;ks<2;ks++)
        kf[mk][ks] = *(const bf8*)&qkv[(rb + j0 + mk*16 + lr)*1536 + 512 + h*64 + ks*32 + lg*8];
    bf8 vb[4];
    #pragma unroll
    for (int nd=0;nd<4;nd++)
      vb[nd] = *(const bf8*)&vT[((size_t)ib*512 + h*64 + nd*16 + lr)*1056 + j0 + lg*8];

    f4 st[2][2];
    #pragma unroll
    for (int mk=0;mk<2;mk++)
      #pragma unroll
      for (int nq=0;nq<2;nq++){ st[mk][nq][0]=0.f; st[mk][nq][1]=0.f; st[mk][nq][2]=0.f; st[mk][nq][3]=0.f; }
    #pragma unroll
    for (int ks=0;ks<2;ks++)
      #pragma unroll
      for (int mk=0;mk<2;mk++)
        #pragma unroll
        for (int nq=0;nq<2;nq++)
          st[mk][nq] = __builtin_amdgcn_mfma_f32_16x16x32_bf16(kf[mk][ks], qf[nq][ks], st[mk][nq], 0, 0, 0);

    float p8[2][8], mx[2];
    #pragma unroll
    for (int nq=0;nq<2;nq++){
      mx[nq] = -1e30f;
      #pragma unroll
      for (int mk=0;mk<2;mk++)
        #pragma unroll
        for (int r=0;r<4;r++){
          float v = st[mk][nq][r];
          if (MASK){
            int kk = j0 + mk*16 + lg*4 + r;
            v = (kk > 1024) ? -1e30f : v;
          }
          p8[nq][mk*4+r] = v;
          mx[nq] = fmaxf(mx[nq], v);
        }
      mx[nq] = fmaxf(mx[nq], __shfl_xor(mx[nq], 16));
      mx[nq] = fmaxf(mx[nq], __shfl_xor(mx[nq], 32));
    }

    bool ok = (mx[0] <= mrun[0] + 8.f) && (mx[1] <= mrun[1] + 8.f);
    if (__all(ok)){
      // defer path: no max update, no rescale
      #pragma unroll
      for (int nq=0;nq<2;nq++){
        float rs = 0.f;
        #pragma unroll
        for (int i=0;i<8;i++){ float p = __expf(p8[nq][i] - mrun[nq]); p8[nq][i] = p; rs += p; }
        rs += __shfl_xor(rs, 16);
        rs += __shfl_xor(rs, 32);
        lrun[nq] += rs;
        uint32_t* prow = (uint32_t*)&Pl[w][pb][(nq*16 + lr)*40];
        #pragma unroll
        for (int mk=0;mk<2;mk++){
          prow[mk*8 + lg*2]     = cvtpk(p8[nq][mk*4+0], p8[nq][mk*4+1]);
          prow[mk*8 + lg*2 + 1] = cvtpk(p8[nq][mk*4+2], p8[nq][mk*4+3]);
        }
      }
      asm volatile("s_waitcnt lgkmcnt(0)" ::: "memory");
      __builtin_amdgcn_sched_barrier(0);
      bf8 pa[2];
      #pragma unroll
      for (int mq=0;mq<2;mq++) pa[mq] = *(const bf8*)&Pl[w][pb][(mq*16 + lr)*40 + lg*8];
      #pragma unroll
      for (int mq=0;mq<2;mq++)
        #pragma unroll
        for (int nd=0;nd<4;nd++)
          o[mq][nd] = __builtin_amdgcn_mfma_f32_16x16x32_bf16(pa[mq], vb[nd], o[mq][nd], 0, 0, 0);
    } else {
      // full online-softmax path
      #pragma unroll
      for (int nq=0;nq<2;nq++){
        float mn = fmaxf(mrun[nq], mx[nq]);
        float sc = __expf(mrun[nq] - mn);
        mrun[nq] = mn;
        float rs = 0.f;
        #pragma unroll
        for (int i=0;i<8;i++){ float p = __expf(p8[nq][i] - mn); p8[nq][i] = p; rs += p; }
        rs += __shfl_xor(rs, 16);
        rs += __shfl_xor(rs, 32);
        lrun[nq] = lrun[nq]*sc + rs;
        Sc[w][pb][nq*16 + lr] = sc;
        uint32_t* prow = (uint32_t*)&Pl[w][pb][(nq*16 + lr)*40];
        #pragma unroll
        for (int mk=0;mk<2;mk++){
          prow[mk*8 + lg*2]     = cvtpk(p8[nq][mk*4+0], p8[nq][mk*4+1]);
          prow[mk*8 + lg*2 + 1] = cvtpk(p8[nq][mk*4+2], p8[nq][mk*4+3]);
        }
      }
      asm volatile("s_waitcnt lgkmcnt(0)" ::: "memory");
      __builtin_amdgcn_sched_barrier(0);
      f4 scv[2]; bf8 pa[2];
      #pragma unroll
      for (int mq=0;mq<2;mq++){
        scv[mq] = *(const f4*)&Sc[w][pb][mq*16 + lg*4];
        pa[mq]  = *(const bf8*)&Pl[w][pb][(mq*16 + lr)*40 + lg*8];
      }
      #pragma unroll
      for (int mq=0;mq<2;mq++)
        #pragma unroll
        for (int nd=0;nd<4;nd++){
          #pragma unroll
          for (int r=0;r<4;r++) o[mq][nd][r] *= scv[mq][r];
        }
      #pragma unroll
      for (int mq=0;mq<2;mq++)
        #pragma unroll
        for (int nd=0;nd<4;nd++)
          o[mq][nd] = __builtin_amdgcn_mfma_f32_16x16x32_bf16(pa[mq], vb[nd], o[mq][nd], 0, 0, 0);
    }
  };

  for (int jt=0; jt<32; jt++) tile(jt, false);
  tile(32, true);

  // final 1/l normalization: route lrun (per q=nq*16+lr) to o-rows (q=mq*16+lg*4+r)
  #pragma unroll
  for (int nq=0;nq<2;nq++) Sc[w][1][nq*16 + lr] = lrun[nq];
  asm volatile("s_waitcnt lgkmcnt(0)" ::: "memory");
  __builtin_amdgcn_sched_barrier(0);
  #pragma unroll
  for (int mq=0;mq<2;mq++){
    f4 lsv = *(const f4*)&Sc[w][1][mq*16 + lg*4];
    float i0 = __builtin_amdgcn_rcpf(lsv[0]);
    float i1 = __builtin_amdgcn_rcpf(lsv[1]);
    float i2 = __builtin_amdgcn_rcpf(lsv[2]);
    float i3 = __builtin_amdgcn_rcpf(lsv[3]);
    const size_t base = rb + t0 + mq*16 + lg*4;
    #pragma unroll
    for (int nd=0;nd<4;nd++){
      int col = h*64 + nd*16 + lr;
      uint32_t u01 = cvtpk(o[mq][nd][0]*i0, o[mq][nd][1]*i1);
      uint32_t u23 = cvtpk(o[mq][nd][2]*i2, o[mq][nd][3]*i3);
      aout[(base+0)*512 + col] = (short)u01;
      aout[(base+1)*512 + col] = (short)(u01>>16);
      aout[(base+2)*512 + col] = (short)u23;
      aout[(base+3)*512 + col] = (short)(u23>>16);
    }
  }
}

// ---------------- cross-attention path (tiny, fp32)
__global__ __launch_bounds__(256)
void k_cross_q(const float* __restrict__ x, const float* __restrict__ Wq, float* __restrict__ qc)
{
  __shared__ float xs[512];
  int ib = blockIdx.x;
  const float* xr = x + (size_t)ib*1056*512;
  for (int e=threadIdx.x;e<512;e+=256) xs[e] = xr[e];
  __syncthreads();
  for (int n=threadIdx.x;n<512;n+=256){
    float acc = 0.f;
    for (int k=0;k<512;k++) acc += xs[k]*Wq[(size_t)k*512 + n];
    qc[(size_t)ib*512 + n] = acc;
  }
}

__global__ __launch_bounds__(64)
void k_cross_attn(const float* __restrict__ qc, const short* __restrict__ kv, float* __restrict__ oc)
{
  int u = blockIdx.x; int ib = u >> 3, h = u & 7;
  int img = ib >> 3, b = ib & 7;
  int sib = (1 - img)*8 + b;
  int l = threadIdx.x;
  __shared__ float qs[64];
  __shared__ float pl[1024];
  qs[l] = qc[(size_t)ib*512 + h*64 + l];
  __syncthreads();
  float lmax = -1e30f;
  for (int jj=0; jj<16; jj++){
    int j = jj*64 + l;
    const short* kr = kv + ((size_t)(sib*1056 + 1 + j))*1024 + h*64;
    float acc = 0.f;
    for (int d=0; d<64; d++) acc += qs[d]*bf2f(kr[d]);
    acc *= 0.125f;
    pl[j] = acc;
    lmax = fmaxf(lmax, acc);
  }
  #pragma unroll
  for (int m=1;m<64;m<<=1) lmax = fmaxf(lmax, __shfl_xor(lmax, m));
  __syncthreads();
  float lsum = 0.f;
  for (int jj=0; jj<16; jj++){
    int j = jj*64 + l;
    float p = __expf(pl[j] - lmax);
    pl[j] = p; lsum += p;
  }
  #pragma unroll
  for (int m=1;m<64;m<<=1) lsum += __shfl_xor(lsum, m);
  __syncthreads();
  float acc = 0.f;
  for (int j=0;j<1024;j++)
    acc += pl[j] * bf2f(kv[((size_t)(sib*1056 + 1 + j))*1024 + 512 + h*64 + l]);
  oc[(size_t)ib*512 + h*64 + l] = acc / lsum;
}

__global__ __launch_bounds__(256)
void k_cross_out(const float* __restrict__ x, const float* __restrict__ oc,
                 const float* __restrict__ Wo, float* __restrict__ cn)
{
  __shared__ float os[512];
  int ib = blockIdx.x;
  for (int e=threadIdx.x;e<512;e+=256) os[e] = oc[(size_t)ib*512+e];
  __syncthreads();
  for (int n=threadIdx.x;n<512;n+=256){
    float acc = 0.f;
    for (int k=0;k<512;k++) acc += os[k]*Wo[(size_t)k*512+n];
    cn[(size_t)ib*512+n] = x[(size_t)ib*1056*512 + n] + acc;
  }
}

__global__ __launch_bounds__(256)
void k_final(const float* __restrict__ cn, const float* __restrict__ nfg, const float* __restrict__ nfb,
             const float* __restrict__ Wdec, const float* __restrict__ bdec, float* __restrict__ out)
{
  int b = blockIdx.x;
  __shared__ float a[512];
  __shared__ float an[512];
  __shared__ float red[8];
  int tid = threadIdx.x;
  float s = 0.f, q = 0.f;
  for (int e=tid;e<512;e+=256){
    float av = 0.5f*(cn[(size_t)b*512 + e] + cn[(size_t)(8+b)*512 + e]);
    a[e] = av; s += av; q += av*av;
  }
  #pragma unroll
  for (int m=1;m<64;m<<=1){ s += __shfl_xor(s,m); q += __shfl_xor(q,m); }
  int w = tid>>6;
  if ((tid&63)==0){ red[w] = s; red[4+w] = q; }
  __syncthreads();
  s = red[0]+red[1]+red[2]+red[3];
  q = red[4]+red[5]+red[6]+red[7];
  float mu = s*0.001953125f;
  float var = q*0.001953125f - mu*mu;
  float rstd = rsqrtf(var + 1e-6f);
  for (int e=tid;e<512;e+=256) an[e] = nfg[e]*(a[e]-mu)*rstd + nfb[e];
  __syncthreads();
  for (int n=tid;n<1024;n+=256){
    float acc = bdec[n];
    for (int e=0;e<512;e++) acc += an[e]*Wdec[(size_t)e*1024 + n];
    out[(size_t)b*1024 + n] = acc;
  }
}

// =======================================================================
extern "C" void kernel_launch(void* const* d_in, const int* in_sizes, int n_in,
                              void* d_out, int out_size, void* d_ws, size_t ws_size,
                              hipStream_t stream)
{
  (void)in_sizes; (void)n_in;
  const float* img1 = (const float*)d_in[0];
  const float* img2 = (const float*)d_in[1];
  const float* patchW = (const float*)d_in[2];
  const float* cls_t = (const float*)d_in[3];
  const float* cls_p = (const float*)d_in[4];
  const float* ln1g = (const float*)d_in[5];
  const float* ln1b = (const float*)d_in[6];
  const float* Wqkv = (const float*)d_in[7];
  const float* Wo   = (const float*)d_in[8];
  const float* ln2g = (const float*)d_in[9];
  const float* ln2b = (const float*)d_in[10];
  const float* W1   = (const float*)d_in[11];
  const float* b1   = (const float*)d_in[12];
  const float* W2   = (const float*)d_in[13];
  const float* b2   = (const float*)d_in[14];
  const float* Wqc  = (const float*)d_in[15];
  const float* Wkvc = (const float*)d_in[16];
  const float* Woc  = (const float*)d_in[17];
  const float* nfg  = (const float*)d_in[18];
  const float* nfb  = (const float*)d_in[19];
  const float* Wdec = (const float*)d_in[20];
  const float* bdec = (const float*)d_in[21];
  float* out = (float*)d_out;

  // ---- compact aliased workspace layout (bytes) ----
  const size_t offA = 34603008, offB = 51904512, offC = 121110528, offD = 148111360;
  const size_t NEEDED = 148209664;
  if (ws_size < NEEDED){
    hipMemsetAsync(d_out, 0, (size_t)out_size*sizeof(float), stream);
    return;
  }
  char* ws = (char*)d_ws;
  float* x    = (float*)ws;
  short* y    = (short*)(ws + offA);
  short* attn = y;
  short* qkv  = (short*)(ws + offB);
  short* vT   = (short*)(ws + offB + 51904512);
  short* mh   = (short*)(ws + offB);
  short* patches = (short*)(ws + offB);
  float* pe   = (float*)(ws + offB + 25165824);
  short* kvc  = (short*)(ws + offB);
  short* wts  = (short*)(ws + offC);
  float* qc   = (float*)(ws + offD);
  float* oc   = (float*)(ws + offD + 32768);
  float* cn   = (float*)(ws + offD + 65536);

  short* patchWt = wts;              // [512][768]
  short* WqkvT = wts + 393216;       // 4 x [1536][512]
  short* WoT   = wts + 3538944;      // 4 x [512][512]
  short* W1T   = wts + 4587520;      // 4 x [2048][512]
  short* W2T   = wts + 8781824;      // 4 x [512][2048]
  short* WkvT  = wts + 12976128;     // [1024][512]

  dim3 tb(32,8,1);
  k_transpose<<<dim3(16,24,1), tb, 0, stream>>>(patchW, patchWt, 768, 512, (size_t)768*512);
  k_transpose<<<dim3(48,16,4), tb, 0, stream>>>(Wqkv, WqkvT, 512, 1536, (size_t)512*1536);
  k_transpose<<<dim3(16,16,4), tb, 0, stream>>>(Wo,   WoT,   512, 512,  (size_t)512*512);
  k_transpose<<<dim3(64,16,4), tb, 0, stream>>>(W1,   W1T,   512, 2048, (size_t)512*2048);
  k_transpose<<<dim3(16,64,4), tb, 0, stream>>>(W2,   W2T,   2048, 512, (size_t)2048*512);
  k_transpose<<<dim3(32,16,1), tb, 0, stream>>>(Wkvc, WkvT,  512, 1024, (size_t)512*1024);

  k_pe<<<1024, 256, 0, stream>>>(pe);
  k_gather<<<16384, 256, 0, stream>>>(img1, img2, patches);
  k_zeropad<<<496, 512, 0, stream>>>(x);
  k_cls<<<16, 512, 0, stream>>>(cls_t, cls_p, x);

  EpiArgs ea;
  // patch embedding: x[:,1:1025,:] = patches @ patchW + pe
  ea = EpiArgs{nullptr, x, nullptr, pe, nullptr};
  k_gemm<4><<<dim3(4, 128), 256, 0, stream>>>(patches, patchWt, 16384, 512, 768, ea);

  for (int i=0;i<4;i++){
    k_layernorm<<<4224, 256, 0, stream>>>(x, y, ln1g + i*512, ln1b + i*512);
    ea = EpiArgs{qkv, nullptr, nullptr, nullptr, vT};
    k_gemm<1><<<dim3(12, 132), 256, 0, stream>>>(y, WqkvT + (size_t)i*1536*512, 16896, 1536, 512, ea);
    k_attn<<<dim3(9, 128), 256, 0, stream>>>(qkv, vT, attn);
    ea = EpiArgs{nullptr, x, nullptr, nullptr, nullptr};
    k_gemm<2><<<dim3(4, 132), 256, 0, stream>>>(attn, WoT + (size_t)i*512*512, 16896, 512, 512, ea);
    k_layernorm<<<4224, 256, 0, stream>>>(x, y, ln2g + i*512, ln2b + i*512);
    ea = EpiArgs{mh, nullptr, b1 + i*2048, nullptr, nullptr};
    k_gemm<3><<<dim3(16, 132), 256, 0, stream>>>(y, W1T + (size_t)i*2048*512, 16896, 2048, 512, ea);
    ea = EpiArgs{nullptr, x, b2 + i*512, nullptr, nullptr};
    k_gemm<2><<<dim3(4, 132), 256, 0, stream>>>(mh, W2T + (size_t)i*512*2048, 16896, 512, 2048, ea);
  }

  // cross attention between cls tokens and the other image's tokens
  k_cast_bf16<<<4224, 256, 0, stream>>>(x, y);
  ea = EpiArgs{kvc, nullptr, nullptr, nullptr, nullptr};
  k_gemm<0><<<dim3(8, 132), 256, 0, stream>>>(y, WkvT, 16896, 1024, 512, ea);
  k_cross_q<<<16, 256, 0, stream>>>(x, Wqc, qc);
  k_cross_attn<<<128, 64, 0, stream>>>(qc, kvc, oc);
  k_cross_out<<<16, 256, 0, stream>>>(x, oc, Woc, cn);
  k_final<<<8, 256, 0, stream>>>(cn, nfg, nfb, Wdec, bdec, out);
}

// Round 7
// 1693.986 us; speedup vs baseline: 1.4230x; 1.0338x over previous
//
#include <hip/hip_runtime.h>
#include <stdint.h>
#include <math.h>

typedef __attribute__((ext_vector_type(4))) float f4;
typedef __attribute__((ext_vector_type(8))) __bf16 bf8;
typedef __attribute__((ext_vector_type(8))) short s8;
typedef __attribute__((ext_vector_type(4))) uint32_t u32x4;

#define DI __device__ __forceinline__

DI short f2bf(float f){
  union { float f; uint32_t u; } v; v.f = f;
  uint32_t r = v.u + 0x7fffu + ((v.u >> 16) & 1u);
  return (short)(r >> 16);
}
DI float bf2f(short s){
  union { uint32_t u; float f; } v; v.u = ((uint32_t)(uint16_t)s) << 16;
  return v.f;
}
// packed f32x2 -> bf16x2 (RNE), lo = first arg
DI uint32_t cvtpk(float lo, float hi){
  uint32_t r;
  asm("v_cvt_pk_bf16_f32 %0, %1, %2" : "=v"(r) : "v"(lo), "v"(hi));
  return r;
}
// gelu-tanh == u * sigmoid(2c(u + 0.044715 u^3)), c = 0.7978845608
DI float gelu_f(float u){
  float z = 1.5957691216057308f * u * fmaf(0.044715f, u*u, 1.f);
  return u * __builtin_amdgcn_rcpf(1.f + __expf(-z));
}
DI void gload16(const void* g, void* l){
  __builtin_amdgcn_global_load_lds((const __attribute__((address_space(1))) unsigned*)g,
                                   (__attribute__((address_space(3))) unsigned*)l, 16, 0, 0);
}

// ---------------- transpose + f32->bf16 convert: in [K][N] f32 -> out [N][K] bf16
// launch grid = (N/32, K/32, z)
__global__ __launch_bounds__(256)
void k_transpose(const float* __restrict__ in, short* __restrict__ out, int K, int N, size_t stride)
{
  __shared__ float t[32][33];
  in  += (size_t)blockIdx.z * stride;
  out += (size_t)blockIdx.z * stride;
  int n0 = blockIdx.x*32, k0 = blockIdx.y*32;
  int tx = threadIdx.x, ty = threadIdx.y;
  #pragma unroll
  for (int i=0;i<32;i+=8) t[ty+i][tx] = in[(size_t)(k0+ty+i)*N + n0+tx];
  __syncthreads();
  #pragma unroll
  for (int i=0;i<32;i+=8) out[(size_t)(n0+ty+i)*K + k0+tx] = f2bf(t[tx][ty+i]);
}

// ---------------- sinusoidal positional table pe[1024][512] f32
__global__ void k_pe(float* __restrict__ pe)
{
  int p = blockIdx.x;
  for (int d = threadIdx.x; d < 512; d += 256){
    int j = (d < 256) ? d : d - 256;
    float div = expf((float)(2*j) * (-9.210340371976184f/512.f));
    float a = (float)p * div;
    pe[(size_t)p*512 + d] = (d < 256) ? sinf(a) : cosf(a);
  }
}

// ---------------- patch gather: img NHWC f32 -> patches[16384][768] bf16
__global__ __launch_bounds__(256)
void k_gather(const float* __restrict__ img1, const float* __restrict__ img2, short* __restrict__ patches)
{
  int row = blockIdx.x;              // (img*8 + b)*1024 + p
  int img = row >> 13;
  int b   = (row >> 10) & 7;
  int p   = row & 1023;
  int ph = p >> 5, pw = p & 31;
  const float* src = (img ? img2 : img1) + (size_t)b*512*512*3;
  short* dst = patches + (size_t)row*768;
  for (int k = threadIdx.x; k < 768; k += 256){
    int i = k / 48; int rem = k - i*48; int j = rem / 3; int c = rem - j*3;
    int yy = ph*16 + i, xx = pw*16 + j;
    dst[k] = f2bf(src[((size_t)yy*512 + xx)*3 + c]);
  }
}

// ---------------- zero pad token rows of x, set cls rows
__global__ void k_zeropad(float* __restrict__ x)
{
  int idx = blockIdx.x; int ib = idx / 31; int t = 1025 + (idx - ib*31);
  x[((size_t)ib*1056 + t)*512 + threadIdx.x] = 0.f;
}
__global__ void k_cls(const float* __restrict__ ct, const float* __restrict__ cp, float* __restrict__ x)
{
  int ib = blockIdx.x; int e = threadIdx.x;
  x[(size_t)ib*1056*512 + e] = ct[e] + cp[e];
}

// ---------------- layernorm rows of x (fp32) -> y (bf16). 4 rows/block, 1 wave per row.
__global__ __launch_bounds__(256)
void k_layernorm(const float* __restrict__ x, short* __restrict__ y,
                 const float* __restrict__ g, const float* __restrict__ b)
{
  int row = blockIdx.x*4 + (threadIdx.x>>6);
  int l = threadIdx.x & 63;
  const float* xr = x + (size_t)row*512 + l*8;
  f4 v0 = *(const f4*)xr;
  f4 v1 = *(const f4*)(xr+4);
  float s = v0[0]+v0[1]+v0[2]+v0[3]+v1[0]+v1[1]+v1[2]+v1[3];
  float q = v0[0]*v0[0]+v0[1]*v0[1]+v0[2]*v0[2]+v0[3]*v0[3]
          + v1[0]*v1[0]+v1[1]*v1[1]+v1[2]*v1[2]+v1[3]*v1[3];
  #pragma unroll
  for (int m=1;m<64;m<<=1){ s += __shfl_xor(s,m); q += __shfl_xor(q,m); }
  float mu = s * 0.001953125f;
  float var = q * 0.001953125f - mu*mu;
  float rstd = rsqrtf(var + 1e-6f);
  const float* gp = g + l*8;
  const float* bp = b + l*8;
  float ov[8];
  #pragma unroll
  for (int j=0;j<8;j++){
    float xv = (j<4) ? v0[j] : v1[j-4];
    ov[j] = gp[j]*(xv-mu)*rstd + bp[j];
  }
  u32x4 pk;
  #pragma unroll
  for (int j=0;j<4;j++) pk[j] = cvtpk(ov[2*j], ov[2*j+1]);
  *(u32x4*)(y + (size_t)row*512 + l*8) = pk;
}

// ---------------- straight f32 -> bf16 cast (8 elems/thread)
__global__ void k_cast_bf16(const float* __restrict__ in, short* __restrict__ out)
{
  size_t i = (size_t)blockIdx.x*256 + threadIdx.x;
  const float* p = in + i*8;
  u32x4 pk;
  #pragma unroll
  for (int j=0;j<4;j++) pk[j] = cvtpk(p[2*j], p[2*j+1]);
  *(u32x4*)(out + i*8) = pk;
}

// ---------------- bf16 MFMA GEMM, 128x128 tile, BK=64, A[M][K], Bt[N][K]
// LDS XOR-swizzled (both sides: pre-swizzled global src + swizzled ds_read).
// EPI: 0=bf16 out, 1=bf16 out + q-prescale + vT scatter (QKV), 2=f32 residual add (+bias),
//      3=bias+gelu->bf16, 4=embed(+pe)->x
struct EpiArgs { short* outb; float* outf; const float* bias; const float* pe; short* vT; };

template<int EPI>
__global__ __launch_bounds__(256)
void k_gemm(const short* __restrict__ A, const short* __restrict__ Bt,
            int M, int N, int K, EpiArgs ea)
{
  __shared__ short Al[128*64];
  __shared__ short Bl[128*64];
  const int tid = threadIdx.x;
  const int l = tid & 63;
  const int w = tid >> 6;
  const int wr = (w >> 1) * 64, wc = (w & 1) * 64;
  const int lr = l & 15, lg = l >> 4;
  const int brow = blockIdx.y * 128, bcol = blockIdx.x * 128;
  const short* Ab = A  + (size_t)brow * K;
  const short* Bb = Bt + (size_t)bcol * K;
  f4 acc[4][4];
  #pragma unroll
  for (int m=0;m<4;m++)
    #pragma unroll
    for (int n=0;n<4;n++){ acc[m][n][0]=0.f; acc[m][n][1]=0.f; acc[m][n][2]=0.f; acc[m][n][3]=0.f; }

  // read-side swizzled col-slot per thread (involution: slot ^ (row&7))
  const int rsw = lr & 7;
  for (int kt = 0; kt < K; kt += 64){
    #pragma unroll
    for (int i=0;i<4;i++){
      int s   = i*256 + tid;
      int row = s >> 3;
      int gs  = (s & 7) ^ (row & 7);
      gload16(Ab + (size_t)row*K + kt + gs*8, &Al[s*8]);
      gload16(Bb + (size_t)row*K + kt + gs*8, &Bl[s*8]);
    }
    __syncthreads();
    #pragma unroll
    for (int ko=0;ko<2;ko++){
      bf8 af[4], bfr[4];
      const int ps = ((ko*4 + lg) ^ rsw) * 8;
      #pragma unroll
      for (int m=0;m<4;m++) af[m]  = *(const bf8*)&Al[(wr + m*16 + lr)*64 + ps];
      #pragma unroll
      for (int n=0;n<4;n++) bfr[n] = *(const bf8*)&Bl[(wc + n*16 + lr)*64 + ps];
      #pragma unroll
      for (int m=0;m<4;m++)
        #pragma unroll
        for (int n=0;n<4;n++)
          acc[m][n] = __builtin_amdgcn_mfma_f32_16x16x32_bf16(af[m], bfr[n], acc[m][n], 0, 0, 0);
    }
    __syncthreads();
  }

  #pragma unroll
  for (int m=0;m<4;m++){
    #pragma unroll
    for (int n=0;n<4;n++){
      const int row0 = brow + wr + m*16 + lg*4;
      const int col  = bcol + wc + n*16 + lr;
      float v0 = acc[m][n][0], v1 = acc[m][n][1], v2 = acc[m][n][2], v3 = acc[m][n][3];
      if (EPI == 0 || EPI == 1){
        if (EPI == 1 && col < 512){ v0*=0.125f; v1*=0.125f; v2*=0.125f; v3*=0.125f; }
        uint32_t u01 = cvtpk(v0, v1), u23 = cvtpk(v2, v3);
        short s0 = (short)u01, s1 = (short)(u01>>16), s2 = (short)u23, s3 = (short)(u23>>16);
        ea.outb[(size_t)(row0+0)*N + col] = s0;
        ea.outb[(size_t)(row0+1)*N + col] = s1;
        ea.outb[(size_t)(row0+2)*N + col] = s2;
        ea.outb[(size_t)(row0+3)*N + col] = s3;
        if (EPI == 1 && col >= 1024){
          int ib = row0 / 1056, t = row0 - ib*1056;
          short* vtb = ea.vT + ((size_t)ib*512 + (col - 1024))*1056;
          vtb[t] = s0; vtb[t+1] = s1; vtb[t+2] = s2; vtb[t+3] = s3;
        }
      } else if (EPI == 2){
        float bv = ea.bias ? ea.bias[col] : 0.f;
        ea.outf[(size_t)(row0+0)*N + col] += v0 + bv;
        ea.outf[(size_t)(row0+1)*N + col] += v1 + bv;
        ea.outf[(size_t)(row0+2)*N + col] += v2 + bv;
        ea.outf[(size_t)(row0+3)*N + col] += v3 + bv;
      } else if (EPI == 3){
        float bv = ea.bias[col];
        float g0 = gelu_f(v0+bv), g1 = gelu_f(v1+bv), g2 = gelu_f(v2+bv), g3 = gelu_f(v3+bv);
        uint32_t u01 = cvtpk(g0, g1), u23 = cvtpk(g2, g3);
        ea.outb[(size_t)(row0+0)*N + col] = (short)u01;
        ea.outb[(size_t)(row0+1)*N + col] = (short)(u01>>16);
        ea.outb[(size_t)(row0+2)*N + col] = (short)u23;
        ea.outb[(size_t)(row0+3)*N + col] = (short)(u23>>16);
      } else if (EPI == 4){
        #pragma unroll
        for (int r=0;r<4;r++){
          int row = row0 + r;
          int ib = row >> 10, p = row & 1023;
          float v = (r==0)?v0:(r==1)?v1:(r==2)?v2:v3;
          ea.outf[((size_t)(ib*1056 + 1 + p))*512 + col] = v + ea.pe[(size_t)p*512 + col];
        }
      }
    }
  }
}

// ---------------- fused self-attention v3+: 16x16 MFMA (proven layouts),
// swapped QK^T, in-register softmax, defer-max, last-tile-only masking,
// K-fragment register double-buffer prefetch + early V issue (latency hiding).
// 4 independent waves per block, 1 wave = one 32-row q-tile. No barriers.
__global__ __launch_bounds__(256)
void k_attn(const short* __restrict__ qkv, const short* __restrict__ vT, short* __restrict__ aout)
{
  __shared__ short Pl[4][2][32*40];
  __shared__ float Sc[4][2][32];

  const int w  = threadIdx.x >> 6;
  const int qt = blockIdx.x * 4 + w;
  if (qt > 32) return;                 // no barriers in kernel -> safe early exit
  const int u  = blockIdx.y;
  const int ib = u >> 3, h = u & 7;
  const int l = threadIdx.x & 63, lr = l & 15, lg = l >> 4;
  const size_t rb = (size_t)ib * 1056;
  const int t0 = qt * 32;

  bf8 qf[2][2];
  #pragma unroll
  for (int nq=0;nq<2;nq++)
    #pragma unroll
    for (int ks=0;ks<2;ks++)
      qf[nq][ks] = *(const bf8*)&qkv[(rb + t0 + nq*16 + lr)*1536 + h*64 + ks*32 + lg*8];

  const short* kbase = &qkv[(rb + lr)*1536 + 512 + h*64 + lg*8];
  const short* vbase = &vT[((size_t)ib*512 + h*64 + lr)*1056 + lg*8];

  f4 o[2][4];
  float mrun[2], lrun[2];
  #pragma unroll
  for (int mq=0;mq<2;mq++)
    #pragma unroll
    for (int nd=0;nd<4;nd++){ o[mq][nd][0]=0.f; o[mq][nd][1]=0.f; o[mq][nd][2]=0.f; o[mq][nd][3]=0.f; }
  mrun[0]=mrun[1]=-1e30f; lrun[0]=lrun[1]=0.f;

  auto LD_K = [&](bf8 (&kf)[2][2], int jt){
    const short* kb = kbase + (size_t)jt*32*1536;
    #pragma unroll
    for (int mk=0;mk<2;mk++)
      #pragma unroll
      for (int ks=0;ks<2;ks++)
        kf[mk][ks] = *(const bf8*)(kb + (size_t)mk*16*1536 + ks*32);
  };

  auto TILE = [&](int jt, bf8 (&kc)[2][2], bf8 (&kn)[2][2], bool MASK){
    const int j0 = jt*32;
    const int pb = jt & 1;
    // early V issue for THIS tile (consumed after softmax, latency hidden)
    bf8 vb[4];
    #pragma unroll
    for (int nd=0;nd<4;nd++)
      vb[nd] = *(const bf8*)(vbase + (size_t)nd*16*1056 + j0);
    // K prefetch for NEXT tile
    if (!MASK) LD_K(kn, jt+1);

    f4 st[2][2];
    #pragma unroll
    for (int mk=0;mk<2;mk++)
      #pragma unroll
      for (int nq=0;nq<2;nq++){ st[mk][nq][0]=0.f; st[mk][nq][1]=0.f; st[mk][nq][2]=0.f; st[mk][nq][3]=0.f; }
    __builtin_amdgcn_s_setprio(1);
    #pragma unroll
    for (int ks=0;ks<2;ks++)
      #pragma unroll
      for (int mk=0;mk<2;mk++)
        #pragma unroll
        for (int nq=0;nq<2;nq++)
          st[mk][nq] = __builtin_amdgcn_mfma_f32_16x16x32_bf16(kc[mk][ks], qf[nq][ks], st[mk][nq], 0, 0, 0);
    __builtin_amdgcn_s_setprio(0);

    float p8[2][8], mx[2];
    #pragma unroll
    for (int nq=0;nq<2;nq++){
      mx[nq] = -1e30f;
      #pragma unroll
      for (int mk=0;mk<2;mk++)
        #pragma unroll
        for (int r=0;r<4;r++){
          float v = st[mk][nq][r];
          if (MASK){
            int kk = j0 + mk*16 + lg*4 + r;
            v = (kk > 1024) ? -1e30f : v;
          }
          p8[nq][mk*4+r] = v;
          mx[nq] = fmaxf(mx[nq], v);
        }
      mx[nq] = fmaxf(mx[nq], __shfl_xor(mx[nq], 16));
      mx[nq] = fmaxf(mx[nq], __shfl_xor(mx[nq], 32));
    }

    bool ok = (mx[0] <= mrun[0] + 8.f) && (mx[1] <= mrun[1] + 8.f);
    if (__all(ok)){
      // defer path: no max update, no rescale
      #pragma unroll
      for (int nq=0;nq<2;nq++){
        float rs = 0.f;
        #pragma unroll
        for (int i=0;i<8;i++){ float p = __expf(p8[nq][i] - mrun[nq]); p8[nq][i] = p; rs += p; }
        rs += __shfl_xor(rs, 16);
        rs += __shfl_xor(rs, 32);
        lrun[nq] += rs;
        uint32_t* prow = (uint32_t*)&Pl[w][pb][(nq*16 + lr)*40];
        #pragma unroll
        for (int mk=0;mk<2;mk++){
          prow[mk*8 + lg*2]     = cvtpk(p8[nq][mk*4+0], p8[nq][mk*4+1]);
          prow[mk*8 + lg*2 + 1] = cvtpk(p8[nq][mk*4+2], p8[nq][mk*4+3]);
        }
      }
      asm volatile("s_waitcnt lgkmcnt(0)" ::: "memory");
      __builtin_amdgcn_sched_barrier(0);
      bf8 pa[2];
      #pragma unroll
      for (int mq=0;mq<2;mq++) pa[mq] = *(const bf8*)&Pl[w][pb][(mq*16 + lr)*40 + lg*8];
      __builtin_amdgcn_s_setprio(1);
      #pragma unroll
      for (int mq=0;mq<2;mq++)
        #pragma unroll
        for (int nd=0;nd<4;nd++)
          o[mq][nd] = __builtin_amdgcn_mfma_f32_16x16x32_bf16(pa[mq], vb[nd], o[mq][nd], 0, 0, 0);
      __builtin_amdgcn_s_setprio(0);
    } else {
      // full online-softmax path
      #pragma unroll
      for (int nq=0;nq<2;nq++){
        float mn = fmaxf(mrun[nq], mx[nq]);
        float sc = __expf(mrun[nq] - mn);
        mrun[nq] = mn;
        float rs = 0.f;
        #pragma unroll
        for (int i=0;i<8;i++){ float p = __expf(p8[nq][i] - mn); p8[nq][i] = p; rs += p; }
        rs += __shfl_xor(rs, 16);
        rs += __shfl_xor(rs, 32);
        lrun[nq] = lrun[nq]*sc + rs;
        Sc[w][pb][nq*16 + lr] = sc;
        uint32_t* prow = (uint32_t*)&Pl[w][pb][(nq*16 + lr)*40];
        #pragma unroll
        for (int mk=0;mk<2;mk++){
          prow[mk*8 + lg*2]     = cvtpk(p8[nq][mk*4+0], p8[nq][mk*4+1]);
          prow[mk*8 + lg*2 + 1] = cvtpk(p8[nq][mk*4+2], p8[nq][mk*4+3]);
        }
      }
      asm volatile("s_waitcnt lgkmcnt(0)" ::: "memory");
      __builtin_amdgcn_sched_barrier(0);
      f4 scv[2]; bf8 pa[2];
      #pragma unroll
      for (int mq=0;mq<2;mq++){
        scv[mq] = *(const f4*)&Sc[w][pb][mq*16 + lg*4];
        pa[mq]  = *(const bf8*)&Pl[w][pb][(mq*16 + lr)*40 + lg*8];
      }
      #pragma unroll
      for (int mq=0;mq<2;mq++)
        #pragma unroll
        for (int nd=0;nd<4;nd++){
          #pragma unroll
          for (int r=0;r<4;r++) o[mq][nd][r] *= scv[mq][r];
        }
      __builtin_amdgcn_s_setprio(1);
      #pragma unroll
      for (int mq=0;mq<2;mq++)
        #pragma unroll
        for (int nd=0;nd<4;nd++)
          o[mq][nd] = __builtin_amdgcn_mfma_f32_16x16x32_bf16(pa[mq], vb[nd], o[mq][nd], 0, 0, 0);
      __builtin_amdgcn_s_setprio(0);
    }
  };

  bf8 kA[2][2], kB[2][2];
  LD_K(kA, 0);
  #pragma unroll 1
  for (int j2=0; j2<16; j2++){
    TILE(2*j2,   kA, kB, false);
    TILE(2*j2+1, kB, kA, false);
  }
  TILE(32, kA, kB, true);

  // final 1/l normalization: route lrun (per q=nq*16+lr) to o-rows (q=mq*16+lg*4+r)
  #pragma unroll
  for (int nq=0;nq<2;nq++) Sc[w][1][nq*16 + lr] = lrun[nq];
  asm volatile("s_waitcnt lgkmcnt(0)" ::: "memory");
  __builtin_amdgcn_sched_barrier(0);
  #pragma unroll
  for (int mq=0;mq<2;mq++){
    f4 lsv = *(const f4*)&Sc[w][1][mq*16 + lg*4];
    float i0 = __builtin_amdgcn_rcpf(lsv[0]);
    float i1 = __builtin_amdgcn_rcpf(lsv[1]);
    float i2 = __builtin_amdgcn_rcpf(lsv[2]);
    float i3 = __builtin_amdgcn_rcpf(lsv[3]);
    const size_t base = rb + t0 + mq*16 + lg*4;
    #pragma unroll
    for (int nd=0;nd<4;nd++){
      int col = h*64 + nd*16 + lr;
      uint32_t u01 = cvtpk(o[mq][nd][0]*i0, o[mq][nd][1]*i1);
      uint32_t u23 = cvtpk(o[mq][nd][2]*i2, o[mq][nd][3]*i3);
      aout[(base+0)*512 + col] = (short)u01;
      aout[(base+1)*512 + col] = (short)(u01>>16);
      aout[(base+2)*512 + col] = (short)u23;
      aout[(base+3)*512 + col] = (short)(u23>>16);
    }
  }
}

// ---------------- cross-attention path (tiny, fp32)
__global__ __launch_bounds__(256)
void k_cross_q(const float* __restrict__ x, const float* __restrict__ Wq, float* __restrict__ qc)
{
  __shared__ float xs[512];
  int ib = blockIdx.x;
  const float* xr = x + (size_t)ib*1056*512;
  for (int e=threadIdx.x;e<512;e+=256) xs[e] = xr[e];
  __syncthreads();
  for (int n=threadIdx.x;n<512;n+=256){
    float acc = 0.f;
    for (int k=0;k<512;k++) acc += xs[k]*Wq[(size_t)k*512 + n];
    qc[(size_t)ib*512 + n] = acc;
  }
}

__global__ __launch_bounds__(64)
void k_cross_attn(const float* __restrict__ qc, const short* __restrict__ kv, float* __restrict__ oc)
{
  int u = blockIdx.x; int ib = u >> 3, h = u & 7;
  int img = ib >> 3, b = ib & 7;
  int sib = (1 - img)*8 + b;
  int l = threadIdx.x;
  __shared__ float qs[64];
  __shared__ float pl[1024];
  qs[l] = qc[(size_t)ib*512 + h*64 + l];
  __syncthreads();
  float lmax = -1e30f;
  for (int jj=0; jj<16; jj++){
    int j = jj*64 + l;
    const short* kr = kv + ((size_t)(sib*1056 + 1 + j))*1024 + h*64;
    float acc = 0.f;
    for (int d=0; d<64; d++) acc += qs[d]*bf2f(kr[d]);
    acc *= 0.125f;
    pl[j] = acc;
    lmax = fmaxf(lmax, acc);
  }
  #pragma unroll
  for (int m=1;m<64;m<<=1) lmax = fmaxf(lmax, __shfl_xor(lmax, m));
  __syncthreads();
  float lsum = 0.f;
  for (int jj=0; jj<16; jj++){
    int j = jj*64 + l;
    float p = __expf(pl[j] - lmax);
    pl[j] = p; lsum += p;
  }
  #pragma unroll
  for (int m=1;m<64;m<<=1) lsum += __shfl_xor(lsum, m);
  __syncthreads();
  float acc = 0.f;
  for (int j=0;j<1024;j++)
    acc += pl[j] * bf2f(kv[((size_t)(sib*1056 + 1 + j))*1024 + 512 + h*64 + l]);
  oc[(size_t)ib*512 + h*64 + l] = acc / lsum;
}

__global__ __launch_bounds__(256)
void k_cross_out(const float* __restrict__ x, const float* __restrict__ oc,
                 const float* __restrict__ Wo, float* __restrict__ cn)
{
  __shared__ float os[512];
  int ib = blockIdx.x;
  for (int e=threadIdx.x;e<512;e+=256) os[e] = oc[(size_t)ib*512+e];
  __syncthreads();
  for (int n=threadIdx.x;n<512;n+=256){
    float acc = 0.f;
    for (int k=0;k<512;k++) acc += os[k]*Wo[(size_t)k*512+n];
    cn[(size_t)ib*512+n] = x[(size_t)ib*1056*512 + n] + acc;
  }
}

__global__ __launch_bounds__(256)
void k_final(const float* __restrict__ cn, const float* __restrict__ nfg, const float* __restrict__ nfb,
             const float* __restrict__ Wdec, const float* __restrict__ bdec, float* __restrict__ out)
{
  int b = blockIdx.x;
  __shared__ float a[512];
  __shared__ float an[512];
  __shared__ float red[8];
  int tid = threadIdx.x;
  float s = 0.f, q = 0.f;
  for (int e=tid;e<512;e+=256){
    float av = 0.5f*(cn[(size_t)b*512 + e] + cn[(size_t)(8+b)*512 + e]);
    a[e] = av; s += av; q += av*av;
  }
  #pragma unroll
  for (int m=1;m<64;m<<=1){ s += __shfl_xor(s,m); q += __shfl_xor(q,m); }
  int w = tid>>6;
  if ((tid&63)==0){ red[w] = s; red[4+w] = q; }
  __syncthreads();
  s = red[0]+red[1]+red[2]+red[3];
  q = red[4]+red[5]+red[6]+red[7];
  float mu = s*0.001953125f;
  float var = q*0.001953125f - mu*mu;
  float rstd = rsqrtf(var + 1e-6f);
  for (int e=tid;e<512;e+=256) an[e] = nfg[e]*(a[e]-mu)*rstd + nfb[e];
  __syncthreads();
  for (int n=tid;n<1024;n+=256){
    float acc = bdec[n];
    for (int e=0;e<512;e++) acc += an[e]*Wdec[(size_t)e*1024 + n];
    out[(size_t)b*1024 + n] = acc;
  }
}

// =======================================================================
extern "C" void kernel_launch(void* const* d_in, const int* in_sizes, int n_in,
                              void* d_out, int out_size, void* d_ws, size_t ws_size,
                              hipStream_t stream)
{
  (void)in_sizes; (void)n_in;
  const float* img1 = (const float*)d_in[0];
  const float* img2 = (const float*)d_in[1];
  const float* patchW = (const float*)d_in[2];
  const float* cls_t = (const float*)d_in[3];
  const float* cls_p = (const float*)d_in[4];
  const float* ln1g = (const float*)d_in[5];
  const float* ln1b = (const float*)d_in[6];
  const float* Wqkv = (const float*)d_in[7];
  const float* Wo   = (const float*)d_in[8];
  const float* ln2g = (const float*)d_in[9];
  const float* ln2b = (const float*)d_in[10];
  const float* W1   = (const float*)d_in[11];
  const float* b1   = (const float*)d_in[12];
  const float* W2   = (const float*)d_in[13];
  const float* b2   = (const float*)d_in[14];
  const float* Wqc  = (const float*)d_in[15];
  const float* Wkvc = (const float*)d_in[16];
  const float* Woc  = (const float*)d_in[17];
  const float* nfg  = (const float*)d_in[18];
  const float* nfb  = (const float*)d_in[19];
  const float* Wdec = (const float*)d_in[20];
  const float* bdec = (const float*)d_in[21];
  float* out = (float*)d_out;

  // ---- compact aliased workspace layout (bytes) ----
  const size_t offA = 34603008, offB = 51904512, offC = 121110528, offD = 148111360;
  const size_t NEEDED = 148209664;
  if (ws_size < NEEDED){
    hipMemsetAsync(d_out, 0, (size_t)out_size*sizeof(float), stream);
    return;
  }
  char* ws = (char*)d_ws;
  float* x    = (float*)ws;
  short* y    = (short*)(ws + offA);
  short* attn = y;
  short* qkv  = (short*)(ws + offB);
  short* vT   = (short*)(ws + offB + 51904512);
  short* mh   = (short*)(ws + offB);
  short* patches = (short*)(ws + offB);
  float* pe   = (float*)(ws + offB + 25165824);
  short* kvc  = (short*)(ws + offB);
  short* wts  = (short*)(ws + offC);
  float* qc   = (float*)(ws + offD);
  float* oc   = (float*)(ws + offD + 32768);
  float* cn   = (float*)(ws + offD + 65536);

  short* patchWt = wts;              // [512][768]
  short* WqkvT = wts + 393216;       // 4 x [1536][512]
  short* WoT   = wts + 3538944;      // 4 x [512][512]
  short* W1T   = wts + 4587520;      // 4 x [2048][512]
  short* W2T   = wts + 8781824;      // 4 x [512][2048]
  short* WkvT  = wts + 12976128;     // [1024][512]

  dim3 tb(32,8,1);
  k_transpose<<<dim3(16,24,1), tb, 0, stream>>>(patchW, patchWt, 768, 512, (size_t)768*512);
  k_transpose<<<dim3(48,16,4), tb, 0, stream>>>(Wqkv, WqkvT, 512, 1536, (size_t)512*1536);
  k_transpose<<<dim3(16,16,4), tb, 0, stream>>>(Wo,   WoT,   512, 512,  (size_t)512*512);
  k_transpose<<<dim3(64,16,4), tb, 0, stream>>>(W1,   W1T,   512, 2048, (size_t)512*2048);
  k_transpose<<<dim3(16,64,4), tb, 0, stream>>>(W2,   W2T,   2048, 512, (size_t)2048*512);
  k_transpose<<<dim3(32,16,1), tb, 0, stream>>>(Wkvc, WkvT,  512, 1024, (size_t)512*1024);

  k_pe<<<1024, 256, 0, stream>>>(pe);
  k_gather<<<16384, 256, 0, stream>>>(img1, img2, patches);
  k_zeropad<<<496, 512, 0, stream>>>(x);
  k_cls<<<16, 512, 0, stream>>>(cls_t, cls_p, x);

  EpiArgs ea;
  // patch embedding: x[:,1:1025,:] = patches @ patchW + pe
  ea = EpiArgs{nullptr, x, nullptr, pe, nullptr};
  k_gemm<4><<<dim3(4, 128), 256, 0, stream>>>(patches, patchWt, 16384, 512, 768, ea);

  for (int i=0;i<4;i++){
    k_layernorm<<<4224, 256, 0, stream>>>(x, y, ln1g + i*512, ln1b + i*512);
    ea = EpiArgs{qkv, nullptr, nullptr, nullptr, vT};
    k_gemm<1><<<dim3(12, 132), 256, 0, stream>>>(y, WqkvT + (size_t)i*1536*512, 16896, 1536, 512, ea);
    k_attn<<<dim3(9, 128), 256, 0, stream>>>(qkv, vT, attn);
    ea = EpiArgs{nullptr, x, nullptr, nullptr, nullptr};
    k_gemm<2><<<dim3(4, 132), 256, 0, stream>>>(attn, WoT + (size_t)i*512*512, 16896, 512, 512, ea);
    k_layernorm<<<4224, 256, 0, stream>>>(x, y, ln2g + i*512, ln2b + i*512);
    ea = EpiArgs{mh, nullptr, b1 + i*2048, nullptr, nullptr};
    k_gemm<3><<<dim3(16, 132), 256, 0, stream>>>(y, W1T + (size_t)i*2048*512, 16896, 2048, 512, ea);
    ea = EpiArgs{nullptr, x, b2 + i*512, nullptr, nullptr};
    k_gemm<2><<<dim3(4, 132), 256, 0, stream>>>(mh, W2T + (size_t)i*512*2048, 16896, 512, 2048, ea);
  }

  // cross attention between cls tokens and the other image's tokens
  k_cast_bf16<<<4224, 256, 0, stream>>>(x, y);
  ea = EpiArgs{kvc, nullptr, nullptr, nullptr, nullptr};
  k_gemm<0><<<dim3(8, 132), 256, 0, stream>>>(y, WkvT, 16896, 1024, 512, ea);
  k_cross_q<<<16, 256, 0, stream>>>(x, Wqc, qc);
  k_cross_attn<<<128, 64, 0, stream>>>(qc, kvc, oc);
  k_cross_out<<<16, 256, 0, stream>>>(x, oc, Woc, cn);
  k_final<<<8, 256, 0, stream>>>(cn, nfg, nfb, Wdec, bdec, out);
}

// Round 8
// 1622.656 us; speedup vs baseline: 1.4855x; 1.0440x over previous
//
#include <hip/hip_runtime.h>
#include <stdint.h>
#include <math.h>

typedef __attribute__((ext_vector_type(4))) float f4;
typedef __attribute__((ext_vector_type(8))) __bf16 bf8;
typedef __attribute__((ext_vector_type(8))) short s8;
typedef __attribute__((ext_vector_type(4))) uint32_t u32x4;

#define DI __device__ __forceinline__

DI short f2bf(float f){
  union { float f; uint32_t u; } v; v.f = f;
  uint32_t r = v.u + 0x7fffu + ((v.u >> 16) & 1u);
  return (short)(r >> 16);
}
DI float bf2f(short s){
  union { uint32_t u; float f; } v; v.u = ((uint32_t)(uint16_t)s) << 16;
  return v.f;
}
// packed f32x2 -> bf16x2 (RNE), lo = first arg
DI uint32_t cvtpk(float lo, float hi){
  uint32_t r;
  asm("v_cvt_pk_bf16_f32 %0, %1, %2" : "=v"(r) : "v"(lo), "v"(hi));
  return r;
}
// gelu-tanh == u * sigmoid(2c(u + 0.044715 u^3)), c = 0.7978845608
DI float gelu_f(float u){
  float z = 1.5957691216057308f * u * fmaf(0.044715f, u*u, 1.f);
  return u * __builtin_amdgcn_rcpf(1.f + __expf(-z));
}
DI void gload16(const void* g, void* l){
  __builtin_amdgcn_global_load_lds((const __attribute__((address_space(1))) unsigned*)g,
                                   (__attribute__((address_space(3))) unsigned*)l, 16, 0, 0);
}

// ---------------- transpose + f32->bf16 convert: in [K][N] f32 -> out [N][K] bf16
// launch grid = (N/32, K/32, z)
__global__ __launch_bounds__(256)
void k_transpose(const float* __restrict__ in, short* __restrict__ out, int K, int N, size_t stride)
{
  __shared__ float t[32][33];
  in  += (size_t)blockIdx.z * stride;
  out += (size_t)blockIdx.z * stride;
  int n0 = blockIdx.x*32, k0 = blockIdx.y*32;
  int tx = threadIdx.x, ty = threadIdx.y;
  #pragma unroll
  for (int i=0;i<32;i+=8) t[ty+i][tx] = in[(size_t)(k0+ty+i)*N + n0+tx];
  __syncthreads();
  #pragma unroll
  for (int i=0;i<32;i+=8) out[(size_t)(n0+ty+i)*K + k0+tx] = f2bf(t[tx][ty+i]);
}

// ---------------- sinusoidal positional table pe[1024][512] f32
__global__ void k_pe(float* __restrict__ pe)
{
  int p = blockIdx.x;
  for (int d = threadIdx.x; d < 512; d += 256){
    int j = (d < 256) ? d : d - 256;
    float div = expf((float)(2*j) * (-9.210340371976184f/512.f));
    float a = (float)p * div;
    pe[(size_t)p*512 + d] = (d < 256) ? sinf(a) : cosf(a);
  }
}

// ---------------- patch gather: img NHWC f32 -> patches[16384][768] bf16
__global__ __launch_bounds__(256)
void k_gather(const float* __restrict__ img1, const float* __restrict__ img2, short* __restrict__ patches)
{
  int row = blockIdx.x;              // (img*8 + b)*1024 + p
  int img = row >> 13;
  int b   = (row >> 10) & 7;
  int p   = row & 1023;
  int ph = p >> 5, pw = p & 31;
  const float* src = (img ? img2 : img1) + (size_t)b*512*512*3;
  short* dst = patches + (size_t)row*768;
  for (int k = threadIdx.x; k < 768; k += 256){
    int i = k / 48; int rem = k - i*48; int j = rem / 3; int c = rem - j*3;
    int yy = ph*16 + i, xx = pw*16 + j;
    dst[k] = f2bf(src[((size_t)yy*512 + xx)*3 + c]);
  }
}

// ---------------- zero pad token rows of x, set cls rows
__global__ void k_zeropad(float* __restrict__ x)
{
  int idx = blockIdx.x; int ib = idx / 31; int t = 1025 + (idx - ib*31);
  x[((size_t)ib*1056 + t)*512 + threadIdx.x] = 0.f;
}
__global__ void k_cls(const float* __restrict__ ct, const float* __restrict__ cp, float* __restrict__ x)
{
  int ib = blockIdx.x; int e = threadIdx.x;
  x[(size_t)ib*1056*512 + e] = ct[e] + cp[e];
}

// ---------------- layernorm rows of x (fp32) -> y (bf16). 4 rows/block, 1 wave per row.
__global__ __launch_bounds__(256)
void k_layernorm(const float* __restrict__ x, short* __restrict__ y,
                 const float* __restrict__ g, const float* __restrict__ b)
{
  int row = blockIdx.x*4 + (threadIdx.x>>6);
  int l = threadIdx.x & 63;
  const float* xr = x + (size_t)row*512 + l*8;
  f4 v0 = *(const f4*)xr;
  f4 v1 = *(const f4*)(xr+4);
  float s = v0[0]+v0[1]+v0[2]+v0[3]+v1[0]+v1[1]+v1[2]+v1[3];
  float q = v0[0]*v0[0]+v0[1]*v0[1]+v0[2]*v0[2]+v0[3]*v0[3]
          + v1[0]*v1[0]+v1[1]*v1[1]+v1[2]*v1[2]+v1[3]*v1[3];
  #pragma unroll
  for (int m=1;m<64;m<<=1){ s += __shfl_xor(s,m); q += __shfl_xor(q,m); }
  float mu = s * 0.001953125f;
  float var = q * 0.001953125f - mu*mu;
  float rstd = rsqrtf(var + 1e-6f);
  const float* gp = g + l*8;
  const float* bp = b + l*8;
  float ov[8];
  #pragma unroll
  for (int j=0;j<8;j++){
    float xv = (j<4) ? v0[j] : v1[j-4];
    ov[j] = gp[j]*(xv-mu)*rstd + bp[j];
  }
  u32x4 pk;
  #pragma unroll
  for (int j=0;j<4;j++) pk[j] = cvtpk(ov[2*j], ov[2*j+1]);
  *(u32x4*)(y + (size_t)row*512 + l*8) = pk;
}

// ---------------- straight f32 -> bf16 cast (8 elems/thread)
__global__ void k_cast_bf16(const float* __restrict__ in, short* __restrict__ out)
{
  size_t i = (size_t)blockIdx.x*256 + threadIdx.x;
  const float* p = in + i*8;
  u32x4 pk;
  #pragma unroll
  for (int j=0;j<4;j++) pk[j] = cvtpk(p[2*j], p[2*j+1]);
  *(u32x4*)(out + i*8) = pk;
}

// ---------------- bf16 MFMA GEMM, 128x128 tile, BK=64, A[M][K], Bt[N][K]
// LDS XOR-swizzled (both sides: pre-swizzled global src + swizzled ds_read).
// EPI: 0=bf16 out, 1=bf16 out + q-prescale + vT scatter (QKV), 2=f32 residual add (+bias),
//      3=bias+gelu->bf16, 4=embed(+pe)->x
struct EpiArgs { short* outb; float* outf; const float* bias; const float* pe; short* vT; };

template<int EPI>
__global__ __launch_bounds__(256)
void k_gemm(const short* __restrict__ A, const short* __restrict__ Bt,
            int M, int N, int K, EpiArgs ea)
{
  __shared__ short Al[128*64];
  __shared__ short Bl[128*64];
  const int tid = threadIdx.x;
  const int l = tid & 63;
  const int w = tid >> 6;
  const int wr = (w >> 1) * 64, wc = (w & 1) * 64;
  const int lr = l & 15, lg = l >> 4;
  const int brow = blockIdx.y * 128, bcol = blockIdx.x * 128;
  const short* Ab = A  + (size_t)brow * K;
  const short* Bb = Bt + (size_t)bcol * K;
  f4 acc[4][4];
  #pragma unroll
  for (int m=0;m<4;m++)
    #pragma unroll
    for (int n=0;n<4;n++){ acc[m][n][0]=0.f; acc[m][n][1]=0.f; acc[m][n][2]=0.f; acc[m][n][3]=0.f; }

  // read-side swizzled col-slot per thread (involution: slot ^ (row&7))
  const int rsw = lr & 7;
  for (int kt = 0; kt < K; kt += 64){
    #pragma unroll
    for (int i=0;i<4;i++){
      int s   = i*256 + tid;
      int row = s >> 3;
      int gs  = (s & 7) ^ (row & 7);
      gload16(Ab + (size_t)row*K + kt + gs*8, &Al[s*8]);
      gload16(Bb + (size_t)row*K + kt + gs*8, &Bl[s*8]);
    }
    __syncthreads();
    #pragma unroll
    for (int ko=0;ko<2;ko++){
      bf8 af[4], bfr[4];
      const int ps = ((ko*4 + lg) ^ rsw) * 8;
      #pragma unroll
      for (int m=0;m<4;m++) af[m]  = *(const bf8*)&Al[(wr + m*16 + lr)*64 + ps];
      #pragma unroll
      for (int n=0;n<4;n++) bfr[n] = *(const bf8*)&Bl[(wc + n*16 + lr)*64 + ps];
      #pragma unroll
      for (int m=0;m<4;m++)
        #pragma unroll
        for (int n=0;n<4;n++)
          acc[m][n] = __builtin_amdgcn_mfma_f32_16x16x32_bf16(af[m], bfr[n], acc[m][n], 0, 0, 0);
    }
    __syncthreads();
  }

  #pragma unroll
  for (int m=0;m<4;m++){
    #pragma unroll
    for (int n=0;n<4;n++){
      const int row0 = brow + wr + m*16 + lg*4;
      const int col  = bcol + wc + n*16 + lr;
      float v0 = acc[m][n][0], v1 = acc[m][n][1], v2 = acc[m][n][2], v3 = acc[m][n][3];
      if (EPI == 0 || EPI == 1){
        if (EPI == 1 && col < 512){ v0*=0.125f; v1*=0.125f; v2*=0.125f; v3*=0.125f; }
        uint32_t u01 = cvtpk(v0, v1), u23 = cvtpk(v2, v3);
        short s0 = (short)u01, s1 = (short)(u01>>16), s2 = (short)u23, s3 = (short)(u23>>16);
        ea.outb[(size_t)(row0+0)*N + col] = s0;
        ea.outb[(size_t)(row0+1)*N + col] = s1;
        ea.outb[(size_t)(row0+2)*N + col] = s2;
        ea.outb[(size_t)(row0+3)*N + col] = s3;
        if (EPI == 1 && col >= 1024){
          int ib = row0 / 1056, t = row0 - ib*1056;
          short* vtb = ea.vT + ((size_t)ib*512 + (col - 1024))*1056;
          vtb[t] = s0; vtb[t+1] = s1; vtb[t+2] = s2; vtb[t+3] = s3;
        }
      } else if (EPI == 2){
        float bv = ea.bias ? ea.bias[col] : 0.f;
        ea.outf[(size_t)(row0+0)*N + col] += v0 + bv;
        ea.outf[(size_t)(row0+1)*N + col] += v1 + bv;
        ea.outf[(size_t)(row0+2)*N + col] += v2 + bv;
        ea.outf[(size_t)(row0+3)*N + col] += v3 + bv;
      } else if (EPI == 3){
        float bv = ea.bias[col];
        float g0 = gelu_f(v0+bv), g1 = gelu_f(v1+bv), g2 = gelu_f(v2+bv), g3 = gelu_f(v3+bv);
        uint32_t u01 = cvtpk(g0, g1), u23 = cvtpk(g2, g3);
        ea.outb[(size_t)(row0+0)*N + col] = (short)u01;
        ea.outb[(size_t)(row0+1)*N + col] = (short)(u01>>16);
        ea.outb[(size_t)(row0+2)*N + col] = (short)u23;
        ea.outb[(size_t)(row0+3)*N + col] = (short)(u23>>16);
      } else if (EPI == 4){
        #pragma unroll
        for (int r=0;r<4;r++){
          int row = row0 + r;
          int ib = row >> 10, p = row & 1023;
          float v = (r==0)?v0:(r==1)?v1:(r==2)?v2:v3;
          ea.outf[((size_t)(ib*1056 + 1 + p))*512 + col] = v + ea.pe[(size_t)p*512 + col];
        }
      }
    }
  }
}

// ---------------- fused self-attention v6: 16x16 MFMA, swapped QK^T,
// in-register softmax, defer-max, last-tile masking, and NEW: cooperative
// double-buffered LDS staging of K/V tiles shared by the block's 4 waves
// (coalesced global_load_lds, XOR-swizzled both sides) — kills the 4x line
// amplification + 4x duplicate streaming that made v3+ L2-BW-bound.
__global__ __launch_bounds__(256)
void k_attn(const short* __restrict__ qkv, const short* __restrict__ vT, short* __restrict__ aout)
{
  __shared__ __align__(16) short Kl[2][32*64];   // K tile: 32 tok x 64 d (swizzled slots)
  __shared__ __align__(16) short Vl[2][64*32];   // V tile: 64 d x 32 tok (swizzled slots)
  __shared__ short Pl[4][2][32*40];
  __shared__ float Sc[4][2][32];

  const int tid = threadIdx.x;
  const int w  = tid >> 6;
  const int qtR = blockIdx.x * 4 + w;
  const int qt  = qtR > 32 ? 32 : qtR;      // clamp; all waves stay for barriers
  const int u  = blockIdx.y;
  const int ib = u >> 3, h = u & 7;
  const int l = tid & 63, lr = l & 15, lg = l >> 4;
  const size_t rb = (size_t)ib * 1056;
  const int t0 = qt * 32;

  bf8 qf[2][2];
  #pragma unroll
  for (int nq=0;nq<2;nq++)
    #pragma unroll
    for (int ks=0;ks<2;ks++)
      qf[nq][ks] = *(const bf8*)&qkv[(rb + t0 + nq*16 + lr)*1536 + h*64 + ks*32 + lg*8];

  f4 o[2][4];
  float mrun[2], lrun[2];
  #pragma unroll
  for (int mq=0;mq<2;mq++)
    #pragma unroll
    for (int nd=0;nd<4;nd++){ o[mq][nd][0]=0.f; o[mq][nd][1]=0.f; o[mq][nd][2]=0.f; o[mq][nd][3]=0.f; }
  mrun[0]=mrun[1]=-1e30f; lrun[0]=lrun[1]=0.f;

  // cooperative staging: K rows are 128B contiguous, V rows 64B contiguous.
  // LDS slot s holds global col-slot (s ^ row&mask) -> read with same involution.
  auto STAGE = [&](int buf, int jt){
    const int j0 = jt*32;
    {
      int krow = tid >> 3, ks = tid & 7;
      int gs = ks ^ (krow & 7);
      gload16(&qkv[(rb + j0 + krow)*1536 + 512 + h*64 + gs*8], &Kl[buf][tid*8]);
    }
    {
      int vrow = tid >> 2, vs = tid & 3;
      int gs = vs ^ (vrow & 3);
      gload16(&vT[((size_t)ib*512 + h*64 + vrow)*1056 + j0 + gs*8], &Vl[buf][tid*8]);
    }
  };

  STAGE(0, 0);

  for (int jt=0; jt<=32; jt++){
    const int cur = jt & 1;
    const int pb  = cur;
    const bool MASK = (jt == 32);
    const int j0 = jt*32;
    __syncthreads();   // staged buf[cur] complete; all prev reads of buf[cur^1] done

    // fragments from LDS (swizzle-inverted)
    bf8 kc[2][2], vb[4];
    #pragma unroll
    for (int mk=0;mk<2;mk++)
      #pragma unroll
      for (int ks=0;ks<2;ks++)
        kc[mk][ks] = *(const bf8*)&Kl[cur][((mk*16+lr)*8 + ((ks*4+lg) ^ (lr&7)))*8];
    #pragma unroll
    for (int nd=0;nd<4;nd++)
      vb[nd] = *(const bf8*)&Vl[cur][((nd*16+lr)*4 + (lg ^ (lr&3)))*8];

    if (jt < 32) STAGE(cur^1, jt+1);   // overlaps with compute below

    f4 st[2][2];
    #pragma unroll
    for (int mk=0;mk<2;mk++)
      #pragma unroll
      for (int nq=0;nq<2;nq++){ st[mk][nq][0]=0.f; st[mk][nq][1]=0.f; st[mk][nq][2]=0.f; st[mk][nq][3]=0.f; }
    __builtin_amdgcn_s_setprio(1);
    #pragma unroll
    for (int ks=0;ks<2;ks++)
      #pragma unroll
      for (int mk=0;mk<2;mk++)
        #pragma unroll
        for (int nq=0;nq<2;nq++)
          st[mk][nq] = __builtin_amdgcn_mfma_f32_16x16x32_bf16(kc[mk][ks], qf[nq][ks], st[mk][nq], 0, 0, 0);
    __builtin_amdgcn_s_setprio(0);

    float p8[2][8], mx[2];
    #pragma unroll
    for (int nq=0;nq<2;nq++){
      mx[nq] = -1e30f;
      #pragma unroll
      for (int mk=0;mk<2;mk++)
        #pragma unroll
        for (int r=0;r<4;r++){
          float v = st[mk][nq][r];
          if (MASK){
            int kk = j0 + mk*16 + lg*4 + r;
            v = (kk > 1024) ? -1e30f : v;
          }
          p8[nq][mk*4+r] = v;
          mx[nq] = fmaxf(mx[nq], v);
        }
      mx[nq] = fmaxf(mx[nq], __shfl_xor(mx[nq], 16));
      mx[nq] = fmaxf(mx[nq], __shfl_xor(mx[nq], 32));
    }

    bool ok = (mx[0] <= mrun[0] + 8.f) && (mx[1] <= mrun[1] + 8.f);
    if (__all(ok)){
      // defer path: no max update, no rescale
      #pragma unroll
      for (int nq=0;nq<2;nq++){
        float rs = 0.f;
        #pragma unroll
        for (int i=0;i<8;i++){ float p = __expf(p8[nq][i] - mrun[nq]); p8[nq][i] = p; rs += p; }
        rs += __shfl_xor(rs, 16);
        rs += __shfl_xor(rs, 32);
        lrun[nq] += rs;
        uint32_t* prow = (uint32_t*)&Pl[w][pb][(nq*16 + lr)*40];
        #pragma unroll
        for (int mk=0;mk<2;mk++){
          prow[mk*8 + lg*2]     = cvtpk(p8[nq][mk*4+0], p8[nq][mk*4+1]);
          prow[mk*8 + lg*2 + 1] = cvtpk(p8[nq][mk*4+2], p8[nq][mk*4+3]);
        }
      }
      asm volatile("s_waitcnt lgkmcnt(0)" ::: "memory");
      __builtin_amdgcn_sched_barrier(0);
      bf8 pa[2];
      #pragma unroll
      for (int mq=0;mq<2;mq++) pa[mq] = *(const bf8*)&Pl[w][pb][(mq*16 + lr)*40 + lg*8];
      __builtin_amdgcn_s_setprio(1);
      #pragma unroll
      for (int mq=0;mq<2;mq++)
        #pragma unroll
        for (int nd=0;nd<4;nd++)
          o[mq][nd] = __builtin_amdgcn_mfma_f32_16x16x32_bf16(pa[mq], vb[nd], o[mq][nd], 0, 0, 0);
      __builtin_amdgcn_s_setprio(0);
    } else {
      // full online-softmax path
      #pragma unroll
      for (int nq=0;nq<2;nq++){
        float mn = fmaxf(mrun[nq], mx[nq]);
        float sc = __expf(mrun[nq] - mn);
        mrun[nq] = mn;
        float rs = 0.f;
        #pragma unroll
        for (int i=0;i<8;i++){ float p = __expf(p8[nq][i] - mn); p8[nq][i] = p; rs += p; }
        rs += __shfl_xor(rs, 16);
        rs += __shfl_xor(rs, 32);
        lrun[nq] = lrun[nq]*sc + rs;
        Sc[w][pb][nq*16 + lr] = sc;
        uint32_t* prow = (uint32_t*)&Pl[w][pb][(nq*16 + lr)*40];
        #pragma unroll
        for (int mk=0;mk<2;mk++){
          prow[mk*8 + lg*2]     = cvtpk(p8[nq][mk*4+0], p8[nq][mk*4+1]);
          prow[mk*8 + lg*2 + 1] = cvtpk(p8[nq][mk*4+2], p8[nq][mk*4+3]);
        }
      }
      asm volatile("s_waitcnt lgkmcnt(0)" ::: "memory");
      __builtin_amdgcn_sched_barrier(0);
      f4 scv[2]; bf8 pa[2];
      #pragma unroll
      for (int mq=0;mq<2;mq++){
        scv[mq] = *(const f4*)&Sc[w][pb][mq*16 + lg*4];
        pa[mq]  = *(const bf8*)&Pl[w][pb][(mq*16 + lr)*40 + lg*8];
      }
      #pragma unroll
      for (int mq=0;mq<2;mq++)
        #pragma unroll
        for (int nd=0;nd<4;nd++){
          #pragma unroll
          for (int r=0;r<4;r++) o[mq][nd][r] *= scv[mq][r];
        }
      __builtin_amdgcn_s_setprio(1);
      #pragma unroll
      for (int mq=0;mq<2;mq++)
        #pragma unroll
        for (int nd=0;nd<4;nd++)
          o[mq][nd] = __builtin_amdgcn_mfma_f32_16x16x32_bf16(pa[mq], vb[nd], o[mq][nd], 0, 0, 0);
      __builtin_amdgcn_s_setprio(0);
    }
  }

  if (qtR <= 32){
    // final 1/l normalization: route lrun (per q=nq*16+lr) to o-rows (q=mq*16+lg*4+r)
    #pragma unroll
    for (int nq=0;nq<2;nq++) Sc[w][1][nq*16 + lr] = lrun[nq];
    asm volatile("s_waitcnt lgkmcnt(0)" ::: "memory");
    __builtin_amdgcn_sched_barrier(0);
    #pragma unroll
    for (int mq=0;mq<2;mq++){
      f4 lsv = *(const f4*)&Sc[w][1][mq*16 + lg*4];
      float i0 = __builtin_amdgcn_rcpf(lsv[0]);
      float i1 = __builtin_amdgcn_rcpf(lsv[1]);
      float i2 = __builtin_amdgcn_rcpf(lsv[2]);
      float i3 = __builtin_amdgcn_rcpf(lsv[3]);
      const size_t base = rb + t0 + mq*16 + lg*4;
      #pragma unroll
      for (int nd=0;nd<4;nd++){
        int col = h*64 + nd*16 + lr;
        uint32_t u01 = cvtpk(o[mq][nd][0]*i0, o[mq][nd][1]*i1);
        uint32_t u23 = cvtpk(o[mq][nd][2]*i2, o[mq][nd][3]*i3);
        aout[(base+0)*512 + col] = (short)u01;
        aout[(base+1)*512 + col] = (short)(u01>>16);
        aout[(base+2)*512 + col] = (short)u23;
        aout[(base+3)*512 + col] = (short)(u23>>16);
      }
    }
  }
}

// ---------------- cross-attention path (tiny, fp32)
__global__ __launch_bounds__(256)
void k_cross_q(const float* __restrict__ x, const float* __restrict__ Wq, float* __restrict__ qc)
{
  __shared__ float xs[512];
  int ib = blockIdx.x;
  const float* xr = x + (size_t)ib*1056*512;
  for (int e=threadIdx.x;e<512;e+=256) xs[e] = xr[e];
  __syncthreads();
  for (int n=threadIdx.x;n<512;n+=256){
    float acc = 0.f;
    for (int k=0;k<512;k++) acc += xs[k]*Wq[(size_t)k*512 + n];
    qc[(size_t)ib*512 + n] = acc;
  }
}

__global__ __launch_bounds__(64)
void k_cross_attn(const float* __restrict__ qc, const short* __restrict__ kv, float* __restrict__ oc)
{
  int u = blockIdx.x; int ib = u >> 3, h = u & 7;
  int img = ib >> 3, b = ib & 7;
  int sib = (1 - img)*8 + b;
  int l = threadIdx.x;
  __shared__ float qs[64];
  __shared__ float pl[1024];
  qs[l] = qc[(size_t)ib*512 + h*64 + l];
  __syncthreads();
  float lmax = -1e30f;
  for (int jj=0; jj<16; jj++){
    int j = jj*64 + l;
    const short* kr = kv + ((size_t)(sib*1056 + 1 + j))*1024 + h*64;
    float acc = 0.f;
    for (int d=0; d<64; d++) acc += qs[d]*bf2f(kr[d]);
    acc *= 0.125f;
    pl[j] = acc;
    lmax = fmaxf(lmax, acc);
  }
  #pragma unroll
  for (int m=1;m<64;m<<=1) lmax = fmaxf(lmax, __shfl_xor(lmax, m));
  __syncthreads();
  float lsum = 0.f;
  for (int jj=0; jj<16; jj++){
    int j = jj*64 + l;
    float p = __expf(pl[j] - lmax);
    pl[j] = p; lsum += p;
  }
  #pragma unroll
  for (int m=1;m<64;m<<=1) lsum += __shfl_xor(lsum, m);
  __syncthreads();
  float acc = 0.f;
  for (int j=0;j<1024;j++)
    acc += pl[j] * bf2f(kv[((size_t)(sib*1056 + 1 + j))*1024 + 512 + h*64 + l]);
  oc[(size_t)ib*512 + h*64 + l] = acc / lsum;
}

__global__ __launch_bounds__(256)
void k_cross_out(const float* __restrict__ x, const float* __restrict__ oc,
                 const float* __restrict__ Wo, float* __restrict__ cn)
{
  __shared__ float os[512];
  int ib = blockIdx.x;
  for (int e=threadIdx.x;e<512;e+=256) os[e] = oc[(size_t)ib*512+e];
  __syncthreads();
  for (int n=threadIdx.x;n<512;n+=256){
    float acc = 0.f;
    for (int k=0;k<512;k++) acc += os[k]*Wo[(size_t)k*512+n];
    cn[(size_t)ib*512+n] = x[(size_t)ib*1056*512 + n] + acc;
  }
}

__global__ __launch_bounds__(256)
void k_final(const float* __restrict__ cn, const float* __restrict__ nfg, const float* __restrict__ nfb,
             const float* __restrict__ Wdec, const float* __restrict__ bdec, float* __restrict__ out)
{
  int b = blockIdx.x;
  __shared__ float a[512];
  __shared__ float an[512];
  __shared__ float red[8];
  int tid = threadIdx.x;
  float s = 0.f, q = 0.f;
  for (int e=tid;e<512;e+=256){
    float av = 0.5f*(cn[(size_t)b*512 + e] + cn[(size_t)(8+b)*512 + e]);
    a[e] = av; s += av; q += av*av;
  }
  #pragma unroll
  for (int m=1;m<64;m<<=1){ s += __shfl_xor(s,m); q += __shfl_xor(q,m); }
  int w = tid>>6;
  if ((tid&63)==0){ red[w] = s; red[4+w] = q; }
  __syncthreads();
  s = red[0]+red[1]+red[2]+red[3];
  q = red[4]+red[5]+red[6]+red[7];
  float mu = s*0.001953125f;
  float var = q*0.001953125f - mu*mu;
  float rstd = rsqrtf(var + 1e-6f);
  for (int e=tid;e<512;e+=256) an[e] = nfg[e]*(a[e]-mu)*rstd + nfb[e];
  __syncthreads();
  for (int n=tid;n<1024;n+=256){
    float acc = bdec[n];
    for (int e=0;e<512;e++) acc += an[e]*Wdec[(size_t)e*1024 + n];
    out[(size_t)b*1024 + n] = acc;
  }
}

// =======================================================================
extern "C" void kernel_launch(void* const* d_in, const int* in_sizes, int n_in,
                              void* d_out, int out_size, void* d_ws, size_t ws_size,
                              hipStream_t stream)
{
  (void)in_sizes; (void)n_in;
  const float* img1 = (const float*)d_in[0];
  const float* img2 = (const float*)d_in[1];
  const float* patchW = (const float*)d_in[2];
  const float* cls_t = (const float*)d_in[3];
  const float* cls_p = (const float*)d_in[4];
  const float* ln1g = (const float*)d_in[5];
  const float* ln1b = (const float*)d_in[6];
  const float* Wqkv = (const float*)d_in[7];
  const float* Wo   = (const float*)d_in[8];
  const float* ln2g = (const float*)d_in[9];
  const float* ln2b = (const float*)d_in[10];
  const float* W1   = (const float*)d_in[11];
  const float* b1   = (const float*)d_in[12];
  const float* W2   = (const float*)d_in[13];
  const float* b2   = (const float*)d_in[14];
  const float* Wqc  = (const float*)d_in[15];
  const float* Wkvc = (const float*)d_in[16];
  const float* Woc  = (const float*)d_in[17];
  const float* nfg  = (const float*)d_in[18];
  const float* nfb  = (const float*)d_in[19];
  const float* Wdec = (const float*)d_in[20];
  const float* bdec = (const float*)d_in[21];
  float* out = (float*)d_out;

  // ---- compact aliased workspace layout (bytes) ----
  const size_t offA = 34603008, offB = 51904512, offC = 121110528, offD = 148111360;
  const size_t NEEDED = 148209664;
  if (ws_size < NEEDED){
    hipMemsetAsync(d_out, 0, (size_t)out_size*sizeof(float), stream);
    return;
  }
  char* ws = (char*)d_ws;
  float* x    = (float*)ws;
  short* y    = (short*)(ws + offA);
  short* attn = y;
  short* qkv  = (short*)(ws + offB);
  short* vT   = (short*)(ws + offB + 51904512);
  short* mh   = (short*)(ws + offB);
  short* patches = (short*)(ws + offB);
  float* pe   = (float*)(ws + offB + 25165824);
  short* kvc  = (short*)(ws + offB);
  short* wts  = (short*)(ws + offC);
  float* qc   = (float*)(ws + offD);
  float* oc   = (float*)(ws + offD + 32768);
  float* cn   = (float*)(ws + offD + 65536);

  short* patchWt = wts;              // [512][768]
  short* WqkvT = wts + 393216;       // 4 x [1536][512]
  short* WoT   = wts + 3538944;      // 4 x [512][512]
  short* W1T   = wts + 4587520;      // 4 x [2048][512]
  short* W2T   = wts + 8781824;      // 4 x [512][2048]
  short* WkvT  = wts + 12976128;     // [1024][512]

  dim3 tb(32,8,1);
  k_transpose<<<dim3(16,24,1), tb, 0, stream>>>(patchW, patchWt, 768, 512, (size_t)768*512);
  k_transpose<<<dim3(48,16,4), tb, 0, stream>>>(Wqkv, WqkvT, 512, 1536, (size_t)512*1536);
  k_transpose<<<dim3(16,16,4), tb, 0, stream>>>(Wo,   WoT,   512, 512,  (size_t)512*512);
  k_transpose<<<dim3(64,16,4), tb, 0, stream>>>(W1,   W1T,   512, 2048, (size_t)512*2048);
  k_transpose<<<dim3(16,64,4), tb, 0, stream>>>(W2,   W2T,   2048, 512, (size_t)2048*512);
  k_transpose<<<dim3(32,16,1), tb, 0, stream>>>(Wkvc, WkvT,  512, 1024, (size_t)512*1024);

  k_pe<<<1024, 256, 0, stream>>>(pe);
  k_gather<<<16384, 256, 0, stream>>>(img1, img2, patches);
  k_zeropad<<<496, 512, 0, stream>>>(x);
  k_cls<<<16, 512, 0, stream>>>(cls_t, cls_p, x);

  EpiArgs ea;
  // patch embedding: x[:,1:1025,:] = patches @ patchW + pe
  ea = EpiArgs{nullptr, x, nullptr, pe, nullptr};
  k_gemm<4><<<dim3(4, 128), 256, 0, stream>>>(patches, patchWt, 16384, 512, 768, ea);

  for (int i=0;i<4;i++){
    k_layernorm<<<4224, 256, 0, stream>>>(x, y, ln1g + i*512, ln1b + i*512);
    ea = EpiArgs{qkv, nullptr, nullptr, nullptr, vT};
    k_gemm<1><<<dim3(12, 132), 256, 0, stream>>>(y, WqkvT + (size_t)i*1536*512, 16896, 1536, 512, ea);
    k_attn<<<dim3(9, 128), 256, 0, stream>>>(qkv, vT, attn);
    ea = EpiArgs{nullptr, x, nullptr, nullptr, nullptr};
    k_gemm<2><<<dim3(4, 132), 256, 0, stream>>>(attn, WoT + (size_t)i*512*512, 16896, 512, 512, ea);
    k_layernorm<<<4224, 256, 0, stream>>>(x, y, ln2g + i*512, ln2b + i*512);
    ea = EpiArgs{mh, nullptr, b1 + i*2048, nullptr, nullptr};
    k_gemm<3><<<dim3(16, 132), 256, 0, stream>>>(y, W1T + (size_t)i*2048*512, 16896, 2048, 512, ea);
    ea = EpiArgs{nullptr, x, b2 + i*512, nullptr, nullptr};
    k_gemm<2><<<dim3(4, 132), 256, 0, stream>>>(mh, W2T + (size_t)i*512*2048, 16896, 512, 2048, ea);
  }

  // cross attention between cls tokens and the other image's tokens
  k_cast_bf16<<<4224, 256, 0, stream>>>(x, y);
  ea = EpiArgs{kvc, nullptr, nullptr, nullptr, nullptr};
  k_gemm<0><<<dim3(8, 132), 256, 0, stream>>>(y, WkvT, 16896, 1024, 512, ea);
  k_cross_q<<<16, 256, 0, stream>>>(x, Wqc, qc);
  k_cross_attn<<<128, 64, 0, stream>>>(qc, kvc, oc);
  k_cross_out<<<16, 256, 0, stream>>>(x, oc, Woc, cn);
  k_final<<<8, 256, 0, stream>>>(cn, nfg, nfb, Wdec, bdec, out);
}

// Round 9
// 1577.649 us; speedup vs baseline: 1.5279x; 1.0285x over previous
//
#include <hip/hip_runtime.h>
#include <stdint.h>
#include <math.h>

typedef __attribute__((ext_vector_type(4))) float f4;
typedef __attribute__((ext_vector_type(8))) __bf16 bf8;
typedef __attribute__((ext_vector_type(8))) short s8;
typedef __attribute__((ext_vector_type(4))) uint32_t u32x4;

#define DI __device__ __forceinline__

DI short f2bf(float f){
  union { float f; uint32_t u; } v; v.f = f;
  uint32_t r = v.u + 0x7fffu + ((v.u >> 16) & 1u);
  return (short)(r >> 16);
}
DI float bf2f(short s){
  union { uint32_t u; float f; } v; v.u = ((uint32_t)(uint16_t)s) << 16;
  return v.f;
}
// packed f32x2 -> bf16x2 (RNE), lo = first arg
DI uint32_t cvtpk(float lo, float hi){
  uint32_t r;
  asm("v_cvt_pk_bf16_f32 %0, %1, %2" : "=v"(r) : "v"(lo), "v"(hi));
  return r;
}
// gelu-tanh == u * sigmoid(2c(u + 0.044715 u^3)), c = 0.7978845608
DI float gelu_f(float u){
  float z = 1.5957691216057308f * u * fmaf(0.044715f, u*u, 1.f);
  return u * __builtin_amdgcn_rcpf(1.f + __expf(-z));
}
DI void gload16(const void* g, void* l){
  __builtin_amdgcn_global_load_lds((const __attribute__((address_space(1))) unsigned*)g,
                                   (__attribute__((address_space(3))) unsigned*)l, 16, 0, 0);
}

// ---------------- transpose + f32->bf16 convert: in [K][N] f32 -> out [N][K] bf16
// launch grid = (N/32, K/32, z)
__global__ __launch_bounds__(256)
void k_transpose(const float* __restrict__ in, short* __restrict__ out, int K, int N, size_t stride)
{
  __shared__ float t[32][33];
  in  += (size_t)blockIdx.z * stride;
  out += (size_t)blockIdx.z * stride;
  int n0 = blockIdx.x*32, k0 = blockIdx.y*32;
  int tx = threadIdx.x, ty = threadIdx.y;
  #pragma unroll
  for (int i=0;i<32;i+=8) t[ty+i][tx] = in[(size_t)(k0+ty+i)*N + n0+tx];
  __syncthreads();
  #pragma unroll
  for (int i=0;i<32;i+=8) out[(size_t)(n0+ty+i)*K + k0+tx] = f2bf(t[tx][ty+i]);
}

// ---------------- sinusoidal positional table pe[1024][512] f32
__global__ void k_pe(float* __restrict__ pe)
{
  int p = blockIdx.x;
  for (int d = threadIdx.x; d < 512; d += 256){
    int j = (d < 256) ? d : d - 256;
    float div = expf((float)(2*j) * (-9.210340371976184f/512.f));
    float a = (float)p * div;
    pe[(size_t)p*512 + d] = (d < 256) ? sinf(a) : cosf(a);
  }
}

// ---------------- patch gather: img NHWC f32 -> patches[16384][768] bf16
__global__ __launch_bounds__(256)
void k_gather(const float* __restrict__ img1, const float* __restrict__ img2, short* __restrict__ patches)
{
  int row = blockIdx.x;              // (img*8 + b)*1024 + p
  int img = row >> 13;
  int b   = (row >> 10) & 7;
  int p   = row & 1023;
  int ph = p >> 5, pw = p & 31;
  const float* src = (img ? img2 : img1) + (size_t)b*512*512*3;
  short* dst = patches + (size_t)row*768;
  for (int k = threadIdx.x; k < 768; k += 256){
    int i = k / 48; int rem = k - i*48; int j = rem / 3; int c = rem - j*3;
    int yy = ph*16 + i, xx = pw*16 + j;
    dst[k] = f2bf(src[((size_t)yy*512 + xx)*3 + c]);
  }
}

// ---------------- zero pad token rows of x, set cls rows
__global__ void k_zeropad(float* __restrict__ x)
{
  int idx = blockIdx.x; int ib = idx / 31; int t = 1025 + (idx - ib*31);
  x[((size_t)ib*1056 + t)*512 + threadIdx.x] = 0.f;
}
__global__ void k_cls(const float* __restrict__ ct, const float* __restrict__ cp, float* __restrict__ x)
{
  int ib = blockIdx.x; int e = threadIdx.x;
  x[(size_t)ib*1056*512 + e] = ct[e] + cp[e];
}

// ---------------- layernorm rows of x (fp32) -> y (bf16). 4 rows/block, 1 wave per row.
__global__ __launch_bounds__(256)
void k_layernorm(const float* __restrict__ x, short* __restrict__ y,
                 const float* __restrict__ g, const float* __restrict__ b)
{
  int row = blockIdx.x*4 + (threadIdx.x>>6);
  int l = threadIdx.x & 63;
  const float* xr = x + (size_t)row*512 + l*8;
  f4 v0 = *(const f4*)xr;
  f4 v1 = *(const f4*)(xr+4);
  float s = v0[0]+v0[1]+v0[2]+v0[3]+v1[0]+v1[1]+v1[2]+v1[3];
  float q = v0[0]*v0[0]+v0[1]*v0[1]+v0[2]*v0[2]+v0[3]*v0[3]
          + v1[0]*v1[0]+v1[1]*v1[1]+v1[2]*v1[2]+v1[3]*v1[3];
  #pragma unroll
  for (int m=1;m<64;m<<=1){ s += __shfl_xor(s,m); q += __shfl_xor(q,m); }
  float mu = s * 0.001953125f;
  float var = q * 0.001953125f - mu*mu;
  float rstd = rsqrtf(var + 1e-6f);
  const float* gp = g + l*8;
  const float* bp = b + l*8;
  float ov[8];
  #pragma unroll
  for (int j=0;j<8;j++){
    float xv = (j<4) ? v0[j] : v1[j-4];
    ov[j] = gp[j]*(xv-mu)*rstd + bp[j];
  }
  u32x4 pk;
  #pragma unroll
  for (int j=0;j<4;j++) pk[j] = cvtpk(ov[2*j], ov[2*j+1]);
  *(u32x4*)(y + (size_t)row*512 + l*8) = pk;
}

// ---------------- straight f32 -> bf16 cast (8 elems/thread)
__global__ void k_cast_bf16(const float* __restrict__ in, short* __restrict__ out)
{
  size_t i = (size_t)blockIdx.x*256 + threadIdx.x;
  const float* p = in + i*8;
  u32x4 pk;
  #pragma unroll
  for (int j=0;j<4;j++) pk[j] = cvtpk(p[2*j], p[2*j+1]);
  *(u32x4*)(out + i*8) = pk;
}

// ---------------- bf16 MFMA GEMM, 128x128 tile, BK=64, A[M][K], Bt[N][K]
// 1-D grid + bijective XCD-chunked swizzle (nwg divisible by 8).
// LDS XOR-swizzled (both sides: pre-swizzled global src + swizzled ds_read).
// EPI: 0=bf16 out, 1=bf16 out + q-prescale(1/8*log2e) + vT scatter (QKV),
//      2=f32 residual add (+bias), 3=bias+gelu->bf16, 4=embed(+pe)->x
struct EpiArgs { short* outb; float* outf; const float* bias; const float* pe; short* vT; };

template<int EPI>
__global__ __launch_bounds__(256)
void k_gemm(const short* __restrict__ A, const short* __restrict__ Bt,
            int M, int N, int K, int gridX, EpiArgs ea)
{
  __shared__ short Al[128*64];
  __shared__ short Bl[128*64];
  const int tid = threadIdx.x;
  const int l = tid & 63;
  const int w = tid >> 6;
  const int wr = (w >> 1) * 64, wc = (w & 1) * 64;
  const int lr = l & 15, lg = l >> 4;
  // XCD-chunked bijective swizzle: blocks on XCD c compute a contiguous tile range
  const int nwg = gridDim.x;
  const int q8 = nwg >> 3;
  const int nb = (blockIdx.x & 7) * q8 + (blockIdx.x >> 3);
  const int brow = (nb / gridX) * 128, bcol = (nb % gridX) * 128;
  const short* Ab = A  + (size_t)brow * K;
  const short* Bb = Bt + (size_t)bcol * K;
  f4 acc[4][4];
  #pragma unroll
  for (int m=0;m<4;m++)
    #pragma unroll
    for (int n=0;n<4;n++){ acc[m][n][0]=0.f; acc[m][n][1]=0.f; acc[m][n][2]=0.f; acc[m][n][3]=0.f; }

  // read-side swizzled col-slot per thread (involution: slot ^ (row&7))
  const int rsw = lr & 7;
  for (int kt = 0; kt < K; kt += 64){
    #pragma unroll
    for (int i=0;i<4;i++){
      int s   = i*256 + tid;
      int row = s >> 3;
      int gs  = (s & 7) ^ (row & 7);
      gload16(Ab + (size_t)row*K + kt + gs*8, &Al[s*8]);
      gload16(Bb + (size_t)row*K + kt + gs*8, &Bl[s*8]);
    }
    __syncthreads();
    #pragma unroll
    for (int ko=0;ko<2;ko++){
      bf8 af[4], bfr[4];
      const int ps = ((ko*4 + lg) ^ rsw) * 8;
      #pragma unroll
      for (int m=0;m<4;m++) af[m]  = *(const bf8*)&Al[(wr + m*16 + lr)*64 + ps];
      #pragma unroll
      for (int n=0;n<4;n++) bfr[n] = *(const bf8*)&Bl[(wc + n*16 + lr)*64 + ps];
      #pragma unroll
      for (int m=0;m<4;m++)
        #pragma unroll
        for (int n=0;n<4;n++)
          acc[m][n] = __builtin_amdgcn_mfma_f32_16x16x32_bf16(af[m], bfr[n], acc[m][n], 0, 0, 0);
    }
    __syncthreads();
  }

  #pragma unroll
  for (int m=0;m<4;m++){
    #pragma unroll
    for (int n=0;n<4;n++){
      const int row0 = brow + wr + m*16 + lg*4;
      const int col  = bcol + wc + n*16 + lr;
      float v0 = acc[m][n][0], v1 = acc[m][n][1], v2 = acc[m][n][2], v3 = acc[m][n][3];
      if (EPI == 0 || EPI == 1){
        if (EPI == 1 && col < 512){
          // 1/8 * log2(e): softmax runs in exp2 domain
          const float qs = 0.1803368801111204f;
          v0*=qs; v1*=qs; v2*=qs; v3*=qs;
        }
        uint32_t u01 = cvtpk(v0, v1), u23 = cvtpk(v2, v3);
        short s0 = (short)u01, s1 = (short)(u01>>16), s2 = (short)u23, s3 = (short)(u23>>16);
        ea.outb[(size_t)(row0+0)*N + col] = s0;
        ea.outb[(size_t)(row0+1)*N + col] = s1;
        ea.outb[(size_t)(row0+2)*N + col] = s2;
        ea.outb[(size_t)(row0+3)*N + col] = s3;
        if (EPI == 1 && col >= 1024){
          int ib = row0 / 1056, t = row0 - ib*1056;
          short* vtb = ea.vT + ((size_t)ib*512 + (col - 1024))*1056;
          vtb[t] = s0; vtb[t+1] = s1; vtb[t+2] = s2; vtb[t+3] = s3;
        }
      } else if (EPI == 2){
        float bv = ea.bias ? ea.bias[col] : 0.f;
        ea.outf[(size_t)(row0+0)*N + col] += v0 + bv;
        ea.outf[(size_t)(row0+1)*N + col] += v1 + bv;
        ea.outf[(size_t)(row0+2)*N + col] += v2 + bv;
        ea.outf[(size_t)(row0+3)*N + col] += v3 + bv;
      } else if (EPI == 3){
        float bv = ea.bias[col];
        float g0 = gelu_f(v0+bv), g1 = gelu_f(v1+bv), g2 = gelu_f(v2+bv), g3 = gelu_f(v3+bv);
        uint32_t u01 = cvtpk(g0, g1), u23 = cvtpk(g2, g3);
        ea.outb[(size_t)(row0+0)*N + col] = (short)u01;
        ea.outb[(size_t)(row0+1)*N + col] = (short)(u01>>16);
        ea.outb[(size_t)(row0+2)*N + col] = (short)u23;
        ea.outb[(size_t)(row0+3)*N + col] = (short)(u23>>16);
      } else if (EPI == 4){
        #pragma unroll
        for (int r=0;r<4;r++){
          int row = row0 + r;
          int ib = row >> 10, p = row & 1023;
          float v = (r==0)?v0:(r==1)?v1:(r==2)?v2:v3;
          ea.outf[((size_t)(ib*1056 + 1 + p))*512 + col] = v + ea.pe[(size_t)p*512 + col];
        }
      }
    }
  }
}

// ---------------- fused self-attention v6b: 16x16 MFMA, swapped QK^T in exp2
// domain (Q pre-scaled by log2e/8), in-register softmax, defer-max, last-tile
// masking, cooperative double-buffered LDS K/V staging shared by 4 waves.
__global__ __launch_bounds__(256)
void k_attn(const short* __restrict__ qkv, const short* __restrict__ vT, short* __restrict__ aout)
{
  __shared__ __align__(16) short Kl[2][32*64];   // K tile: 32 tok x 64 d (swizzled slots)
  __shared__ __align__(16) short Vl[2][64*32];   // V tile: 64 d x 32 tok (swizzled slots)
  __shared__ short Pl[4][2][32*40];
  __shared__ float Sc[4][2][32];

  const int tid = threadIdx.x;
  const int w  = tid >> 6;
  const int qtR = blockIdx.x * 4 + w;
  const int qt  = qtR > 32 ? 32 : qtR;      // clamp; all waves stay for barriers
  const int u  = blockIdx.y;
  const int ib = u >> 3, h = u & 7;
  const int l = tid & 63, lr = l & 15, lg = l >> 4;
  const size_t rb = (size_t)ib * 1056;
  const int t0 = qt * 32;
  const float DEFER_THR = 11.541560327111707f;   // 8 * log2(e)

  bf8 qf[2][2];
  #pragma unroll
  for (int nq=0;nq<2;nq++)
    #pragma unroll
    for (int ks=0;ks<2;ks++)
      qf[nq][ks] = *(const bf8*)&qkv[(rb + t0 + nq*16 + lr)*1536 + h*64 + ks*32 + lg*8];

  f4 o[2][4];
  float mrun[2], lrun[2];
  #pragma unroll
  for (int mq=0;mq<2;mq++)
    #pragma unroll
    for (int nd=0;nd<4;nd++){ o[mq][nd][0]=0.f; o[mq][nd][1]=0.f; o[mq][nd][2]=0.f; o[mq][nd][3]=0.f; }
  mrun[0]=mrun[1]=-1e30f; lrun[0]=lrun[1]=0.f;

  // cooperative staging: K rows are 128B contiguous, V rows 64B contiguous.
  // LDS slot s holds global col-slot (s ^ row&mask) -> read with same involution.
  auto STAGE = [&](int buf, int jt){
    const int j0 = jt*32;
    {
      int krow = tid >> 3, ks = tid & 7;
      int gs = ks ^ (krow & 7);
      gload16(&qkv[(rb + j0 + krow)*1536 + 512 + h*64 + gs*8], &Kl[buf][tid*8]);
    }
    {
      int vrow = tid >> 2, vs = tid & 3;
      int gs = vs ^ (vrow & 3);
      gload16(&vT[((size_t)ib*512 + h*64 + vrow)*1056 + j0 + gs*8], &Vl[buf][tid*8]);
    }
  };

  STAGE(0, 0);

  for (int jt=0; jt<=32; jt++){
    const int cur = jt & 1;
    const int pb  = cur;
    const bool MASK = (jt == 32);
    const int j0 = jt*32;
    __syncthreads();   // staged buf[cur] complete; all prev reads of buf[cur^1] done

    // fragments from LDS (swizzle-inverted)
    bf8 kc[2][2], vb[4];
    #pragma unroll
    for (int mk=0;mk<2;mk++)
      #pragma unroll
      for (int ks=0;ks<2;ks++)
        kc[mk][ks] = *(const bf8*)&Kl[cur][((mk*16+lr)*8 + ((ks*4+lg) ^ (lr&7)))*8];
    #pragma unroll
    for (int nd=0;nd<4;nd++)
      vb[nd] = *(const bf8*)&Vl[cur][((nd*16+lr)*4 + (lg ^ (lr&3)))*8];

    if (jt < 32) STAGE(cur^1, jt+1);   // overlaps with compute below

    f4 st[2][2];
    #pragma unroll
    for (int mk=0;mk<2;mk++)
      #pragma unroll
      for (int nq=0;nq<2;nq++){ st[mk][nq][0]=0.f; st[mk][nq][1]=0.f; st[mk][nq][2]=0.f; st[mk][nq][3]=0.f; }
    __builtin_amdgcn_s_setprio(1);
    #pragma unroll
    for (int ks=0;ks<2;ks++)
      #pragma unroll
      for (int mk=0;mk<2;mk++)
        #pragma unroll
        for (int nq=0;nq<2;nq++)
          st[mk][nq] = __builtin_amdgcn_mfma_f32_16x16x32_bf16(kc[mk][ks], qf[nq][ks], st[mk][nq], 0, 0, 0);
    __builtin_amdgcn_s_setprio(0);

    float p8[2][8], mx[2];
    #pragma unroll
    for (int nq=0;nq<2;nq++){
      mx[nq] = -1e30f;
      #pragma unroll
      for (int mk=0;mk<2;mk++)
        #pragma unroll
        for (int r=0;r<4;r++){
          float v = st[mk][nq][r];
          if (MASK){
            int kk = j0 + mk*16 + lg*4 + r;
            v = (kk > 1024) ? -1e30f : v;
          }
          p8[nq][mk*4+r] = v;
          mx[nq] = fmaxf(mx[nq], v);
        }
      mx[nq] = fmaxf(mx[nq], __shfl_xor(mx[nq], 16));
      mx[nq] = fmaxf(mx[nq], __shfl_xor(mx[nq], 32));
    }

    bool ok = (mx[0] <= mrun[0] + DEFER_THR) && (mx[1] <= mrun[1] + DEFER_THR);
    if (__all(ok)){
      // defer path: no max update, no rescale
      #pragma unroll
      for (int nq=0;nq<2;nq++){
        float rs = 0.f;
        #pragma unroll
        for (int i=0;i<8;i++){ float p = exp2f(p8[nq][i] - mrun[nq]); p8[nq][i] = p; rs += p; }
        rs += __shfl_xor(rs, 16);
        rs += __shfl_xor(rs, 32);
        lrun[nq] += rs;
        uint32_t* prow = (uint32_t*)&Pl[w][pb][(nq*16 + lr)*40];
        #pragma unroll
        for (int mk=0;mk<2;mk++){
          prow[mk*8 + lg*2]     = cvtpk(p8[nq][mk*4+0], p8[nq][mk*4+1]);
          prow[mk*8 + lg*2 + 1] = cvtpk(p8[nq][mk*4+2], p8[nq][mk*4+3]);
        }
      }
      asm volatile("s_waitcnt lgkmcnt(0)" ::: "memory");
      __builtin_amdgcn_sched_barrier(0);
      bf8 pa[2];
      #pragma unroll
      for (int mq=0;mq<2;mq++) pa[mq] = *(const bf8*)&Pl[w][pb][(mq*16 + lr)*40 + lg*8];
      __builtin_amdgcn_s_setprio(1);
      #pragma unroll
      for (int mq=0;mq<2;mq++)
        #pragma unroll
        for (int nd=0;nd<4;nd++)
          o[mq][nd] = __builtin_amdgcn_mfma_f32_16x16x32_bf16(pa[mq], vb[nd], o[mq][nd], 0, 0, 0);
      __builtin_amdgcn_s_setprio(0);
    } else {
      // full online-softmax path
      #pragma unroll
      for (int nq=0;nq<2;nq++){
        float mn = fmaxf(mrun[nq], mx[nq]);
        float sc = exp2f(mrun[nq] - mn);
        mrun[nq] = mn;
        float rs = 0.f;
        #pragma unroll
        for (int i=0;i<8;i++){ float p = exp2f(p8[nq][i] - mn); p8[nq][i] = p; rs += p; }
        rs += __shfl_xor(rs, 16);
        rs += __shfl_xor(rs, 32);
        lrun[nq] = lrun[nq]*sc + rs;
        Sc[w][pb][nq*16 + lr] = sc;
        uint32_t* prow = (uint32_t*)&Pl[w][pb][(nq*16 + lr)*40];
        #pragma unroll
        for (int mk=0;mk<2;mk++){
          prow[mk*8 + lg*2]     = cvtpk(p8[nq][mk*4+0], p8[nq][mk*4+1]);
          prow[mk*8 + lg*2 + 1] = cvtpk(p8[nq][mk*4+2], p8[nq][mk*4+3]);
        }
      }
      asm volatile("s_waitcnt lgkmcnt(0)" ::: "memory");
      __builtin_amdgcn_sched_barrier(0);
      f4 scv[2]; bf8 pa[2];
      #pragma unroll
      for (int mq=0;mq<2;mq++){
        scv[mq] = *(const f4*)&Sc[w][pb][mq*16 + lg*4];
        pa[mq]  = *(const bf8*)&Pl[w][pb][(mq*16 + lr)*40 + lg*8];
      }
      #pragma unroll
      for (int mq=0;mq<2;mq++)
        #pragma unroll
        for (int nd=0;nd<4;nd++){
          #pragma unroll
          for (int r=0;r<4;r++) o[mq][nd][r] *= scv[mq][r];
        }
      __builtin_amdgcn_s_setprio(1);
      #pragma unroll
      for (int mq=0;mq<2;mq++)
        #pragma unroll
        for (int nd=0;nd<4;nd++)
          o[mq][nd] = __builtin_amdgcn_mfma_f32_16x16x32_bf16(pa[mq], vb[nd], o[mq][nd], 0, 0, 0);
      __builtin_amdgcn_s_setprio(0);
    }
  }

  if (qtR <= 32){
    // final 1/l normalization: route lrun (per q=nq*16+lr) to o-rows (q=mq*16+lg*4+r)
    #pragma unroll
    for (int nq=0;nq<2;nq++) Sc[w][1][nq*16 + lr] = lrun[nq];
    asm volatile("s_waitcnt lgkmcnt(0)" ::: "memory");
    __builtin_amdgcn_sched_barrier(0);
    #pragma unroll
    for (int mq=0;mq<2;mq++){
      f4 lsv = *(const f4*)&Sc[w][1][mq*16 + lg*4];
      float i0 = __builtin_amdgcn_rcpf(lsv[0]);
      float i1 = __builtin_amdgcn_rcpf(lsv[1]);
      float i2 = __builtin_amdgcn_rcpf(lsv[2]);
      float i3 = __builtin_amdgcn_rcpf(lsv[3]);
      const size_t base = rb + t0 + mq*16 + lg*4;
      #pragma unroll
      for (int nd=0;nd<4;nd++){
        int col = h*64 + nd*16 + lr;
        uint32_t u01 = cvtpk(o[mq][nd][0]*i0, o[mq][nd][1]*i1);
        uint32_t u23 = cvtpk(o[mq][nd][2]*i2, o[mq][nd][3]*i3);
        aout[(base+0)*512 + col] = (short)u01;
        aout[(base+1)*512 + col] = (short)(u01>>16);
        aout[(base+2)*512 + col] = (short)u23;
        aout[(base+3)*512 + col] = (short)(u23>>16);
      }
    }
  }
}

// ---------------- cross-attention path (tiny, fp32)
__global__ __launch_bounds__(256)
void k_cross_q(const float* __restrict__ x, const float* __restrict__ Wq, float* __restrict__ qc)
{
  __shared__ float xs[512];
  int ib = blockIdx.x;
  const float* xr = x + (size_t)ib*1056*512;
  for (int e=threadIdx.x;e<512;e+=256) xs[e] = xr[e];
  __syncthreads();
  for (int n=threadIdx.x;n<512;n+=256){
    float acc = 0.f;
    for (int k=0;k<512;k++) acc += xs[k]*Wq[(size_t)k*512 + n];
    qc[(size_t)ib*512 + n] = acc;
  }
}

__global__ __launch_bounds__(64)
void k_cross_attn(const float* __restrict__ qc, const short* __restrict__ kv, float* __restrict__ oc)
{
  int u = blockIdx.x; int ib = u >> 3, h = u & 7;
  int img = ib >> 3, b = ib & 7;
  int sib = (1 - img)*8 + b;
  int l = threadIdx.x;
  __shared__ float qs[64];
  __shared__ float pl[1024];
  qs[l] = qc[(size_t)ib*512 + h*64 + l];
  __syncthreads();
  float lmax = -1e30f;
  for (int jj=0; jj<16; jj++){
    int j = jj*64 + l;
    const short* kr = kv + ((size_t)(sib*1056 + 1 + j))*1024 + h*64;
    float acc = 0.f;
    for (int d=0; d<64; d++) acc += qs[d]*bf2f(kr[d]);
    acc *= 0.125f;
    pl[j] = acc;
    lmax = fmaxf(lmax, acc);
  }
  #pragma unroll
  for (int m=1;m<64;m<<=1) lmax = fmaxf(lmax, __shfl_xor(lmax, m));
  __syncthreads();
  float lsum = 0.f;
  for (int jj=0; jj<16; jj++){
    int j = jj*64 + l;
    float p = __expf(pl[j] - lmax);
    pl[j] = p; lsum += p;
  }
  #pragma unroll
  for (int m=1;m<64;m<<=1) lsum += __shfl_xor(lsum, m);
  __syncthreads();
  float acc = 0.f;
  for (int j=0;j<1024;j++)
    acc += pl[j] * bf2f(kv[((size_t)(sib*1056 + 1 + j))*1024 + 512 + h*64 + l]);
  oc[(size_t)ib*512 + h*64 + l] = acc / lsum;
}

__global__ __launch_bounds__(256)
void k_cross_out(const float* __restrict__ x, const float* __restrict__ oc,
                 const float* __restrict__ Wo, float* __restrict__ cn)
{
  __shared__ float os[512];
  int ib = blockIdx.x;
  for (int e=threadIdx.x;e<512;e+=256) os[e] = oc[(size_t)ib*512+e];
  __syncthreads();
  for (int n=threadIdx.x;n<512;n+=256){
    float acc = 0.f;
    for (int k=0;k<512;k++) acc += os[k]*Wo[(size_t)k*512+n];
    cn[(size_t)ib*512+n] = x[(size_t)ib*1056*512 + n] + acc;
  }
}

// 64 blocks: b = blk>>3, col-chunk = blk&7 (128 cols each). Stats recomputed per block.
__global__ __launch_bounds__(256)
void k_final(const float* __restrict__ cn, const float* __restrict__ nfg, const float* __restrict__ nfb,
             const float* __restrict__ Wdec, const float* __restrict__ bdec, float* __restrict__ out)
{
  int b = blockIdx.x >> 3;
  int n0 = (blockIdx.x & 7) * 128;
  __shared__ float an[512];
  __shared__ float red[8];
  int tid = threadIdx.x;
  float s = 0.f, q = 0.f;
  for (int e=tid;e<512;e+=256){
    float av = 0.5f*(cn[(size_t)b*512 + e] + cn[(size_t)(8+b)*512 + e]);
    an[e] = av; s += av; q += av*av;
  }
  #pragma unroll
  for (int m=1;m<64;m<<=1){ s += __shfl_xor(s,m); q += __shfl_xor(q,m); }
  int w = tid>>6;
  if ((tid&63)==0){ red[w] = s; red[4+w] = q; }
  __syncthreads();
  s = red[0]+red[1]+red[2]+red[3];
  q = red[4]+red[5]+red[6]+red[7];
  float mu = s*0.001953125f;
  float var = q*0.001953125f - mu*mu;
  float rstd = rsqrtf(var + 1e-6f);
  for (int e=tid;e<512;e+=256) an[e] = nfg[e]*(an[e]-mu)*rstd + nfb[e];
  __syncthreads();
  for (int n=tid;n<128;n+=256){
    int col = n0 + n;
    float acc = bdec[col];
    for (int e=0;e<512;e++) acc += an[e]*Wdec[(size_t)e*1024 + col];
    out[(size_t)b*1024 + col] = acc;
  }
}

// =======================================================================
extern "C" void kernel_launch(void* const* d_in, const int* in_sizes, int n_in,
                              void* d_out, int out_size, void* d_ws, size_t ws_size,
                              hipStream_t stream)
{
  (void)in_sizes; (void)n_in;
  const float* img1 = (const float*)d_in[0];
  const float* img2 = (const float*)d_in[1];
  const float* patchW = (const float*)d_in[2];
  const float* cls_t = (const float*)d_in[3];
  const float* cls_p = (const float*)d_in[4];
  const float* ln1g = (const float*)d_in[5];
  const float* ln1b = (const float*)d_in[6];
  const float* Wqkv = (const float*)d_in[7];
  const float* Wo   = (const float*)d_in[8];
  const float* ln2g = (const float*)d_in[9];
  const float* ln2b = (const float*)d_in[10];
  const float* W1   = (const float*)d_in[11];
  const float* b1   = (const float*)d_in[12];
  const float* W2   = (const float*)d_in[13];
  const float* b2   = (const float*)d_in[14];
  const float* Wqc  = (const float*)d_in[15];
  const float* Wkvc = (const float*)d_in[16];
  const float* Woc  = (const float*)d_in[17];
  const float* nfg  = (const float*)d_in[18];
  const float* nfb  = (const float*)d_in[19];
  const float* Wdec = (const float*)d_in[20];
  const float* bdec = (const float*)d_in[21];
  float* out = (float*)d_out;

  // ---- compact aliased workspace layout (bytes) ----
  const size_t offA = 34603008, offB = 51904512, offC = 121110528, offD = 148111360;
  const size_t NEEDED = 148209664;
  if (ws_size < NEEDED){
    hipMemsetAsync(d_out, 0, (size_t)out_size*sizeof(float), stream);
    return;
  }
  char* ws = (char*)d_ws;
  float* x    = (float*)ws;
  short* y    = (short*)(ws + offA);
  short* attn = y;
  short* qkv  = (short*)(ws + offB);
  short* vT   = (short*)(ws + offB + 51904512);
  short* mh   = (short*)(ws + offB);
  short* patches = (short*)(ws + offB);
  float* pe   = (float*)(ws + offB + 25165824);
  short* kvc  = (short*)(ws + offB);
  short* wts  = (short*)(ws + offC);
  float* qc   = (float*)(ws + offD);
  float* oc   = (float*)(ws + offD + 32768);
  float* cn   = (float*)(ws + offD + 65536);

  short* patchWt = wts;              // [512][768]
  short* WqkvT = wts + 393216;       // 4 x [1536][512]
  short* WoT   = wts + 3538944;      // 4 x [512][512]
  short* W1T   = wts + 4587520;      // 4 x [2048][512]
  short* W2T   = wts + 8781824;      // 4 x [512][2048]
  short* WkvT  = wts + 12976128;     // [1024][512]

  dim3 tb(32,8,1);
  k_transpose<<<dim3(16,24,1), tb, 0, stream>>>(patchW, patchWt, 768, 512, (size_t)768*512);
  k_transpose<<<dim3(48,16,4), tb, 0, stream>>>(Wqkv, WqkvT, 512, 1536, (size_t)512*1536);
  k_transpose<<<dim3(16,16,4), tb, 0, stream>>>(Wo,   WoT,   512, 512,  (size_t)512*512);
  k_transpose<<<dim3(64,16,4), tb, 0, stream>>>(W1,   W1T,   512, 2048, (size_t)512*2048);
  k_transpose<<<dim3(16,64,4), tb, 0, stream>>>(W2,   W2T,   2048, 512, (size_t)2048*512);
  k_transpose<<<dim3(32,16,1), tb, 0, stream>>>(Wkvc, WkvT,  512, 1024, (size_t)512*1024);

  k_pe<<<1024, 256, 0, stream>>>(pe);
  k_gather<<<16384, 256, 0, stream>>>(img1, img2, patches);
  k_zeropad<<<496, 512, 0, stream>>>(x);
  k_cls<<<16, 512, 0, stream>>>(cls_t, cls_p, x);

  EpiArgs ea;
  // patch embedding: x[:,1:1025,:] = patches @ patchW + pe   (grid 4x128 -> 512)
  ea = EpiArgs{nullptr, x, nullptr, pe, nullptr};
  k_gemm<4><<<512, 256, 0, stream>>>(patches, patchWt, 16384, 512, 768, 4, ea);

  for (int i=0;i<4;i++){
    k_layernorm<<<4224, 256, 0, stream>>>(x, y, ln1g + i*512, ln1b + i*512);
    ea = EpiArgs{qkv, nullptr, nullptr, nullptr, vT};
    k_gemm<1><<<1584, 256, 0, stream>>>(y, WqkvT + (size_t)i*1536*512, 16896, 1536, 512, 12, ea);
    k_attn<<<dim3(9, 128), 256, 0, stream>>>(qkv, vT, attn);
    ea = EpiArgs{nullptr, x, nullptr, nullptr, nullptr};
    k_gemm<2><<<528, 256, 0, stream>>>(attn, WoT + (size_t)i*512*512, 16896, 512, 512, 4, ea);
    k_layernorm<<<4224, 256, 0, stream>>>(x, y, ln2g + i*512, ln2b + i*512);
    ea = EpiArgs{mh, nullptr, b1 + i*2048, nullptr, nullptr};
    k_gemm<3><<<2112, 256, 0, stream>>>(y, W1T + (size_t)i*2048*512, 16896, 2048, 512, 16, ea);
    ea = EpiArgs{nullptr, x, b2 + i*512, nullptr, nullptr};
    k_gemm<2><<<528, 256, 0, stream>>>(mh, W2T + (size_t)i*512*2048, 16896, 512, 2048, 4, ea);
  }

  // cross attention between cls tokens and the other image's tokens
  k_cast_bf16<<<4224, 256, 0, stream>>>(x, y);
  ea = EpiArgs{kvc, nullptr, nullptr, nullptr, nullptr};
  k_gemm<0><<<1056, 256, 0, stream>>>(y, WkvT, 16896, 1024, 512, 8, ea);
  k_cross_q<<<16, 256, 0, stream>>>(x, Wqc, qc);
  k_cross_attn<<<128, 64, 0, stream>>>(qc, kvc, oc);
  k_cross_out<<<16, 256, 0, stream>>>(x, oc, Woc, cn);
  k_final<<<64, 256, 0, stream>>>(cn, nfg, nfb, Wdec, bdec, out);
}

// Round 10
// 1496.736 us; speedup vs baseline: 1.6105x; 1.0541x over previous
//
#include <hip/hip_runtime.h>
#include <stdint.h>
#include <math.h>

typedef __attribute__((ext_vector_type(4))) float f4;
typedef __attribute__((ext_vector_type(8))) __bf16 bf8;
typedef __attribute__((ext_vector_type(8))) short s8;
typedef __attribute__((ext_vector_type(4))) uint32_t u32x4;

#define DI __device__ __forceinline__

DI short f2bf(float f){
  union { float f; uint32_t u; } v; v.f = f;
  uint32_t r = v.u + 0x7fffu + ((v.u >> 16) & 1u);
  return (short)(r >> 16);
}
DI float bf2f(short s){
  union { uint32_t u; float f; } v; v.u = ((uint32_t)(uint16_t)s) << 16;
  return v.f;
}
// packed f32x2 -> bf16x2 (RNE), lo = first arg
DI uint32_t cvtpk(float lo, float hi){
  uint32_t r;
  asm("v_cvt_pk_bf16_f32 %0, %1, %2" : "=v"(r) : "v"(lo), "v"(hi));
  return r;
}
// raw 2^x (v_exp_f32). Denormal results flush to 0 — fine for softmax weights.
DI float fexp2(float x){
  float r;
  asm("v_exp_f32 %0, %1" : "=v"(r) : "v"(x));
  return r;
}
// gelu-tanh == u * sigmoid(2c*(u + 0.044715 u^3)); exp in exp2 domain:
// 2c/ln2 = 2.3022081383. One v_exp, no extra mul.
DI float gelu_f(float u){
  float zl = 2.3022081383f * u * fmaf(0.044715f, u*u, 1.f);
  return u * __builtin_amdgcn_rcpf(1.f + fexp2(-zl));
}
DI void gload16(const void* g, void* l){
  __builtin_amdgcn_global_load_lds((const __attribute__((address_space(1))) unsigned*)g,
                                   (__attribute__((address_space(3))) unsigned*)l, 16, 0, 0);
}

// ---------------- transpose + f32->bf16 convert: in [K][N] f32 -> out [N][K] bf16
// launch grid = (N/32, K/32, z)
__global__ __launch_bounds__(256)
void k_transpose(const float* __restrict__ in, short* __restrict__ out, int K, int N, size_t stride)
{
  __shared__ float t[32][33];
  in  += (size_t)blockIdx.z * stride;
  out += (size_t)blockIdx.z * stride;
  int n0 = blockIdx.x*32, k0 = blockIdx.y*32;
  int tx = threadIdx.x, ty = threadIdx.y;
  #pragma unroll
  for (int i=0;i<32;i+=8) t[ty+i][tx] = in[(size_t)(k0+ty+i)*N + n0+tx];
  __syncthreads();
  #pragma unroll
  for (int i=0;i<32;i+=8) out[(size_t)(n0+ty+i)*K + k0+tx] = f2bf(t[tx][ty+i]);
}

// ---------------- sinusoidal positional table pe[1024][512] f32
__global__ void k_pe(float* __restrict__ pe)
{
  int p = blockIdx.x;
  for (int d = threadIdx.x; d < 512; d += 256){
    int j = (d < 256) ? d : d - 256;
    float div = expf((float)(2*j) * (-9.210340371976184f/512.f));
    float a = (float)p * div;
    pe[(size_t)p*512 + d] = (d < 256) ? sinf(a) : cosf(a);
  }
}

// ---------------- patch gather: img NHWC f32 -> patches[16384][768] bf16
__global__ __launch_bounds__(256)
void k_gather(const float* __restrict__ img1, const float* __restrict__ img2, short* __restrict__ patches)
{
  int row = blockIdx.x;              // (img*8 + b)*1024 + p
  int img = row >> 13;
  int b   = (row >> 10) & 7;
  int p   = row & 1023;
  int ph = p >> 5, pw = p & 31;
  const float* src = (img ? img2 : img1) + (size_t)b*512*512*3;
  short* dst = patches + (size_t)row*768;
  for (int k = threadIdx.x; k < 768; k += 256){
    int i = k / 48; int rem = k - i*48; int j = rem / 3; int c = rem - j*3;
    int yy = ph*16 + i, xx = pw*16 + j;
    dst[k] = f2bf(src[((size_t)yy*512 + xx)*3 + c]);
  }
}

// ---------------- zero pad token rows of x, set cls rows
__global__ void k_zeropad(float* __restrict__ x)
{
  int idx = blockIdx.x; int ib = idx / 31; int t = 1025 + (idx - ib*31);
  x[((size_t)ib*1056 + t)*512 + threadIdx.x] = 0.f;
}
__global__ void k_cls(const float* __restrict__ ct, const float* __restrict__ cp, float* __restrict__ x)
{
  int ib = blockIdx.x; int e = threadIdx.x;
  x[(size_t)ib*1056*512 + e] = ct[e] + cp[e];
}

// ---------------- layernorm rows of x (fp32) -> y (bf16). 4 rows/block, 1 wave per row.
__global__ __launch_bounds__(256)
void k_layernorm(const float* __restrict__ x, short* __restrict__ y,
                 const float* __restrict__ g, const float* __restrict__ b)
{
  int row = blockIdx.x*4 + (threadIdx.x>>6);
  int l = threadIdx.x & 63;
  const float* xr = x + (size_t)row*512 + l*8;
  f4 v0 = *(const f4*)xr;
  f4 v1 = *(const f4*)(xr+4);
  float s = v0[0]+v0[1]+v0[2]+v0[3]+v1[0]+v1[1]+v1[2]+v1[3];
  float q = v0[0]*v0[0]+v0[1]*v0[1]+v0[2]*v0[2]+v0[3]*v0[3]
          + v1[0]*v1[0]+v1[1]*v1[1]+v1[2]*v1[2]+v1[3]*v1[3];
  #pragma unroll
  for (int m=1;m<64;m<<=1){ s += __shfl_xor(s,m); q += __shfl_xor(q,m); }
  float mu = s * 0.001953125f;
  float var = q * 0.001953125f - mu*mu;
  float rstd = rsqrtf(var + 1e-6f);
  const float* gp = g + l*8;
  const float* bp = b + l*8;
  float ov[8];
  #pragma unroll
  for (int j=0;j<8;j++){
    float xv = (j<4) ? v0[j] : v1[j-4];
    ov[j] = gp[j]*(xv-mu)*rstd + bp[j];
  }
  u32x4 pk;
  #pragma unroll
  for (int j=0;j<4;j++) pk[j] = cvtpk(ov[2*j], ov[2*j+1]);
  *(u32x4*)(y + (size_t)row*512 + l*8) = pk;
}

// ---------------- straight f32 -> bf16 cast (8 elems/thread)
__global__ void k_cast_bf16(const float* __restrict__ in, short* __restrict__ out)
{
  size_t i = (size_t)blockIdx.x*256 + threadIdx.x;
  const float* p = in + i*8;
  u32x4 pk;
  #pragma unroll
  for (int j=0;j<4;j++) pk[j] = cvtpk(p[2*j], p[2*j+1]);
  *(u32x4*)(out + i*8) = pk;
}

// ---------------- bf16 MFMA GEMM, 128x128 tile, BK=64, A[M][K], Bt[N][K]
// 1-D grid + bijective XCD-chunked swizzle (nwg divisible by 8).
// LDS XOR-swizzled (both sides: pre-swizzled global src + swizzled ds_read).
// EPI: 0=bf16 out, 1=bf16 out + q-prescale(1/8*log2e) + vT scatter (QKV),
//      2=f32 residual add (+bias), 3=bias+gelu->bf16, 4=embed(+pe)->x
struct EpiArgs { short* outb; float* outf; const float* bias; const float* pe; short* vT; };

template<int EPI>
__global__ __launch_bounds__(256)
void k_gemm(const short* __restrict__ A, const short* __restrict__ Bt,
            int M, int N, int K, int gridX, EpiArgs ea)
{
  __shared__ short Al[128*64];
  __shared__ short Bl[128*64];
  const int tid = threadIdx.x;
  const int l = tid & 63;
  const int w = tid >> 6;
  const int wr = (w >> 1) * 64, wc = (w & 1) * 64;
  const int lr = l & 15, lg = l >> 4;
  // XCD-chunked bijective swizzle: blocks on XCD c compute a contiguous tile range
  const int nwg = gridDim.x;
  const int q8 = nwg >> 3;
  const int nb = (blockIdx.x & 7) * q8 + (blockIdx.x >> 3);
  const int brow = (nb / gridX) * 128, bcol = (nb % gridX) * 128;
  const short* Ab = A  + (size_t)brow * K;
  const short* Bb = Bt + (size_t)bcol * K;
  f4 acc[4][4];
  #pragma unroll
  for (int m=0;m<4;m++)
    #pragma unroll
    for (int n=0;n<4;n++){ acc[m][n][0]=0.f; acc[m][n][1]=0.f; acc[m][n][2]=0.f; acc[m][n][3]=0.f; }

  // read-side swizzled col-slot per thread (involution: slot ^ (row&7))
  const int rsw = lr & 7;
  for (int kt = 0; kt < K; kt += 64){
    #pragma unroll
    for (int i=0;i<4;i++){
      int s   = i*256 + tid;
      int row = s >> 3;
      int gs  = (s & 7) ^ (row & 7);
      gload16(Ab + (size_t)row*K + kt + gs*8, &Al[s*8]);
      gload16(Bb + (size_t)row*K + kt + gs*8, &Bl[s*8]);
    }
    __syncthreads();
    #pragma unroll
    for (int ko=0;ko<2;ko++){
      bf8 af[4], bfr[4];
      const int ps = ((ko*4 + lg) ^ rsw) * 8;
      #pragma unroll
      for (int m=0;m<4;m++) af[m]  = *(const bf8*)&Al[(wr + m*16 + lr)*64 + ps];
      #pragma unroll
      for (int n=0;n<4;n++) bfr[n] = *(const bf8*)&Bl[(wc + n*16 + lr)*64 + ps];
      #pragma unroll
      for (int m=0;m<4;m++)
        #pragma unroll
        for (int n=0;n<4;n++)
          acc[m][n] = __builtin_amdgcn_mfma_f32_16x16x32_bf16(af[m], bfr[n], acc[m][n], 0, 0, 0);
    }
    __syncthreads();
  }

  #pragma unroll
  for (int m=0;m<4;m++){
    #pragma unroll
    for (int n=0;n<4;n++){
      const int row0 = brow + wr + m*16 + lg*4;
      const int col  = bcol + wc + n*16 + lr;
      float v0 = acc[m][n][0], v1 = acc[m][n][1], v2 = acc[m][n][2], v3 = acc[m][n][3];
      if (EPI == 0 || EPI == 1){
        if (EPI == 1 && col < 512){
          // 1/8 * log2(e): softmax runs in exp2 domain
          const float qs = 0.1803368801111204f;
          v0*=qs; v1*=qs; v2*=qs; v3*=qs;
        }
        uint32_t u01 = cvtpk(v0, v1), u23 = cvtpk(v2, v3);
        short s0 = (short)u01, s1 = (short)(u01>>16), s2 = (short)u23, s3 = (short)(u23>>16);
        ea.outb[(size_t)(row0+0)*N + col] = s0;
        ea.outb[(size_t)(row0+1)*N + col] = s1;
        ea.outb[(size_t)(row0+2)*N + col] = s2;
        ea.outb[(size_t)(row0+3)*N + col] = s3;
        if (EPI == 1 && col >= 1024){
          int ib = row0 / 1056, t = row0 - ib*1056;
          short* vtb = ea.vT + ((size_t)ib*512 + (col - 1024))*1056;
          vtb[t] = s0; vtb[t+1] = s1; vtb[t+2] = s2; vtb[t+3] = s3;
        }
      } else if (EPI == 2){
        float bv = ea.bias ? ea.bias[col] : 0.f;
        ea.outf[(size_t)(row0+0)*N + col] += v0 + bv;
        ea.outf[(size_t)(row0+1)*N + col] += v1 + bv;
        ea.outf[(size_t)(row0+2)*N + col] += v2 + bv;
        ea.outf[(size_t)(row0+3)*N + col] += v3 + bv;
      } else if (EPI == 3){
        float bv = ea.bias[col];
        float g0 = gelu_f(v0+bv), g1 = gelu_f(v1+bv), g2 = gelu_f(v2+bv), g3 = gelu_f(v3+bv);
        uint32_t u01 = cvtpk(g0, g1), u23 = cvtpk(g2, g3);
        ea.outb[(size_t)(row0+0)*N + col] = (short)u01;
        ea.outb[(size_t)(row0+1)*N + col] = (short)(u01>>16);
        ea.outb[(size_t)(row0+2)*N + col] = (short)u23;
        ea.outb[(size_t)(row0+3)*N + col] = (short)(u23>>16);
      } else if (EPI == 4){
        #pragma unroll
        for (int r=0;r<4;r++){
          int row = row0 + r;
          int ib = row >> 10, p = row & 1023;
          float v = (r==0)?v0:(r==1)?v1:(r==2)?v2:v3;
          ea.outf[((size_t)(ib*1056 + 1 + p))*512 + col] = v + ea.pe[(size_t)p*512 + col];
        }
      }
    }
  }
}

// ---------------- fused self-attention v6c: 16x16 MFMA, swapped QK^T in exp2
// domain (Q pre-scaled by log2e/8), in-register softmax with RAW v_exp_f32,
// defer-max, last-tile masking, cooperative double-buffered LDS K/V staging.
__global__ __launch_bounds__(256)
void k_attn(const short* __restrict__ qkv, const short* __restrict__ vT, short* __restrict__ aout)
{
  __shared__ __align__(16) short Kl[2][32*64];   // K tile: 32 tok x 64 d (swizzled slots)
  __shared__ __align__(16) short Vl[2][64*32];   // V tile: 64 d x 32 tok (swizzled slots)
  __shared__ short Pl[4][2][32*40];
  __shared__ float Sc[4][2][32];

  const int tid = threadIdx.x;
  const int w  = tid >> 6;
  const int qtR = blockIdx.x * 4 + w;
  const int qt  = qtR > 32 ? 32 : qtR;      // clamp; all waves stay for barriers
  const int u  = blockIdx.y;
  const int ib = u >> 3, h = u & 7;
  const int l = tid & 63, lr = l & 15, lg = l >> 4;
  const size_t rb = (size_t)ib * 1056;
  const int t0 = qt * 32;
  const float DEFER_THR = 11.541560327111707f;   // 8 * log2(e)

  bf8 qf[2][2];
  #pragma unroll
  for (int nq=0;nq<2;nq++)
    #pragma unroll
    for (int ks=0;ks<2;ks++)
      qf[nq][ks] = *(const bf8*)&qkv[(rb + t0 + nq*16 + lr)*1536 + h*64 + ks*32 + lg*8];

  f4 o[2][4];
  float mrun[2], lrun[2];
  #pragma unroll
  for (int mq=0;mq<2;mq++)
    #pragma unroll
    for (int nd=0;nd<4;nd++){ o[mq][nd][0]=0.f; o[mq][nd][1]=0.f; o[mq][nd][2]=0.f; o[mq][nd][3]=0.f; }
  mrun[0]=mrun[1]=-1e30f; lrun[0]=lrun[1]=0.f;

  // cooperative staging: K rows are 128B contiguous, V rows 64B contiguous.
  // LDS slot s holds global col-slot (s ^ row&mask) -> read with same involution.
  auto STAGE = [&](int buf, int jt){
    const int j0 = jt*32;
    {
      int krow = tid >> 3, ks = tid & 7;
      int gs = ks ^ (krow & 7);
      gload16(&qkv[(rb + j0 + krow)*1536 + 512 + h*64 + gs*8], &Kl[buf][tid*8]);
    }
    {
      int vrow = tid >> 2, vs = tid & 3;
      int gs = vs ^ (vrow & 3);
      gload16(&vT[((size_t)ib*512 + h*64 + vrow)*1056 + j0 + gs*8], &Vl[buf][tid*8]);
    }
  };

  STAGE(0, 0);

  for (int jt=0; jt<=32; jt++){
    const int cur = jt & 1;
    const int pb  = cur;
    const bool MASK = (jt == 32);
    const int j0 = jt*32;
    __syncthreads();   // staged buf[cur] complete; all prev reads of buf[cur^1] done

    // fragments from LDS (swizzle-inverted)
    bf8 kc[2][2], vb[4];
    #pragma unroll
    for (int mk=0;mk<2;mk++)
      #pragma unroll
      for (int ks=0;ks<2;ks++)
        kc[mk][ks] = *(const bf8*)&Kl[cur][((mk*16+lr)*8 + ((ks*4+lg) ^ (lr&7)))*8];
    #pragma unroll
    for (int nd=0;nd<4;nd++)
      vb[nd] = *(const bf8*)&Vl[cur][((nd*16+lr)*4 + (lg ^ (lr&3)))*8];

    if (jt < 32) STAGE(cur^1, jt+1);   // overlaps with compute below

    f4 st[2][2];
    #pragma unroll
    for (int mk=0;mk<2;mk++)
      #pragma unroll
      for (int nq=0;nq<2;nq++){ st[mk][nq][0]=0.f; st[mk][nq][1]=0.f; st[mk][nq][2]=0.f; st[mk][nq][3]=0.f; }
    __builtin_amdgcn_s_setprio(1);
    #pragma unroll
    for (int ks=0;ks<2;ks++)
      #pragma unroll
      for (int mk=0;mk<2;mk++)
        #pragma unroll
        for (int nq=0;nq<2;nq++)
          st[mk][nq] = __builtin_amdgcn_mfma_f32_16x16x32_bf16(kc[mk][ks], qf[nq][ks], st[mk][nq], 0, 0, 0);
    __builtin_amdgcn_s_setprio(0);

    float p8[2][8], mx[2];
    #pragma unroll
    for (int nq=0;nq<2;nq++){
      mx[nq] = -1e30f;
      #pragma unroll
      for (int mk=0;mk<2;mk++)
        #pragma unroll
        for (int r=0;r<4;r++){
          float v = st[mk][nq][r];
          if (MASK){
            int kk = j0 + mk*16 + lg*4 + r;
            v = (kk > 1024) ? -1e30f : v;
          }
          p8[nq][mk*4+r] = v;
          mx[nq] = fmaxf(mx[nq], v);
        }
      mx[nq] = fmaxf(mx[nq], __shfl_xor(mx[nq], 16));
      mx[nq] = fmaxf(mx[nq], __shfl_xor(mx[nq], 32));
    }

    bool ok = (mx[0] <= mrun[0] + DEFER_THR) && (mx[1] <= mrun[1] + DEFER_THR);
    if (__all(ok)){
      // defer path: no max update, no rescale
      #pragma unroll
      for (int nq=0;nq<2;nq++){
        float rs = 0.f;
        #pragma unroll
        for (int i=0;i<8;i++){ float p = fexp2(p8[nq][i] - mrun[nq]); p8[nq][i] = p; rs += p; }
        rs += __shfl_xor(rs, 16);
        rs += __shfl_xor(rs, 32);
        lrun[nq] += rs;
        uint32_t* prow = (uint32_t*)&Pl[w][pb][(nq*16 + lr)*40];
        #pragma unroll
        for (int mk=0;mk<2;mk++){
          prow[mk*8 + lg*2]     = cvtpk(p8[nq][mk*4+0], p8[nq][mk*4+1]);
          prow[mk*8 + lg*2 + 1] = cvtpk(p8[nq][mk*4+2], p8[nq][mk*4+3]);
        }
      }
      asm volatile("s_waitcnt lgkmcnt(0)" ::: "memory");
      __builtin_amdgcn_sched_barrier(0);
      bf8 pa[2];
      #pragma unroll
      for (int mq=0;mq<2;mq++) pa[mq] = *(const bf8*)&Pl[w][pb][(mq*16 + lr)*40 + lg*8];
      __builtin_amdgcn_s_setprio(1);
      #pragma unroll
      for (int mq=0;mq<2;mq++)
        #pragma unroll
        for (int nd=0;nd<4;nd++)
          o[mq][nd] = __builtin_amdgcn_mfma_f32_16x16x32_bf16(pa[mq], vb[nd], o[mq][nd], 0, 0, 0);
      __builtin_amdgcn_s_setprio(0);
    } else {
      // full online-softmax path
      #pragma unroll
      for (int nq=0;nq<2;nq++){
        float mn = fmaxf(mrun[nq], mx[nq]);
        float sc = fexp2(mrun[nq] - mn);
        mrun[nq] = mn;
        float rs = 0.f;
        #pragma unroll
        for (int i=0;i<8;i++){ float p = fexp2(p8[nq][i] - mn); p8[nq][i] = p; rs += p; }
        rs += __shfl_xor(rs, 16);
        rs += __shfl_xor(rs, 32);
        lrun[nq] = lrun[nq]*sc + rs;
        Sc[w][pb][nq*16 + lr] = sc;
        uint32_t* prow = (uint32_t*)&Pl[w][pb][(nq*16 + lr)*40];
        #pragma unroll
        for (int mk=0;mk<2;mk++){
          prow[mk*8 + lg*2]     = cvtpk(p8[nq][mk*4+0], p8[nq][mk*4+1]);
          prow[mk*8 + lg*2 + 1] = cvtpk(p8[nq][mk*4+2], p8[nq][mk*4+3]);
        }
      }
      asm volatile("s_waitcnt lgkmcnt(0)" ::: "memory");
      __builtin_amdgcn_sched_barrier(0);
      f4 scv[2]; bf8 pa[2];
      #pragma unroll
      for (int mq=0;mq<2;mq++){
        scv[mq] = *(const f4*)&Sc[w][pb][mq*16 + lg*4];
        pa[mq]  = *(const bf8*)&Pl[w][pb][(mq*16 + lr)*40 + lg*8];
      }
      #pragma unroll
      for (int mq=0;mq<2;mq++)
        #pragma unroll
        for (int nd=0;nd<4;nd++){
          #pragma unroll
          for (int r=0;r<4;r++) o[mq][nd][r] *= scv[mq][r];
        }
      __builtin_amdgcn_s_setprio(1);
      #pragma unroll
      for (int mq=0;mq<2;mq++)
        #pragma unroll
        for (int nd=0;nd<4;nd++)
          o[mq][nd] = __builtin_amdgcn_mfma_f32_16x16x32_bf16(pa[mq], vb[nd], o[mq][nd], 0, 0, 0);
      __builtin_amdgcn_s_setprio(0);
    }
  }

  if (qtR <= 32){
    // final 1/l normalization: route lrun (per q=nq*16+lr) to o-rows (q=mq*16+lg*4+r)
    #pragma unroll
    for (int nq=0;nq<2;nq++) Sc[w][1][nq*16 + lr] = lrun[nq];
    asm volatile("s_waitcnt lgkmcnt(0)" ::: "memory");
    __builtin_amdgcn_sched_barrier(0);
    #pragma unroll
    for (int mq=0;mq<2;mq++){
      f4 lsv = *(const f4*)&Sc[w][1][mq*16 + lg*4];
      float i0 = __builtin_amdgcn_rcpf(lsv[0]);
      float i1 = __builtin_amdgcn_rcpf(lsv[1]);
      float i2 = __builtin_amdgcn_rcpf(lsv[2]);
      float i3 = __builtin_amdgcn_rcpf(lsv[3]);
      const size_t base = rb + t0 + mq*16 + lg*4;
      #pragma unroll
      for (int nd=0;nd<4;nd++){
        int col = h*64 + nd*16 + lr;
        uint32_t u01 = cvtpk(o[mq][nd][0]*i0, o[mq][nd][1]*i1);
        uint32_t u23 = cvtpk(o[mq][nd][2]*i2, o[mq][nd][3]*i3);
        aout[(base+0)*512 + col] = (short)u01;
        aout[(base+1)*512 + col] = (short)(u01>>16);
        aout[(base+2)*512 + col] = (short)u23;
        aout[(base+3)*512 + col] = (short)(u23>>16);
      }
    }
  }
}

// ---------------- cross-attention path (tiny, fp32)
__global__ __launch_bounds__(256)
void k_cross_q(const float* __restrict__ x, const float* __restrict__ Wq, float* __restrict__ qc)
{
  __shared__ float xs[512];
  int ib = blockIdx.x;
  const float* xr = x + (size_t)ib*1056*512;
  for (int e=threadIdx.x;e<512;e+=256) xs[e] = xr[e];
  __syncthreads();
  for (int n=threadIdx.x;n<512;n+=256){
    float acc = 0.f;
    for (int k=0;k<512;k++) acc += xs[k]*Wq[(size_t)k*512 + n];
    qc[(size_t)ib*512 + n] = acc;
  }
}

__global__ __launch_bounds__(64)
void k_cross_attn(const float* __restrict__ qc, const short* __restrict__ kv, float* __restrict__ oc)
{
  int u = blockIdx.x; int ib = u >> 3, h = u & 7;
  int img = ib >> 3, b = ib & 7;
  int sib = (1 - img)*8 + b;
  int l = threadIdx.x;
  __shared__ float qs[64];
  __shared__ float pl[1024];
  qs[l] = qc[(size_t)ib*512 + h*64 + l];
  __syncthreads();
  float lmax = -1e30f;
  for (int jj=0; jj<16; jj++){
    int j = jj*64 + l;
    const short* kr = kv + ((size_t)(sib*1056 + 1 + j))*1024 + h*64;
    float acc = 0.f;
    for (int d=0; d<64; d++) acc += qs[d]*bf2f(kr[d]);
    acc *= 0.125f;
    pl[j] = acc;
    lmax = fmaxf(lmax, acc);
  }
  #pragma unroll
  for (int m=1;m<64;m<<=1) lmax = fmaxf(lmax, __shfl_xor(lmax, m));
  __syncthreads();
  float lsum = 0.f;
  for (int jj=0; jj<16; jj++){
    int j = jj*64 + l;
    float p = __expf(pl[j] - lmax);
    pl[j] = p; lsum += p;
  }
  #pragma unroll
  for (int m=1;m<64;m<<=1) lsum += __shfl_xor(lsum, m);
  __syncthreads();
  float acc = 0.f;
  for (int j=0;j<1024;j++)
    acc += pl[j] * bf2f(kv[((size_t)(sib*1056 + 1 + j))*1024 + 512 + h*64 + l]);
  oc[(size_t)ib*512 + h*64 + l] = acc / lsum;
}

__global__ __launch_bounds__(256)
void k_cross_out(const float* __restrict__ x, const float* __restrict__ oc,
                 const float* __restrict__ Wo, float* __restrict__ cn)
{
  __shared__ float os[512];
  int ib = blockIdx.x;
  for (int e=threadIdx.x;e<512;e+=256) os[e] = oc[(size_t)ib*512+e];
  __syncthreads();
  for (int n=threadIdx.x;n<512;n+=256){
    float acc = 0.f;
    for (int k=0;k<512;k++) acc += os[k]*Wo[(size_t)k*512+n];
    cn[(size_t)ib*512+n] = x[(size_t)ib*1056*512 + n] + acc;
  }
}

// 64 blocks: b = blk>>3, col-chunk = blk&7 (128 cols each). Stats recomputed per block.
__global__ __launch_bounds__(256)
void k_final(const float* __restrict__ cn, const float* __restrict__ nfg, const float* __restrict__ nfb,
             const float* __restrict__ Wdec, const float* __restrict__ bdec, float* __restrict__ out)
{
  int b = blockIdx.x >> 3;
  int n0 = (blockIdx.x & 7) * 128;
  __shared__ float an[512];
  __shared__ float red[8];
  int tid = threadIdx.x;
  float s = 0.f, q = 0.f;
  for (int e=tid;e<512;e+=256){
    float av = 0.5f*(cn[(size_t)b*512 + e] + cn[(size_t)(8+b)*512 + e]);
    an[e] = av; s += av; q += av*av;
  }
  #pragma unroll
  for (int m=1;m<64;m<<=1){ s += __shfl_xor(s,m); q += __shfl_xor(q,m); }
  int w = tid>>6;
  if ((tid&63)==0){ red[w] = s; red[4+w] = q; }
  __syncthreads();
  s = red[0]+red[1]+red[2]+red[3];
  q = red[4]+red[5]+red[6]+red[7];
  float mu = s*0.001953125f;
  float var = q*0.001953125f - mu*mu;
  float rstd = rsqrtf(var + 1e-6f);
  for (int e=tid;e<512;e+=256) an[e] = nfg[e]*(an[e]-mu)*rstd + nfb[e];
  __syncthreads();
  for (int n=tid;n<128;n+=256){
    int col = n0 + n;
    float acc = bdec[col];
    for (int e=0;e<512;e++) acc += an[e]*Wdec[(size_t)e*1024 + col];
    out[(size_t)b*1024 + col] = acc;
  }
}

// =======================================================================
extern "C" void kernel_launch(void* const* d_in, const int* in_sizes, int n_in,
                              void* d_out, int out_size, void* d_ws, size_t ws_size,
                              hipStream_t stream)
{
  (void)in_sizes; (void)n_in;
  const float* img1 = (const float*)d_in[0];
  const float* img2 = (const float*)d_in[1];
  const float* patchW = (const float*)d_in[2];
  const float* cls_t = (const float*)d_in[3];
  const float* cls_p = (const float*)d_in[4];
  const float* ln1g = (const float*)d_in[5];
  const float* ln1b = (const float*)d_in[6];
  const float* Wqkv = (const float*)d_in[7];
  const float* Wo   = (const float*)d_in[8];
  const float* ln2g = (const float*)d_in[9];
  const float* ln2b = (const float*)d_in[10];
  const float* W1   = (const float*)d_in[11];
  const float* b1   = (const float*)d_in[12];
  const float* W2   = (const float*)d_in[13];
  const float* b2   = (const float*)d_in[14];
  const float* Wqc  = (const float*)d_in[15];
  const float* Wkvc = (const float*)d_in[16];
  const float* Woc  = (const float*)d_in[17];
  const float* nfg  = (const float*)d_in[18];
  const float* nfb  = (const float*)d_in[19];
  const float* Wdec = (const float*)d_in[20];
  const float* bdec = (const float*)d_in[21];
  float* out = (float*)d_out;

  // ---- compact aliased workspace layout (bytes) ----
  const size_t offA = 34603008, offB = 51904512, offC = 121110528, offD = 148111360;
  const size_t NEEDED = 148209664;
  if (ws_size < NEEDED){
    hipMemsetAsync(d_out, 0, (size_t)out_size*sizeof(float), stream);
    return;
  }
  char* ws = (char*)d_ws;
  float* x    = (float*)ws;
  short* y    = (short*)(ws + offA);
  short* attn = y;
  short* qkv  = (short*)(ws + offB);
  short* vT   = (short*)(ws + offB + 51904512);
  short* mh   = (short*)(ws + offB);
  short* patches = (short*)(ws + offB);
  float* pe   = (float*)(ws + offB + 25165824);
  short* kvc  = (short*)(ws + offB);
  short* wts  = (short*)(ws + offC);
  float* qc   = (float*)(ws + offD);
  float* oc   = (float*)(ws + offD + 32768);
  float* cn   = (float*)(ws + offD + 65536);

  short* patchWt = wts;              // [512][768]
  short* WqkvT = wts + 393216;       // 4 x [1536][512]
  short* WoT   = wts + 3538944;      // 4 x [512][512]
  short* W1T   = wts + 4587520;      // 4 x [2048][512]
  short* W2T   = wts + 8781824;      // 4 x [512][2048]
  short* WkvT  = wts + 12976128;     // [1024][512]

  dim3 tb(32,8,1);
  k_transpose<<<dim3(16,24,1), tb, 0, stream>>>(patchW, patchWt, 768, 512, (size_t)768*512);
  k_transpose<<<dim3(48,16,4), tb, 0, stream>>>(Wqkv, WqkvT, 512, 1536, (size_t)512*1536);
  k_transpose<<<dim3(16,16,4), tb, 0, stream>>>(Wo,   WoT,   512, 512,  (size_t)512*512);
  k_transpose<<<dim3(64,16,4), tb, 0, stream>>>(W1,   W1T,   512, 2048, (size_t)512*2048);
  k_transpose<<<dim3(16,64,4), tb, 0, stream>>>(W2,   W2T,   2048, 512, (size_t)2048*512);
  k_transpose<<<dim3(32,16,1), tb, 0, stream>>>(Wkvc, WkvT,  512, 1024, (size_t)512*1024);

  k_pe<<<1024, 256, 0, stream>>>(pe);
  k_gather<<<16384, 256, 0, stream>>>(img1, img2, patches);
  k_zeropad<<<496, 512, 0, stream>>>(x);
  k_cls<<<16, 512, 0, stream>>>(cls_t, cls_p, x);

  EpiArgs ea;
  // patch embedding: x[:,1:1025,:] = patches @ patchW + pe   (grid 4x128 -> 512)
  ea = EpiArgs{nullptr, x, nullptr, pe, nullptr};
  k_gemm<4><<<512, 256, 0, stream>>>(patches, patchWt, 16384, 512, 768, 4, ea);

  for (int i=0;i<4;i++){
    k_layernorm<<<4224, 256, 0, stream>>>(x, y, ln1g + i*512, ln1b + i*512);
    ea = EpiArgs{qkv, nullptr, nullptr, nullptr, vT};
    k_gemm<1><<<1584, 256, 0, stream>>>(y, WqkvT + (size_t)i*1536*512, 16896, 1536, 512, 12, ea);
    k_attn<<<dim3(9, 128), 256, 0, stream>>>(qkv, vT, attn);
    ea = EpiArgs{nullptr, x, nullptr, nullptr, nullptr};
    k_gemm<2><<<528, 256, 0, stream>>>(attn, WoT + (size_t)i*512*512, 16896, 512, 512, 4, ea);
    k_layernorm<<<4224, 256, 0, stream>>>(x, y, ln2g + i*512, ln2b + i*512);
    ea = EpiArgs{mh, nullptr, b1 + i*2048, nullptr, nullptr};
    k_gemm<3><<<2112, 256, 0, stream>>>(y, W1T + (size_t)i*2048*512, 16896, 2048, 512, 16, ea);
    ea = EpiArgs{nullptr, x, b2 + i*512, nullptr, nullptr};
    k_gemm<2><<<528, 256, 0, stream>>>(mh, W2T + (size_t)i*512*2048, 16896, 512, 2048, 4, ea);
  }

  // cross attention between cls tokens and the other image's tokens
  k_cast_bf16<<<4224, 256, 0, stream>>>(x, y);
  ea = EpiArgs{kvc, nullptr, nullptr, nullptr, nullptr};
  k_gemm<0><<<1056, 256, 0, stream>>>(y, WkvT, 16896, 1024, 512, 8, ea);
  k_cross_q<<<16, 256, 0, stream>>>(x, Wqc, qc);
  k_cross_attn<<<128, 64, 0, stream>>>(qc, kvc, oc);
  k_cross_out<<<16, 256, 0, stream>>>(x, oc, Woc, cn);
  k_final<<<64, 256, 0, stream>>>(cn, nfg, nfb, Wdec, bdec, out);
}